// Round 6
// baseline (394.127 us; speedup 1.0000x reference)
//
#include <hip/hip_runtime.h>
#include <math.h>

// ---------------------------------------------------------------------------
// GenNet_tanh forward, round 6:
//  - sup_agg v4: 64x192 tile, 32KB LDS, grid 1024 (4 blocks/CU)
//  - fused_gru: gates+rh+cand+rnn+transpose in one kernel (64 blocks)
// ---------------------------------------------------------------------------

#define T_WIN 4
#define NN 2048
#define F_IN 128
#define HF 256
#define HH 256
#define DZ 128
#define G_IN 384
#define EIN 512
#define E1D 256
#define E2D 64

typedef _Float16 f16;
typedef _Float16 f16x8 __attribute__((ext_vector_type(8)));
typedef _Float16 f16x4 __attribute__((ext_vector_type(4)));
typedef float f32x4 __attribute__((ext_vector_type(4)));

__device__ __forceinline__ float wave_sum(float v) {
#pragma unroll
  for (int o = 32; o > 0; o >>= 1) v += __shfl_down(v, o);
  return v;
}
__device__ __forceinline__ float wave_max(float v) {
#pragma unroll
  for (int o = 32; o > 0; o >>= 1) v = fmaxf(v, __shfl_down(v, o));
  return v;
}
__device__ __forceinline__ float fast_tanh(float x) {
  float e = __expf(-2.f * fabsf(x));
  float r = (1.f - e) / (1.f + e);
  return copysignf(r, x);
}

__device__ __forceinline__ void gld_lds16(const void* g, void* l) {
  __builtin_amdgcn_global_load_lds(
      (const __attribute__((address_space(1))) unsigned int*)g,
      (__attribute__((address_space(3))) unsigned int*)l, 16, 0, 0);
}

// ---------------------------------------------------------------------------
// fp16 MFMA GEMM, 128 x BN tile, BK=64, 256 threads (4 waves 2x2).
// A: [.,lda] row-major; dual-source: k<kspl from A, else A2 (lda2).
// BT: [N,ldb] row-major.  C index: r*ldc + cc.  grid.z advances by zA/zB/zC.
// EPI: 0 none, 1 relu, 5 z-sel tanh/sig, 6 col-sel.  WOUT: 0 f32, 1 f16, 2 both.
// ---------------------------------------------------------------------------
template <int EPI, int BN, int WOUT>
__global__ __launch_bounds__(256) void hgemm(
    const f16* __restrict__ A, const f16* __restrict__ A2,
    const f16* __restrict__ BT, const float* __restrict__ bias,
    const float* __restrict__ bias2, float* __restrict__ Cf,
    f16* __restrict__ Ch, int lda, int lda2, int kspl, int ldb,
    int ldc, int K, long zA, long zB, long zC) {
  constexpr int WN = BN / 2;
  constexpr int FN = WN / 16;
  constexpr int BI = BN / 32;
  __shared__ alignas(16) f16 As[128 * 64];
  __shared__ alignas(16) f16 Bs[BN * 64];
  const int tid = threadIdx.x;
  const int lane = tid & 63, wid = tid >> 6;
  const int wm = wid >> 1, wn = wid & 1;
  const int row0 = blockIdx.y * 128, col0 = blockIdx.x * BN;
  const long zb = blockIdx.z;
  A += zb * zA;
  BT += zb * zB;
  const int l8 = lane >> 3;
  const int lx = ((lane & 7) ^ l8) * 8;  // pre-swizzled source chunk
  const int sw = (lane & 7) * 8;         // frag-read XOR

  f32x4 acc[4][FN];
#pragma unroll
  for (int m = 0; m < 4; ++m)
#pragma unroll
    for (int n = 0; n < FN; ++n) acc[m][n] = (f32x4){0.f, 0.f, 0.f, 0.f};

  for (int k0 = 0; k0 < K; k0 += 64) {
#pragma unroll
    for (int i = 0; i < 4; ++i) {
      int r = wid * 32 + i * 8;
      const f16* src =
          (k0 < kspl) ? A + (size_t)(row0 + r + l8) * lda + k0 + lx
                      : A2 + (size_t)(row0 + r + l8) * lda2 + (k0 - kspl) + lx;
      gld_lds16(src, &As[r * 64]);
    }
#pragma unroll
    for (int i = 0; i < BI; ++i) {
      int r = wid * (BN / 4) + i * 8;
      gld_lds16(BT + (size_t)(col0 + r + l8) * ldb + k0 + lx, &Bs[r * 64]);
    }
    __syncthreads();
#pragma unroll
    for (int ks = 0; ks < 2; ++ks) {
      f16x8 af[4], bf[FN];
#pragma unroll
      for (int m = 0; m < 4; ++m)
        af[m] = *(const f16x8*)&As[((wm * 64 + m * 16 + (lane & 15)) * 64 +
                                    ks * 32 + (lane >> 4) * 8) ^ sw];
#pragma unroll
      for (int n = 0; n < FN; ++n)
        bf[n] = *(const f16x8*)&Bs[((wn * WN + n * 16 + (lane & 15)) * 64 +
                                    ks * 32 + (lane >> 4) * 8) ^ sw];
#pragma unroll
      for (int m = 0; m < 4; ++m)
#pragma unroll
        for (int n = 0; n < FN; ++n)
          acc[m][n] = __builtin_amdgcn_mfma_f32_16x16x32_f16(af[m], bf[n],
                                                             acc[m][n], 0, 0, 0);
    }
    __syncthreads();
  }

  const int cl = lane & 15, rh4 = (lane >> 4) * 4;
  float* Cfb = Cf + zb * zC;
  f16* Chb = Ch + zb * zC;
  const float* bp = (EPI == 5 && zb == 1) ? bias2 : bias;
#pragma unroll
  for (int m = 0; m < 4; ++m) {
#pragma unroll
    for (int n = 0; n < FN; ++n) {
      int cc = col0 + wn * WN + n * 16 + cl;
      float bv = 0.f;
      if (EPI == 6)
        bv = (cc < 256) ? bias[cc] : bias2[cc - 256];
      else if (bp)
        bv = bp[cc];
#pragma unroll
      for (int q = 0; q < 4; ++q) {
        size_t r = row0 + wm * 64 + m * 16 + rh4 + q;
        float v = acc[m][n][q] + bv;
        if (EPI == 1) v = fmaxf(v, 0.f);
        if (EPI == 5) v = (zb == 0) ? tanhf(v) : 1.f / (1.f + __expf(-v));
        if (EPI == 6) v = (cc < 256) ? tanhf(v) : 1.f / (1.f + __expf(-v));
        if (WOUT == 0 || WOUT == 2) Cfb[r * ldc + cc] = v;
        if (WOUT == 1 || WOUT == 2) Chb[r * ldc + cc] = (f16)v;
      }
    }
  }
}

// ---------------------------------------------------------------------------
// sup_agg v4: aggP[kh][t][m][c] partials.  Tile 64 rows x 192 cols x K=512.
// grid (32, 2, 16): x = m-tile, y = n-tile, z = t*4 + kh.  LDS 32 KB.
// ---------------------------------------------------------------------------
__global__ __launch_bounds__(256) void sup_agg(
    const float* __restrict__ sup, const f16* __restrict__ edmT,
    f16* __restrict__ aggP) {
  __shared__ alignas(16) f16 As[64 * 64];
  __shared__ alignas(16) f16 Bs[192 * 64];
  const int tid = threadIdx.x;
  const int lane = tid & 63, wid = tid >> 6;
  const int m0 = blockIdx.x * 64, n0 = blockIdx.y * 192;
  const int t = blockIdx.z >> 2, kh = blockIdx.z & 3;
  const int l8 = lane >> 3;
  const int lx = ((lane & 7) ^ l8) * 8;
  const int sw = (lane & 7) * 8;
  const int cl = lane & 15, hi = lane >> 4;
  const int wm = wid >> 1, wn = wid & 1;
  const float* supT = sup + (size_t)t * NN * NN;
  const f16* edmTt = edmT + (size_t)t * G_IN * NN;

  f32x4 acc[2][6];
#pragma unroll
  for (int m = 0; m < 2; ++m)
#pragma unroll
    for (int n = 0; n < 6; ++n) acc[m][n] = (f32x4){0.f, 0.f, 0.f, 0.f};

  const int ar = tid >> 2;       // 0..63 rows
  const int g0 = (tid & 3) * 2;  // source granule pair
  const int kbeg = kh * 512;

  for (int k0 = kbeg; k0 < kbeg + 512; k0 += 64) {
    const float* ap = supT + (size_t)(m0 + ar) * NN + k0 + (tid & 3) * 16;
    float4 f0 = *(const float4*)ap;
    float4 f1 = *(const float4*)(ap + 4);
    float4 f2 = *(const float4*)(ap + 8);
    float4 f3 = *(const float4*)(ap + 12);
    f16x8 hv0 = {(f16)f0.x, (f16)f0.y, (f16)f0.z, (f16)f0.w,
                 (f16)f1.x, (f16)f1.y, (f16)f1.z, (f16)f1.w};
    f16x8 hv1 = {(f16)f2.x, (f16)f2.y, (f16)f2.z, (f16)f2.w,
                 (f16)f3.x, (f16)f3.y, (f16)f3.z, (f16)f3.w};
    *(f16x8*)&As[ar * 64 + ((g0 ^ (ar & 7)) * 8)] = hv0;
    *(f16x8*)&As[ar * 64 + (((g0 + 1) ^ (ar & 7)) * 8)] = hv1;
#pragma unroll
    for (int i = 0; i < 6; ++i) {
      int rn = wid * 48 + i * 8;
      gld_lds16(edmTt + (size_t)(n0 + rn + l8) * NN + k0 + lx, &Bs[rn * 64]);
    }
    __syncthreads();
#pragma unroll
    for (int ks = 0; ks < 2; ++ks) {
      f16x8 af[2], bf[6];
#pragma unroll
      for (int m = 0; m < 2; ++m)
        af[m] = *(const f16x8*)&As[((wm * 32 + m * 16 + cl) * 64 + ks * 32 +
                                    hi * 8) ^ sw];
#pragma unroll
      for (int n = 0; n < 6; ++n)
        bf[n] = *(const f16x8*)&Bs[((wn * 96 + n * 16 + cl) * 64 + ks * 32 +
                                    hi * 8) ^ sw];
#pragma unroll
      for (int m = 0; m < 2; ++m)
#pragma unroll
        for (int n = 0; n < 6; ++n)
          acc[m][n] = __builtin_amdgcn_mfma_f32_16x16x32_f16(af[m], bf[n],
                                                             acc[m][n], 0, 0, 0);
    }
    __syncthreads();
  }

  f16* dst = aggP + (size_t)kh * (4L * NN * G_IN) +
             ((size_t)t * NN + m0) * G_IN + n0;
#pragma unroll
  for (int m = 0; m < 2; ++m)
#pragma unroll
    for (int n = 0; n < 6; ++n)
#pragma unroll
      for (int q = 0; q < 4; ++q)
        dst[(size_t)(wm * 32 + m * 16 + hi * 4 + q) * G_IN + wn * 96 +
            n * 16 + cl] = (f16)acc[m][n][q];
}

// ---------------------------------------------------------------------------
// gnn_l2: g16[r] = l2norm(relu((sum of 4 aggP partials) @ Wgnn + b))
// ---------------------------------------------------------------------------
__global__ __launch_bounds__(256) void gnn_l2(
    const f16* __restrict__ aggP, const f16* __restrict__ WgnnT,
    const float* __restrict__ bgnn, f16* __restrict__ g16) {
  __shared__ alignas(16) f16 As[32 * 64];
  __shared__ alignas(16) f16 Bs[256 * 64];
  __shared__ float red[4][32];
  const int tid = threadIdx.x;
  const int lane = tid & 63, wid = tid >> 6;
  const int m0 = blockIdx.x * 32;
  const int l8 = lane >> 3;
  const int lx = ((lane & 7) ^ l8) * 8;
  const int sw = (lane & 7) * 8;
  const int cl = lane & 15, hi = lane >> 4;
  const long PS = 4L * NN * G_IN;

  f32x4 acc[2][4];
#pragma unroll
  for (int m = 0; m < 2; ++m)
#pragma unroll
    for (int n = 0; n < 4; ++n) acc[m][n] = (f32x4){0.f, 0.f, 0.f, 0.f};

  const int ar = tid >> 3;
  const int acw = ((tid & 7) ^ (ar & 7)) * 8;

  for (int k0 = 0; k0 < G_IN; k0 += 64) {
    size_t gi = (size_t)(m0 + ar) * G_IN + k0 + ((tid & 7) * 8);
    f16x8 a0 = *(const f16x8*)(aggP + gi);
    f16x8 a1 = *(const f16x8*)(aggP + PS + gi);
    f16x8 a2 = *(const f16x8*)(aggP + 2 * PS + gi);
    f16x8 a3 = *(const f16x8*)(aggP + 3 * PS + gi);
    f16x8 s;
#pragma unroll
    for (int e = 0; e < 8; ++e)
      s[e] = (f16)((float)a0[e] + (float)a1[e] + (float)a2[e] + (float)a3[e]);
    *(f16x8*)&As[ar * 64 + acw] = s;
#pragma unroll
    for (int i = 0; i < 8; ++i) {
      int rn = wid * 64 + i * 8;
      gld_lds16(WgnnT + (size_t)(rn + l8) * G_IN + k0 + lx, &Bs[rn * 64]);
    }
    __syncthreads();
#pragma unroll
    for (int ks = 0; ks < 2; ++ks) {
      f16x8 af[2], bf[4];
#pragma unroll
      for (int m = 0; m < 2; ++m)
        af[m] = *(const f16x8*)&As[((m * 16 + cl) * 64 + ks * 32 + hi * 8) ^ sw];
#pragma unroll
      for (int n = 0; n < 4; ++n)
        bf[n] = *(const f16x8*)&Bs[((wid * 64 + n * 16 + cl) * 64 + ks * 32 +
                                    hi * 8) ^ sw];
#pragma unroll
      for (int m = 0; m < 2; ++m)
#pragma unroll
        for (int n = 0; n < 4; ++n)
          acc[m][n] = __builtin_amdgcn_mfma_f32_16x16x32_f16(af[m], bf[n],
                                                             acc[m][n], 0, 0, 0);
    }
    __syncthreads();
  }

#pragma unroll
  for (int m = 0; m < 2; ++m)
#pragma unroll
    for (int n = 0; n < 4; ++n) {
      float bv = bgnn[wid * 64 + n * 16 + cl];
#pragma unroll
      for (int q = 0; q < 4; ++q)
        acc[m][n][q] = fmaxf(acc[m][n][q] + bv, 0.f);
    }
#pragma unroll
  for (int m = 0; m < 2; ++m)
#pragma unroll
    for (int q = 0; q < 4; ++q) {
      float ss = 0.f;
#pragma unroll
      for (int n = 0; n < 4; ++n) ss += acc[m][n][q] * acc[m][n][q];
#pragma unroll
      for (int msk = 1; msk < 16; msk <<= 1) ss += __shfl_xor(ss, msk);
      if (cl == 0) red[wid][m * 16 + hi * 4 + q] = ss;
    }
  __syncthreads();
#pragma unroll
  for (int m = 0; m < 2; ++m)
#pragma unroll
    for (int q = 0; q < 4; ++q) {
      int row = m * 16 + hi * 4 + q;
      float tot = red[0][row] + red[1][row] + red[2][row] + red[3][row];
      float inv = 1.f / fmaxf(sqrtf(tot), 1e-12f);
#pragma unroll
      for (int n = 0; n < 4; ++n)
        g16[(size_t)(m0 + row) * 256 + wid * 64 + n * 16 + cl] =
            (f16)(acc[m][n][q] * inv);
    }
}

// --- sum 4 K-split partials -> h f32 + f16 -----------------------------------
__global__ __launch_bounds__(256) void hsum4(const float* __restrict__ hP,
                                             float* __restrict__ hf,
                                             f16* __restrict__ h16) {
  long i = ((long)blockIdx.x * 256 + threadIdx.x) * 4;
  float4 a = *(const float4*)(hP + i);
  float4 b = *(const float4*)(hP + 524288 + i);
  float4 c = *(const float4*)(hP + 1048576 + i);
  float4 d = *(const float4*)(hP + 1572864 + i);
  float4 s = {a.x + b.x + c.x + d.x, a.y + b.y + c.y + d.y,
              a.z + b.z + c.z + d.z, a.w + b.w + c.w + d.w};
  *(float4*)(hf + i) = s;
  f16x4 o = {(f16)s.x, (f16)s.y, (f16)s.z, (f16)s.w};
  *(f16x4*)(h16 + i) = o;
}

// --- t=0 shortcut: rnn0 = sigmoid(Xg_u+bg)*tanh(Xc+bc), transposed ----------
__global__ __launch_bounds__(256) void rnn0_t(const f16* __restrict__ Xgc,
                                              const float* __restrict__ bg,
                                              const float* __restrict__ bc,
                                              f16* __restrict__ rnnT) {
  __shared__ float tile[32][33];
  int n0 = blockIdx.x * 32, k0 = blockIdx.y * 32;
  int tx = threadIdx.x & 31, ty = threadIdx.x >> 5;
#pragma unroll
  for (int i = 0; i < 32; i += 8) {
    int n = n0 + ty + i, k = k0 + tx;
    float u = 1.f / (1.f + __expf(-((float)Xgc[(size_t)n * 768 + 256 + k] +
                                    bg[256 + k])));
    float c = tanhf((float)Xgc[(size_t)n * 768 + 512 + k] + bc[k]);
    tile[ty + i][tx] = u * c;
  }
  __syncthreads();
#pragma unroll
  for (int i = 0; i < 32; i += 8)
    rnnT[(size_t)(k0 + ty + i) * NN + n0 + tx] = (f16)tile[tx][ty + i];
}

// ---------------------------------------------------------------------------
// fused_gru: one kernel per scan step (t>=1).
// Block = 32 rows.  Phase 1: gates = sigmoid(h@Wgh + Xg + bg) -> rh (LDS f16),
// u (LDS f32).  Phase 2: c = tanh(rh@Wch + Xc + bc); rnn = (1-u)h + u*c ->
// transposed write to rnnT.  A/B fragments read direct from L2 (no staging).
// ---------------------------------------------------------------------------
__global__ __launch_bounds__(256) void fused_gru(
    const f16* __restrict__ h16, const float* __restrict__ hf,
    const f16* __restrict__ Xgc, const f16* __restrict__ WghT,
    const f16* __restrict__ WchT, const float* __restrict__ bg,
    const float* __restrict__ bc, f16* __restrict__ rnnT) {
  __shared__ alignas(16) f16 rh_s[32 * 264];
  __shared__ float u_s[32 * 260];
  __shared__ alignas(16) f16 tileT[256 * 40];
  const int tid = threadIdx.x;
  const int lane = tid & 63, wid = tid >> 6;
  const int cl = lane & 15, hi = lane >> 4;
  const int r0 = blockIdx.x * 32;

  // --- phase 1: gates GEMM [32 x 512], K=256 --------------------------------
  const int wc0 = wid * 128;
  f32x4 acc[2][8];
#pragma unroll
  for (int m = 0; m < 2; ++m)
#pragma unroll
    for (int n = 0; n < 8; ++n) acc[m][n] = (f32x4){0.f, 0.f, 0.f, 0.f};
  for (int k0 = 0; k0 < 256; k0 += 64) {
    f16x8 af[2][2], bf[8][2];
#pragma unroll
    for (int m = 0; m < 2; ++m)
#pragma unroll
      for (int ks = 0; ks < 2; ++ks)
        af[m][ks] = *(const f16x8*)(h16 + (size_t)(r0 + m * 16 + cl) * 256 +
                                    k0 + ks * 32 + hi * 8);
#pragma unroll
    for (int n = 0; n < 8; ++n)
#pragma unroll
      for (int ks = 0; ks < 2; ++ks)
        bf[n][ks] = *(const f16x8*)(WghT + (size_t)(wc0 + n * 16 + cl) * 256 +
                                    k0 + ks * 32 + hi * 8);
#pragma unroll
    for (int ks = 0; ks < 2; ++ks)
#pragma unroll
      for (int m = 0; m < 2; ++m)
#pragma unroll
        for (int n = 0; n < 8; ++n)
          acc[m][n] = __builtin_amdgcn_mfma_f32_16x16x32_f16(af[m][ks],
                                                             bf[n][ks],
                                                             acc[m][n], 0, 0, 0);
  }
#pragma unroll
  for (int m = 0; m < 2; ++m) {
#pragma unroll
    for (int n = 0; n < 8; ++n) {
      int cc = wc0 + n * 16 + cl;
      float bgv = bg[cc];
#pragma unroll
      for (int q = 0; q < 4; ++q) {
        int rl = m * 16 + hi * 4 + q;
        size_t r = r0 + rl;
        float v = acc[m][n][q] + bgv + (float)Xgc[r * 768 + cc];
        float sv = 1.f / (1.f + __expf(-v));
        if (wc0 < 256)
          rh_s[rl * 264 + cc] = (f16)(sv * hf[r * 256 + cc]);
        else
          u_s[rl * 260 + cc - 256] = sv;
      }
    }
  }
  __syncthreads();

  // --- phase 2: cand GEMM [32 x 256], K=256, A from LDS ----------------------
  const int wc2 = wid * 64;
  f32x4 acc2[2][4];
#pragma unroll
  for (int m = 0; m < 2; ++m)
#pragma unroll
    for (int n = 0; n < 4; ++n) acc2[m][n] = (f32x4){0.f, 0.f, 0.f, 0.f};
  for (int k0 = 0; k0 < 256; k0 += 64) {
    f16x8 af[2][2], bf[4][2];
#pragma unroll
    for (int m = 0; m < 2; ++m)
#pragma unroll
      for (int ks = 0; ks < 2; ++ks)
        af[m][ks] = *(const f16x8*)&rh_s[(m * 16 + cl) * 264 + k0 + ks * 32 +
                                         hi * 8];
#pragma unroll
    for (int n = 0; n < 4; ++n)
#pragma unroll
      for (int ks = 0; ks < 2; ++ks)
        bf[n][ks] = *(const f16x8*)(WchT + (size_t)(wc2 + n * 16 + cl) * 256 +
                                    k0 + ks * 32 + hi * 8);
#pragma unroll
    for (int ks = 0; ks < 2; ++ks)
#pragma unroll
      for (int m = 0; m < 2; ++m)
#pragma unroll
        for (int n = 0; n < 4; ++n)
          acc2[m][n] = __builtin_amdgcn_mfma_f32_16x16x32_f16(af[m][ks],
                                                              bf[n][ks],
                                                              acc2[m][n], 0, 0, 0);
  }
#pragma unroll
  for (int m = 0; m < 2; ++m) {
#pragma unroll
    for (int n = 0; n < 4; ++n) {
      int cc = wc2 + n * 16 + cl;
      float bcv = bc[cc];
#pragma unroll
      for (int q = 0; q < 4; ++q) {
        int rl = m * 16 + hi * 4 + q;
        size_t r = r0 + rl;
        float cv = fast_tanh(acc2[m][n][q] + bcv +
                             (float)Xgc[r * 768 + 512 + cc]);
        float u = u_s[rl * 260 + cc];
        float hv = hf[r * 256 + cc];
        tileT[cc * 40 + rl] = (f16)((1.f - u) * hv + u * cv);
      }
    }
  }
  __syncthreads();
  // write out: thread tid handles column cc = tid
  {
    int cc = tid;
    const f16x8* src = (const f16x8*)&tileT[cc * 40];
    f16x8* dst = (f16x8*)&rnnT[(size_t)cc * NN + r0];
    dst[0] = src[0];
    dst[1] = src[1];
    dst[2] = src[2];
    dst[3] = src[3];
  }
}

// ---------------------------------------------------------------------------
// Fused P/Q/decode
// ---------------------------------------------------------------------------
__global__ __launch_bounds__(256) void pq_decode(
    const f16* __restrict__ emb, const f16* __restrict__ scal,
    const float* __restrict__ sq, float* __restrict__ out) {
  __shared__ alignas(16) f16 EA[128 * 64], EB[128 * 64], SA[128 * 64],
      SB[128 * 64];
  const int tid = threadIdx.x;
  const int lane = tid & 63, wid = tid >> 6;
  const int wm = wid >> 1, wn = wid & 1;
  const int row0 = blockIdx.y * 128, col0 = blockIdx.x * 128;
  const int l8 = lane >> 3;
  const int lx = ((lane & 7) ^ l8) * 8;
  const int sw = (lane & 7) * 8;
#pragma unroll
  for (int i = 0; i < 2; ++i) {
    int r = wid * 16 + i * 8;
    gld_lds16(emb + (size_t)(row0 + r + l8) * 64 + lx, &EA[r * 64]);
    gld_lds16(emb + (size_t)(col0 + r + l8) * 64 + lx, &EB[r * 64]);
    gld_lds16(scal + (size_t)(row0 + r + l8) * 64 + lx, &SA[r * 64]);
    gld_lds16(scal + (size_t)(col0 + r + l8) * 64 + lx, &SB[r * 64]);
    int r2 = r + 64;
    gld_lds16(emb + (size_t)(row0 + r2 + l8) * 64 + lx, &EA[r2 * 64]);
    gld_lds16(emb + (size_t)(col0 + r2 + l8) * 64 + lx, &EB[r2 * 64]);
    gld_lds16(scal + (size_t)(row0 + r2 + l8) * 64 + lx, &SA[r2 * 64]);
    gld_lds16(scal + (size_t)(col0 + r2 + l8) * 64 + lx, &SB[r2 * 64]);
  }
  __syncthreads();
  f32x4 accP[4][4], accQ[4][4];
#pragma unroll
  for (int m = 0; m < 4; ++m)
#pragma unroll
    for (int n = 0; n < 4; ++n) {
      accP[m][n] = (f32x4){0.f, 0.f, 0.f, 0.f};
      accQ[m][n] = (f32x4){0.f, 0.f, 0.f, 0.f};
    }
#pragma unroll
  for (int ks = 0; ks < 2; ++ks) {
    f16x8 af[4], bf[4];
#pragma unroll
    for (int m = 0; m < 4; ++m)
      af[m] = *(const f16x8*)&EA[((wm * 64 + m * 16 + (lane & 15)) * 64 +
                                  ks * 32 + (lane >> 4) * 8) ^ sw];
#pragma unroll
    for (int n = 0; n < 4; ++n)
      bf[n] = *(const f16x8*)&EB[((wn * 64 + n * 16 + (lane & 15)) * 64 +
                                  ks * 32 + (lane >> 4) * 8) ^ sw];
#pragma unroll
    for (int m = 0; m < 4; ++m)
#pragma unroll
      for (int n = 0; n < 4; ++n)
        accP[m][n] = __builtin_amdgcn_mfma_f32_16x16x32_f16(af[m], bf[n],
                                                            accP[m][n], 0, 0, 0);
#pragma unroll
    for (int m = 0; m < 4; ++m)
      af[m] = *(const f16x8*)&SA[((wm * 64 + m * 16 + (lane & 15)) * 64 +
                                  ks * 32 + (lane >> 4) * 8) ^ sw];
#pragma unroll
    for (int n = 0; n < 4; ++n)
      bf[n] = *(const f16x8*)&SB[((wn * 64 + n * 16 + (lane & 15)) * 64 +
                                  ks * 32 + (lane >> 4) * 8) ^ sw];
#pragma unroll
    for (int m = 0; m < 4; ++m)
#pragma unroll
      for (int n = 0; n < 4; ++n)
        accQ[m][n] = __builtin_amdgcn_mfma_f32_16x16x32_f16(af[m], bf[n],
                                                            accQ[m][n], 0, 0, 0);
  }
  const int cl = lane & 15, rh4 = (lane >> 4) * 4;
#pragma unroll
  for (int m = 0; m < 4; ++m) {
#pragma unroll
    for (int n = 0; n < 4; ++n) {
      int c = col0 + wn * 64 + n * 16 + cl;
      float sqc = sq[c];
#pragma unroll
      for (int q = 0; q < 4; ++q) {
        size_t r = row0 + wm * 64 + m * 16 + rh4 + q;
        float dist = -(sq[r] + sqc - 2.f * accP[m][n][q]);
        out[r * NN + c] = 1.f + tanhf(dist * accQ[m][n][q]);
      }
    }
  }
}

// --- fused transpose+convert of the weight matrices --------------------------
struct MT {
  const float* src[11];
  f16* dst[11];
  int K[11], N[11], st[11], ts[12];
};
__global__ __launch_bounds__(256) void multi_transp(MT mt) {
  __shared__ float tile[32][33];
  int b = blockIdx.x, w = 0;
  while (b >= mt.ts[w + 1]) ++w;
  int lt = b - mt.ts[w];
  int K = mt.K[w], N = mt.N[w];
  int tk = lt % (K >> 5), tn = lt / (K >> 5);
  int k0 = tk * 32, n0 = tn * 32;
  int tx = threadIdx.x & 31, ty = threadIdx.x >> 5;
  const float* src = mt.src[w];
#pragma unroll
  for (int i = 0; i < 32; i += 8)
    tile[ty + i][tx] = src[(size_t)(k0 + ty + i) * N + n0 + tx];
  __syncthreads();
  f16* dst = mt.dst[w];
  int st = mt.st[w];
#pragma unroll
  for (int i = 0; i < 32; i += 8)
    dst[(size_t)(n0 + ty + i) * st + k0 + tx] = (f16)tile[tx][ty + i];
}

// --- fused edmT builder: transpose fem16 (f16) + noise (f32) -----------------
__global__ __launch_bounds__(256) void edm_t(const f16* __restrict__ fem16,
                                             const float* __restrict__ noise,
                                             f16* __restrict__ edmT) {
  __shared__ float tile[32][33];
  int bx = blockIdx.x, r0 = blockIdx.y * 32, t = blockIdx.z;
  int tx = threadIdx.x & 31, ty = threadIdx.x >> 5;
  f16* dstT = edmT + (size_t)t * G_IN * NN;
  if (bx < 8) {
    int c0 = bx * 32;
    const f16* src = fem16 + (size_t)t * NN * HF;
#pragma unroll
    for (int i = 0; i < 32; i += 8)
      tile[ty + i][tx] = (float)src[(size_t)(r0 + ty + i) * HF + c0 + tx];
    __syncthreads();
#pragma unroll
    for (int i = 0; i < 32; i += 8)
      dstT[(size_t)(c0 + ty + i) * NN + r0 + tx] = (f16)tile[tx][ty + i];
  } else {
    int c0 = (bx - 8) * 32;
    const float* src = noise + (size_t)t * NN * DZ;
#pragma unroll
    for (int i = 0; i < 32; i += 8)
      tile[ty + i][tx] = src[(size_t)(r0 + ty + i) * DZ + c0 + tx];
    __syncthreads();
#pragma unroll
    for (int i = 0; i < 32; i += 8)
      dstT[(size_t)(HF + c0 + ty + i) * NN + r0 + tx] = (f16)tile[tx][ty + i];
  }
}

// --- f32 -> fp16 convert -----------------------------------------------------
__global__ __launch_bounds__(256) void cvt_h(const float* __restrict__ in,
                                             f16* __restrict__ out) {
  long i = ((long)blockIdx.x * 256 + threadIdx.x) * 4;
  float4 v = *(const float4*)(in + i);
  f16x4 o = {(f16)v.x, (f16)v.y, (f16)v.z, (f16)v.w};
  *(f16x4*)(out + i) = o;
}

// --- row softmax + mix with align -> fp16 ------------------------------------
__global__ __launch_bounds__(256) void softmax_mix(
    const float* __restrict__ S, const float* __restrict__ Al,
    const float* __restrict__ lam_ptr, f16* __restrict__ Mh) {
  const int tid = threadIdx.x;
  const float4* s4 = (const float4*)(S + (long)blockIdx.x * 2048);
  float4 a = s4[tid], b = s4[tid + 256];
  float m = fmaxf(fmaxf(fmaxf(a.x, a.y), fmaxf(a.z, a.w)),
                  fmaxf(fmaxf(b.x, b.y), fmaxf(b.z, b.w)));
  __shared__ float red[4];
  float w = wave_max(m);
  if ((tid & 63) == 0) red[tid >> 6] = w;
  __syncthreads();
  m = fmaxf(fmaxf(red[0], red[1]), fmaxf(red[2], red[3]));
  __syncthreads();
  a.x = __expf(a.x - m); a.y = __expf(a.y - m);
  a.z = __expf(a.z - m); a.w = __expf(a.w - m);
  b.x = __expf(b.x - m); b.y = __expf(b.y - m);
  b.z = __expf(b.z - m); b.w = __expf(b.w - m);
  float s = a.x + a.y + a.z + a.w + b.x + b.y + b.z + b.w;
  w = wave_sum(s);
  if ((tid & 63) == 0) red[tid >> 6] = w;
  __syncthreads();
  float inv = 1.f / (red[0] + red[1] + red[2] + red[3]);
  float lam = lam_ptr[0], oml = 1.f - lam;
  const float4* al4 = (const float4*)(Al + (long)blockIdx.x * 2048);
  float4 x = al4[tid], y = al4[tid + 256];
  f16x4 o0 = {(f16)(lam * x.x + oml * a.x * inv),
              (f16)(lam * x.y + oml * a.y * inv),
              (f16)(lam * x.z + oml * a.z * inv),
              (f16)(lam * x.w + oml * a.w * inv)};
  f16x4 o1 = {(f16)(lam * y.x + oml * b.x * inv),
              (f16)(lam * y.y + oml * b.y * inv),
              (f16)(lam * y.z + oml * b.z * inv),
              (f16)(lam * y.w + oml * b.w * inv)};
  f16x4* out4 = (f16x4*)(Mh + (long)blockIdx.x * 2048);
  out4[tid] = o0;
  out4[tid + 256] = o1;
}

// --- column L2 norms of emb0 [N,64] ------------------------------------------
__global__ __launch_bounds__(256) void col_l2norm64(
    const float* __restrict__ x, float* __restrict__ cn) {
  int c = blockIdx.x;
  float ss = 0.f;
  for (int r = threadIdx.x; r < NN; r += 256) {
    float v = x[(long)r * 64 + c];
    ss += v * v;
  }
  __shared__ float red[4];
  float w = wave_sum(ss);
  if ((threadIdx.x & 63) == 0) red[threadIdx.x >> 6] = w;
  __syncthreads();
  if (threadIdx.x == 0)
    cn[c] = fmaxf(sqrtf(red[0] + red[1] + red[2] + red[3]), 1e-12f);
}

// --- emb16 = emb0/cn ; sq[i] = row sumsq -------------------------------------
__global__ void norm_sq64h(const float* __restrict__ x,
                           const float* __restrict__ cn,
                           f16* __restrict__ emb16, float* __restrict__ sq) {
  int i = blockIdx.x, j = threadIdx.x;
  float e = x[(long)i * 64 + j] / cn[j];
  emb16[(long)i * 64 + j] = (f16)e;
  float s = wave_sum(e * e);
  if (j == 0) sq[i] = s;
}

// ---------------------------------------------------------------------------
extern "C" void kernel_launch(void* const* d_in, const int* in_sizes, int n_in,
                              void* d_out, int out_size, void* d_ws,
                              size_t ws_size, hipStream_t stream) {
  (void)in_sizes; (void)n_in; (void)out_size; (void)ws_size;
  const float* sup    = (const float*)d_in[0];
  const float* feat   = (const float*)d_in[1];
  const float* noise  = (const float*)d_in[2];
  const float* align  = (const float*)d_in[3];
  const float* lambd  = (const float*)d_in[4];
  const float* W_fem  = (const float*)d_in[5];
  const float* b_fem  = (const float*)d_in[6];
  const float* W_gnn  = (const float*)d_in[7];
  const float* b_gnn  = (const float*)d_in[8];
  const float* Wg_x   = (const float*)d_in[9];
  const float* Wg_h   = (const float*)d_in[10];
  const float* bg     = (const float*)d_in[11];
  const float* Wc_x   = (const float*)d_in[12];
  const float* Wc_h   = (const float*)d_in[13];
  const float* bc     = (const float*)d_in[14];
  const float* W_att  = (const float*)d_in[15];
  const float* b_att  = (const float*)d_in[16];
  const float* W_emb1 = (const float*)d_in[17];
  const float* b_emb1 = (const float*)d_in[18];
  const float* W_emb2 = (const float*)d_in[19];
  const float* b_emb2 = (const float*)d_in[20];
  const float* W_scal1= (const float*)d_in[21];
  const float* b_scal1= (const float*)d_in[22];
  const float* W_scal2= (const float*)d_in[23];
  const float* b_scal2= (const float*)d_in[24];

  char* wsb = (char*)d_ws;
  size_t po = 0;
  auto P = [&](size_t bytes) {
    size_t r = po;
    po += (bytes + 255) & ~(size_t)255;
    return r;
  };
  f16* fem16  = (f16*)(wsb + P(5L * NN * HF * 2));
  f16* fm16   = (f16*)(wsb + P(5L * NN * HH * 2));
  f16* g16    = (f16*)(wsb + P(4L * NN * HH * 2));
  f16* WT     = (f16*)(wsb + P(884736L * 2));
  f16* Xgc16  = (f16*)(wsb + P(4L * NN * 768 * 2));
  float* hA   = (float*)(wsb + P((long)NN * HH * 4));
  float* hB   = (float*)(wsb + P((long)NN * HH * 4));
  f16* h16A   = (f16*)(wsb + P((long)NN * HH * 2));
  f16* h16B   = (f16*)(wsb + P((long)NN * HH * 2));
  f16* rnnT16 = (f16*)(wsb + P((long)NN * HH * 2));
  float* hP   = (float*)(wsb + P(4L * NN * HH * 4));
  f16* M16_2  = (f16*)(wsb + P(2L * NN * NN * 2));
  f16* e1s1   = (f16*)(wsb + P((long)NN * 512 * 2));
  float* embscF = (float*)(wsb + P(2L * NN * E2D * 4));
  f16* embsc16  = (f16*)(wsb + P(2L * NN * E2D * 2));
  f16* emb16  = (f16*)(wsb + P((long)NN * E2D * 2));
  float* cn   = (float*)(wsb + P(64 * 4));
  float* sq   = (float*)(wsb + P(NN * 4));
  // arena: feat16 | edmT | aggP live early; Sbuf2 aliases after gnn_l2
  size_t arena = P(34078720);
  f16* feat16 = (f16*)(wsb + arena);
  f16* edmT   = (f16*)(wsb + arena + 2621440);
  f16* aggP   = (f16*)(wsb + arena + 8912896);
  float* Sbuf2 = (float*)(wsb + arena);

  // --- weight transpose table -------------------------------------------------
  f16* W_femT  = WT;                       // 256x128
  f16* W_gnnT  = W_femT + 32768;           // 256x384
  f16* WgxcT   = W_gnnT + 98304;           // 768x256 ([Wgx^T; Wcx^T])
  f16* WghT    = WgxcT + 196608;           // 512x256
  f16* WchT    = WghT + 131072;            // 256x256
  f16* W_attT  = WchT + 65536;             // 256x256
  f16* We1s1T  = W_attT + 65536;           // 512x512 ([Wemb1^T; Wscal1^T])
  f16* Wemb2T  = We1s1T + 262144;          // 64x256
  f16* Wscal2T = Wemb2T + 16384;           // 64x256 (adjacent: zB=16384)

  MT mt;
  const float* wsrc[11] = {W_fem, W_gnn, Wg_x, Wc_x, Wg_h, Wc_h,
                           W_att, W_emb1, W_scal1, W_emb2, W_scal2};
  f16* wdst[11] = {W_femT, W_gnnT, WgxcT, WgxcT + 512 * 256, WghT, WchT,
                   W_attT, We1s1T, We1s1T + 256 * 512, Wemb2T, Wscal2T};
  const int wK[11]  = {128, 384, 256, 256, 256, 256, 256, 512, 512, 256, 256};
  const int wNd[11] = {256, 256, 512, 256, 512, 256, 256, 256, 256, 64, 64};
  const int wSt[11] = {128, 384, 256, 256, 256, 256, 256, 512, 512, 256, 256};
  int tcum = 0;
  for (int i = 0; i < 11; ++i) {
    mt.src[i] = wsrc[i];
    mt.dst[i] = wdst[i];
    mt.K[i] = wK[i];
    mt.N[i] = wNd[i];
    mt.st[i] = wSt[i];
    mt.ts[i] = tcum;
    tcum += (wK[i] >> 5) * (wNd[i] >> 5);
  }
  mt.ts[11] = tcum;

  const f16* NH = nullptr;
  float* NF = nullptr;
  f16* NHm = nullptr;

  multi_transp<<<tcum, 256, 0, stream>>>(mt);
  cvt_h<<<(5L * NN * F_IN) / 1024, 256, 0, stream>>>(feat, feat16);

  // FEM: fem16 = relu(feat @ W_fem + b)
  hgemm<1, 64, 1><<<dim3(4, 80, 1), 256, 0, stream>>>(
      feat16, NH, W_femT, b_fem, nullptr, NF, fem16,
      128, 0, 128, 128, 256, 128, 0, 0, 0);

  // edmT
  edm_t<<<dim3(12, 64, 4), 256, 0, stream>>>(fem16, noise, edmT);

  // sup path: 1024-block partial aggregation + fused gnn/l2norm
  sup_agg<<<dim3(32, 2, 16), 256, 0, stream>>>(sup, edmT, aggP);
  gnn_l2<<<256, 256, 0, stream>>>(aggP, W_gnnT, b_gnn, g16);

  // fm16 = fem @ W_att + b
  hgemm<0, 64, 1><<<dim3(4, 80, 1), 256, 0, stream>>>(
      fem16, NH, W_attT, b_att, nullptr, NF, fm16,
      256, 0, 256, 256, 256, 256, 0, 0, 0);

  // Xgc = g16 @ [Wgx | Wcx]  -> [8192 x 768] f16 pre-activations
  hgemm<0, 64, 1><<<dim3(12, 64, 1), 256, 0, stream>>>(
      g16, NH, WgxcT, nullptr, nullptr, NF, Xgc16,
      256, 0, 256, 256, 768, 256, 0, 0, 0);

  float* hs[2] = {hA, hB};
  f16* h16s[2] = {h16A, h16B};

  for (int p = 0; p < 2; ++p) {
    // S pair: S[z] = fm[2p+z+1] @ fm[2p+z]^T
    hgemm<0, 128, 0><<<dim3(16, 16, 2), 256, 0, stream>>>(
        fm16 + (size_t)(2 * p + 1) * NN * HH, NH,
        fm16 + (size_t)(2 * p) * NN * HH, nullptr, nullptr, Sbuf2, NHm,
        256, 0, 256, 256, 2048, 256, (long)NN * HH, (long)NN * HH,
        (long)NN * NN);
    softmax_mix<<<2 * NN, 256, 0, stream>>>(
        Sbuf2, align + (size_t)(2 * p) * NN * NN, lambd, M16_2);

    for (int tl = 0; tl < 2; ++tl) {
      int t = 2 * p + tl;
      if (t == 0) {
        rnn0_t<<<dim3(64, 8, 1), 256, 0, stream>>>(Xgc16, bg, bc, rnnT16);
      } else {
        fused_gru<<<64, 256, 0, stream>>>(
            h16s[(t - 1) & 1], hs[(t - 1) & 1],
            Xgc16 + (size_t)t * NN * 768, WghT, WchT, bg, bc, rnnT16);
      }
      // h_{t} partials = M16 @ rnn (K-split x4)
      hgemm<0, 64, 0><<<dim3(4, 16, 4), 256, 0, stream>>>(
          M16_2 + (size_t)(t & 1) * NN * NN, NH, rnnT16, nullptr, nullptr,
          hP, NHm, 2048, 0, 2048, 2048, 256, 512, 512, 512, 524288);
      hsum4<<<512, 256, 0, stream>>>(hP, hs[t & 1], h16s[t & 1]);
    }
  }

  // --- EAM tail ---------------------------------------------------------------
  const f16* h16fin = h16s[1];  // t=3 -> slot 1
  hgemm<6, 64, 1><<<dim3(8, 16, 1), 256, 0, stream>>>(
      h16fin, fem16 + 4L * NN * HF, We1s1T, b_emb1, b_scal1, NF, e1s1,
      256, 256, 256, 512, 512, 512, 0, 0, 0);
  hgemm<5, 64, 2><<<dim3(1, 16, 2), 256, 0, stream>>>(
      e1s1, NH, Wemb2T, b_emb2, b_scal2, embscF, embsc16,
      512, 0, 512, 256, 64, 256, 256, 16384, (long)NN * E2D);
  col_l2norm64<<<64, 256, 0, stream>>>(embscF, cn);
  norm_sq64h<<<NN, 64, 0, stream>>>(embscF, cn, emb16, sq);

  pq_decode<<<dim3(16, 16, 1), 256, 0, stream>>>(
      emb16, embsc16 + (size_t)NN * E2D, sq, (float*)d_out);
}

// Round 7
// 317.014 us; speedup vs baseline: 1.2432x; 1.2432x over previous
//
#include <hip/hip_runtime.h>
#include <math.h>

// ---------------------------------------------------------------------------
// GenNet_tanh forward, round 7:
//  - gru_step: lean 128-block GRU (gates+rh+cand+rnn+transpose), reads hP
//    partials directly (kills 3 hsum4 dispatches), B-frags direct from L2
//  - sup_agg v4 kept (64x192, 1024 blocks)
// ---------------------------------------------------------------------------

#define T_WIN 4
#define NN 2048
#define F_IN 128
#define HF 256
#define HH 256
#define DZ 128
#define G_IN 384
#define EIN 512
#define E1D 256
#define E2D 64

typedef _Float16 f16;
typedef _Float16 f16x8 __attribute__((ext_vector_type(8)));
typedef _Float16 f16x4 __attribute__((ext_vector_type(4)));
typedef float f32x4 __attribute__((ext_vector_type(4)));

__device__ __forceinline__ float wave_sum(float v) {
#pragma unroll
  for (int o = 32; o > 0; o >>= 1) v += __shfl_down(v, o);
  return v;
}
__device__ __forceinline__ float wave_max(float v) {
#pragma unroll
  for (int o = 32; o > 0; o >>= 1) v = fmaxf(v, __shfl_down(v, o));
  return v;
}

__device__ __forceinline__ void gld_lds16(const void* g, void* l) {
  __builtin_amdgcn_global_load_lds(
      (const __attribute__((address_space(1))) unsigned int*)g,
      (__attribute__((address_space(3))) unsigned int*)l, 16, 0, 0);
}

// ---------------------------------------------------------------------------
// fp16 MFMA GEMM, 128 x BN tile, BK=64, 256 threads (4 waves 2x2).
// A: [.,lda] row-major; dual-source: k<kspl from A, else A2 (lda2).
// BT: [N,ldb] row-major.  C index: r*ldc + cc.  grid.z advances by zA/zB/zC.
// EPI: 0 none, 1 relu, 5 z-sel tanh/sig, 6 col-sel.  WOUT: 0 f32, 1 f16, 2 both.
// ---------------------------------------------------------------------------
template <int EPI, int BN, int WOUT>
__global__ __launch_bounds__(256) void hgemm(
    const f16* __restrict__ A, const f16* __restrict__ A2,
    const f16* __restrict__ BT, const float* __restrict__ bias,
    const float* __restrict__ bias2, float* __restrict__ Cf,
    f16* __restrict__ Ch, int lda, int lda2, int kspl, int ldb,
    int ldc, int K, long zA, long zB, long zC) {
  constexpr int WN = BN / 2;
  constexpr int FN = WN / 16;
  constexpr int BI = BN / 32;
  __shared__ alignas(16) f16 As[128 * 64];
  __shared__ alignas(16) f16 Bs[BN * 64];
  const int tid = threadIdx.x;
  const int lane = tid & 63, wid = tid >> 6;
  const int wm = wid >> 1, wn = wid & 1;
  const int row0 = blockIdx.y * 128, col0 = blockIdx.x * BN;
  const long zb = blockIdx.z;
  A += zb * zA;
  BT += zb * zB;
  const int l8 = lane >> 3;
  const int lx = ((lane & 7) ^ l8) * 8;  // pre-swizzled source chunk
  const int sw = (lane & 7) * 8;         // frag-read XOR

  f32x4 acc[4][FN];
#pragma unroll
  for (int m = 0; m < 4; ++m)
#pragma unroll
    for (int n = 0; n < FN; ++n) acc[m][n] = (f32x4){0.f, 0.f, 0.f, 0.f};

  for (int k0 = 0; k0 < K; k0 += 64) {
#pragma unroll
    for (int i = 0; i < 4; ++i) {
      int r = wid * 32 + i * 8;
      const f16* src =
          (k0 < kspl) ? A + (size_t)(row0 + r + l8) * lda + k0 + lx
                      : A2 + (size_t)(row0 + r + l8) * lda2 + (k0 - kspl) + lx;
      gld_lds16(src, &As[r * 64]);
    }
#pragma unroll
    for (int i = 0; i < BI; ++i) {
      int r = wid * (BN / 4) + i * 8;
      gld_lds16(BT + (size_t)(col0 + r + l8) * ldb + k0 + lx, &Bs[r * 64]);
    }
    __syncthreads();
#pragma unroll
    for (int ks = 0; ks < 2; ++ks) {
      f16x8 af[4], bf[FN];
#pragma unroll
      for (int m = 0; m < 4; ++m)
        af[m] = *(const f16x8*)&As[((wm * 64 + m * 16 + (lane & 15)) * 64 +
                                    ks * 32 + (lane >> 4) * 8) ^ sw];
#pragma unroll
      for (int n = 0; n < FN; ++n)
        bf[n] = *(const f16x8*)&Bs[((wn * WN + n * 16 + (lane & 15)) * 64 +
                                    ks * 32 + (lane >> 4) * 8) ^ sw];
#pragma unroll
      for (int m = 0; m < 4; ++m)
#pragma unroll
        for (int n = 0; n < FN; ++n)
          acc[m][n] = __builtin_amdgcn_mfma_f32_16x16x32_f16(af[m], bf[n],
                                                             acc[m][n], 0, 0, 0);
    }
    __syncthreads();
  }

  const int cl = lane & 15, rh4 = (lane >> 4) * 4;
  float* Cfb = Cf + zb * zC;
  f16* Chb = Ch + zb * zC;
  const float* bp = (EPI == 5 && zb == 1) ? bias2 : bias;
#pragma unroll
  for (int m = 0; m < 4; ++m) {
#pragma unroll
    for (int n = 0; n < FN; ++n) {
      int cc = col0 + wn * WN + n * 16 + cl;
      float bv = 0.f;
      if (EPI == 6)
        bv = (cc < 256) ? bias[cc] : bias2[cc - 256];
      else if (bp)
        bv = bp[cc];
#pragma unroll
      for (int q = 0; q < 4; ++q) {
        size_t r = row0 + wm * 64 + m * 16 + rh4 + q;
        float v = acc[m][n][q] + bv;
        if (EPI == 1) v = fmaxf(v, 0.f);
        if (EPI == 5) v = (zb == 0) ? tanhf(v) : 1.f / (1.f + __expf(-v));
        if (EPI == 6) v = (cc < 256) ? tanhf(v) : 1.f / (1.f + __expf(-v));
        if (WOUT == 0 || WOUT == 2) Cfb[r * ldc + cc] = v;
        if (WOUT == 1 || WOUT == 2) Chb[r * ldc + cc] = (f16)v;
      }
    }
  }
}

// ---------------------------------------------------------------------------
// sup_agg v4: aggP[kh][t][m][c] partials.  Tile 64 rows x 192 cols x K=512.
// grid (32, 2, 16): x = m-tile, y = n-tile, z = t*4 + kh.  LDS 32 KB.
// ---------------------------------------------------------------------------
__global__ __launch_bounds__(256) void sup_agg(
    const float* __restrict__ sup, const f16* __restrict__ edmT,
    f16* __restrict__ aggP) {
  __shared__ alignas(16) f16 As[64 * 64];
  __shared__ alignas(16) f16 Bs[192 * 64];
  const int tid = threadIdx.x;
  const int lane = tid & 63, wid = tid >> 6;
  const int m0 = blockIdx.x * 64, n0 = blockIdx.y * 192;
  const int t = blockIdx.z >> 2, kh = blockIdx.z & 3;
  const int l8 = lane >> 3;
  const int lx = ((lane & 7) ^ l8) * 8;
  const int sw = (lane & 7) * 8;
  const int cl = lane & 15, hi = lane >> 4;
  const int wm = wid >> 1, wn = wid & 1;
  const float* supT = sup + (size_t)t * NN * NN;
  const f16* edmTt = edmT + (size_t)t * G_IN * NN;

  f32x4 acc[2][6];
#pragma unroll
  for (int m = 0; m < 2; ++m)
#pragma unroll
    for (int n = 0; n < 6; ++n) acc[m][n] = (f32x4){0.f, 0.f, 0.f, 0.f};

  const int ar = tid >> 2;       // 0..63 rows
  const int g0 = (tid & 3) * 2;  // source granule pair
  const int kbeg = kh * 512;

  for (int k0 = kbeg; k0 < kbeg + 512; k0 += 64) {
    const float* ap = supT + (size_t)(m0 + ar) * NN + k0 + (tid & 3) * 16;
    float4 f0 = *(const float4*)ap;
    float4 f1 = *(const float4*)(ap + 4);
    float4 f2 = *(const float4*)(ap + 8);
    float4 f3 = *(const float4*)(ap + 12);
    f16x8 hv0 = {(f16)f0.x, (f16)f0.y, (f16)f0.z, (f16)f0.w,
                 (f16)f1.x, (f16)f1.y, (f16)f1.z, (f16)f1.w};
    f16x8 hv1 = {(f16)f2.x, (f16)f2.y, (f16)f2.z, (f16)f2.w,
                 (f16)f3.x, (f16)f3.y, (f16)f3.z, (f16)f3.w};
    *(f16x8*)&As[ar * 64 + ((g0 ^ (ar & 7)) * 8)] = hv0;
    *(f16x8*)&As[ar * 64 + (((g0 + 1) ^ (ar & 7)) * 8)] = hv1;
#pragma unroll
    for (int i = 0; i < 6; ++i) {
      int rn = wid * 48 + i * 8;
      gld_lds16(edmTt + (size_t)(n0 + rn + l8) * NN + k0 + lx, &Bs[rn * 64]);
    }
    __syncthreads();
#pragma unroll
    for (int ks = 0; ks < 2; ++ks) {
      f16x8 af[2], bf[6];
#pragma unroll
      for (int m = 0; m < 2; ++m)
        af[m] = *(const f16x8*)&As[((wm * 32 + m * 16 + cl) * 64 + ks * 32 +
                                    hi * 8) ^ sw];
#pragma unroll
      for (int n = 0; n < 6; ++n)
        bf[n] = *(const f16x8*)&Bs[((wn * 96 + n * 16 + cl) * 64 + ks * 32 +
                                    hi * 8) ^ sw];
#pragma unroll
      for (int m = 0; m < 2; ++m)
#pragma unroll
        for (int n = 0; n < 6; ++n)
          acc[m][n] = __builtin_amdgcn_mfma_f32_16x16x32_f16(af[m], bf[n],
                                                             acc[m][n], 0, 0, 0);
    }
    __syncthreads();
  }

  f16* dst = aggP + (size_t)kh * (4L * NN * G_IN) +
             ((size_t)t * NN + m0) * G_IN + n0;
#pragma unroll
  for (int m = 0; m < 2; ++m)
#pragma unroll
    for (int n = 0; n < 6; ++n)
#pragma unroll
      for (int q = 0; q < 4; ++q)
        dst[(size_t)(wm * 32 + m * 16 + hi * 4 + q) * G_IN + wn * 96 +
            n * 16 + cl] = (f16)acc[m][n][q];
}

// ---------------------------------------------------------------------------
// gnn_l2: g16[r] = l2norm(relu((sum of 4 aggP partials) @ Wgnn + b))
// ---------------------------------------------------------------------------
__global__ __launch_bounds__(256) void gnn_l2(
    const f16* __restrict__ aggP, const f16* __restrict__ WgnnT,
    const float* __restrict__ bgnn, f16* __restrict__ g16) {
  __shared__ alignas(16) f16 As[32 * 64];
  __shared__ alignas(16) f16 Bs[256 * 64];
  __shared__ float red[4][32];
  const int tid = threadIdx.x;
  const int lane = tid & 63, wid = tid >> 6;
  const int m0 = blockIdx.x * 32;
  const int l8 = lane >> 3;
  const int lx = ((lane & 7) ^ l8) * 8;
  const int sw = (lane & 7) * 8;
  const int cl = lane & 15, hi = lane >> 4;
  const long PS = 4L * NN * G_IN;

  f32x4 acc[2][4];
#pragma unroll
  for (int m = 0; m < 2; ++m)
#pragma unroll
    for (int n = 0; n < 4; ++n) acc[m][n] = (f32x4){0.f, 0.f, 0.f, 0.f};

  const int ar = tid >> 3;
  const int acw = ((tid & 7) ^ (ar & 7)) * 8;

  for (int k0 = 0; k0 < G_IN; k0 += 64) {
    size_t gi = (size_t)(m0 + ar) * G_IN + k0 + ((tid & 7) * 8);
    f16x8 a0 = *(const f16x8*)(aggP + gi);
    f16x8 a1 = *(const f16x8*)(aggP + PS + gi);
    f16x8 a2 = *(const f16x8*)(aggP + 2 * PS + gi);
    f16x8 a3 = *(const f16x8*)(aggP + 3 * PS + gi);
    f16x8 s;
#pragma unroll
    for (int e = 0; e < 8; ++e)
      s[e] = (f16)((float)a0[e] + (float)a1[e] + (float)a2[e] + (float)a3[e]);
    *(f16x8*)&As[ar * 64 + acw] = s;
#pragma unroll
    for (int i = 0; i < 8; ++i) {
      int rn = wid * 64 + i * 8;
      gld_lds16(WgnnT + (size_t)(rn + l8) * G_IN + k0 + lx, &Bs[rn * 64]);
    }
    __syncthreads();
#pragma unroll
    for (int ks = 0; ks < 2; ++ks) {
      f16x8 af[2], bf[4];
#pragma unroll
      for (int m = 0; m < 2; ++m)
        af[m] = *(const f16x8*)&As[((m * 16 + cl) * 64 + ks * 32 + hi * 8) ^ sw];
#pragma unroll
      for (int n = 0; n < 4; ++n)
        bf[n] = *(const f16x8*)&Bs[((wid * 64 + n * 16 + cl) * 64 + ks * 32 +
                                    hi * 8) ^ sw];
#pragma unroll
      for (int m = 0; m < 2; ++m)
#pragma unroll
        for (int n = 0; n < 4; ++n)
          acc[m][n] = __builtin_amdgcn_mfma_f32_16x16x32_f16(af[m], bf[n],
                                                             acc[m][n], 0, 0, 0);
    }
    __syncthreads();
  }

#pragma unroll
  for (int m = 0; m < 2; ++m)
#pragma unroll
    for (int n = 0; n < 4; ++n) {
      float bv = bgnn[wid * 64 + n * 16 + cl];
#pragma unroll
      for (int q = 0; q < 4; ++q)
        acc[m][n][q] = fmaxf(acc[m][n][q] + bv, 0.f);
    }
#pragma unroll
  for (int m = 0; m < 2; ++m)
#pragma unroll
    for (int q = 0; q < 4; ++q) {
      float ss = 0.f;
#pragma unroll
      for (int n = 0; n < 4; ++n) ss += acc[m][n][q] * acc[m][n][q];
#pragma unroll
      for (int msk = 1; msk < 16; msk <<= 1) ss += __shfl_xor(ss, msk);
      if (cl == 0) red[wid][m * 16 + hi * 4 + q] = ss;
    }
  __syncthreads();
#pragma unroll
  for (int m = 0; m < 2; ++m)
#pragma unroll
    for (int q = 0; q < 4; ++q) {
      int row = m * 16 + hi * 4 + q;
      float tot = red[0][row] + red[1][row] + red[2][row] + red[3][row];
      float inv = 1.f / fmaxf(sqrtf(tot), 1e-12f);
#pragma unroll
      for (int n = 0; n < 4; ++n)
        g16[(size_t)(m0 + row) * 256 + wid * 64 + n * 16 + cl] =
            (f16)(acc[m][n][q] * inv);
    }
}

// --- sum 4 K-split partials -> h f32 + f16 -----------------------------------
__global__ __launch_bounds__(256) void hsum4(const float* __restrict__ hP,
                                             float* __restrict__ hf,
                                             f16* __restrict__ h16) {
  long i = ((long)blockIdx.x * 256 + threadIdx.x) * 4;
  float4 a = *(const float4*)(hP + i);
  float4 b = *(const float4*)(hP + 524288 + i);
  float4 c = *(const float4*)(hP + 1048576 + i);
  float4 d = *(const float4*)(hP + 1572864 + i);
  float4 s = {a.x + b.x + c.x + d.x, a.y + b.y + c.y + d.y,
              a.z + b.z + c.z + d.z, a.w + b.w + c.w + d.w};
  *(float4*)(hf + i) = s;
  f16x4 o = {(f16)s.x, (f16)s.y, (f16)s.z, (f16)s.w};
  *(f16x4*)(h16 + i) = o;
}

// --- t=0 shortcut: rnn0 = sigmoid(Xg_u+bg)*tanh(Xc+bc), transposed ----------
__global__ __launch_bounds__(256) void rnn0_t(const f16* __restrict__ Xgc,
                                              const float* __restrict__ bg,
                                              const float* __restrict__ bc,
                                              f16* __restrict__ rnnT) {
  __shared__ float tile[32][33];
  int n0 = blockIdx.x * 32, k0 = blockIdx.y * 32;
  int tx = threadIdx.x & 31, ty = threadIdx.x >> 5;
#pragma unroll
  for (int i = 0; i < 32; i += 8) {
    int n = n0 + ty + i, k = k0 + tx;
    float u = 1.f / (1.f + __expf(-((float)Xgc[(size_t)n * 768 + 256 + k] +
                                    bg[256 + k])));
    float c = tanhf((float)Xgc[(size_t)n * 768 + 512 + k] + bc[k]);
    tile[ty + i][tx] = u * c;
  }
  __syncthreads();
#pragma unroll
  for (int i = 0; i < 32; i += 8)
    rnnT[(size_t)(k0 + ty + i) * NN + n0 + tx] = (f16)tile[tx][ty + i];
}

// ---------------------------------------------------------------------------
// gru_step: one kernel per scan step (t>=1).  16 rows per block, grid 128.
// Stages h = sum of 4 hP partials (f32 + f16 in LDS).  Phase 1: gates =
// sigmoid(h@Wgh + Xg + bg) -> rh (LDS f16), u (LDS f32); B-frags direct from
// L2.  Phase 2: c = tanh(rh@Wch + Xc + bc); rnn = (1-u)h + u*c -> transposed
// write to rnnT.
// ---------------------------------------------------------------------------
__global__ __launch_bounds__(256) void gru_step(
    const float* __restrict__ hP, const f16* __restrict__ Xgc,
    const f16* __restrict__ WghT, const f16* __restrict__ WchT,
    const float* __restrict__ bg, const float* __restrict__ bc,
    f16* __restrict__ rnnT) {
  __shared__ alignas(16) f16 A_s[16 * 264];
  __shared__ alignas(16) f16 rh_s[16 * 264];
  __shared__ float u_s[16 * 260];
  __shared__ float hf_s[16 * 260];
  __shared__ alignas(16) f16 tileT[256 * 24];
  const int tid = threadIdx.x;
  const int lane = tid & 63, wid = tid >> 6;
  const int cl = lane & 15, hi = lane >> 4;
  const int r0 = blockIdx.x * 16;

  // --- stage h rows: sum 4 partials -> hf_s (f32), A_s (f16) -----------------
#pragma unroll
  for (int i = 0; i < 4; ++i) {
    int e = i * 256 + tid;  // f32x4 chunk, 1024 total
    int row = e >> 6, off = (e & 63) * 4;
    size_t gi = (size_t)(r0 + row) * 256 + off;
    float4 a = *(const float4*)(hP + gi);
    float4 b = *(const float4*)(hP + 524288 + gi);
    float4 c = *(const float4*)(hP + 1048576 + gi);
    float4 d = *(const float4*)(hP + 1572864 + gi);
    float4 s = {a.x + b.x + c.x + d.x, a.y + b.y + c.y + d.y,
                a.z + b.z + c.z + d.z, a.w + b.w + c.w + d.w};
    *(float4*)&hf_s[row * 260 + off] = s;
    f16x4 h4 = {(f16)s.x, (f16)s.y, (f16)s.z, (f16)s.w};
    *(f16x4*)&A_s[row * 264 + off] = h4;
  }
  __syncthreads();

  // --- phase 1: gates [16 x 512], K=256; wave covers 128 cols ---------------
  const int wc0 = wid * 128;
  f32x4 acc[8];
#pragma unroll
  for (int n = 0; n < 8; ++n) acc[n] = (f32x4){0.f, 0.f, 0.f, 0.f};
#pragma unroll
  for (int kk = 0; kk < 256; kk += 32) {
    f16x8 af = *(const f16x8*)&A_s[cl * 264 + kk + hi * 8];
#pragma unroll
    for (int n = 0; n < 8; ++n) {
      f16x8 bf = *(const f16x8*)(WghT + (size_t)(wc0 + n * 16 + cl) * 256 +
                                 kk + hi * 8);
      acc[n] = __builtin_amdgcn_mfma_f32_16x16x32_f16(af, bf, acc[n], 0, 0, 0);
    }
  }
#pragma unroll
  for (int n = 0; n < 8; ++n) {
    int cc = wc0 + n * 16 + cl;
    float bgv = bg[cc];
#pragma unroll
    for (int q = 0; q < 4; ++q) {
      int rl = hi * 4 + q;
      float v = acc[n][q] + bgv + (float)Xgc[(size_t)(r0 + rl) * 768 + cc];
      float sv = 1.f / (1.f + __expf(-v));
      if (cc < 256)
        rh_s[rl * 264 + cc] = (f16)(sv * hf_s[rl * 260 + cc]);
      else
        u_s[rl * 260 + cc - 256] = sv;
    }
  }
  __syncthreads();

  // --- phase 2: cand [16 x 256], K=256; wave covers 64 cols ------------------
  const int wc2 = wid * 64;
  f32x4 acc2[4];
#pragma unroll
  for (int n = 0; n < 4; ++n) acc2[n] = (f32x4){0.f, 0.f, 0.f, 0.f};
#pragma unroll
  for (int kk = 0; kk < 256; kk += 32) {
    f16x8 af = *(const f16x8*)&rh_s[cl * 264 + kk + hi * 8];
#pragma unroll
    for (int n = 0; n < 4; ++n) {
      f16x8 bf = *(const f16x8*)(WchT + (size_t)(wc2 + n * 16 + cl) * 256 +
                                 kk + hi * 8);
      acc2[n] = __builtin_amdgcn_mfma_f32_16x16x32_f16(af, bf, acc2[n], 0, 0, 0);
    }
  }
#pragma unroll
  for (int n = 0; n < 4; ++n) {
    int cc = wc2 + n * 16 + cl;
    float bcv = bc[cc];
#pragma unroll
    for (int q = 0; q < 4; ++q) {
      int rl = hi * 4 + q;
      float cv = tanhf(acc2[n][q] + bcv +
                       (float)Xgc[(size_t)(r0 + rl) * 768 + 512 + cc]);
      float u = u_s[rl * 260 + cc];
      float hv = hf_s[rl * 260 + cc];
      tileT[cc * 24 + rl] = (f16)((1.f - u) * hv + u * cv);
    }
  }
  __syncthreads();

  // --- transposed write-out: thread tid = column --------------------------
  {
    int cc = tid;
    *(f16x8*)&rnnT[(size_t)cc * NN + r0] = *(const f16x8*)&tileT[cc * 24];
    *(f16x8*)&rnnT[(size_t)cc * NN + r0 + 8] =
        *(const f16x8*)&tileT[cc * 24 + 8];
  }
}

// ---------------------------------------------------------------------------
// Fused P/Q/decode
// ---------------------------------------------------------------------------
__global__ __launch_bounds__(256) void pq_decode(
    const f16* __restrict__ emb, const f16* __restrict__ scal,
    const float* __restrict__ sq, float* __restrict__ out) {
  __shared__ alignas(16) f16 EA[128 * 64], EB[128 * 64], SA[128 * 64],
      SB[128 * 64];
  const int tid = threadIdx.x;
  const int lane = tid & 63, wid = tid >> 6;
  const int wm = wid >> 1, wn = wid & 1;
  const int row0 = blockIdx.y * 128, col0 = blockIdx.x * 128;
  const int l8 = lane >> 3;
  const int lx = ((lane & 7) ^ l8) * 8;
  const int sw = (lane & 7) * 8;
#pragma unroll
  for (int i = 0; i < 2; ++i) {
    int r = wid * 16 + i * 8;
    gld_lds16(emb + (size_t)(row0 + r + l8) * 64 + lx, &EA[r * 64]);
    gld_lds16(emb + (size_t)(col0 + r + l8) * 64 + lx, &EB[r * 64]);
    gld_lds16(scal + (size_t)(row0 + r + l8) * 64 + lx, &SA[r * 64]);
    gld_lds16(scal + (size_t)(col0 + r + l8) * 64 + lx, &SB[r * 64]);
    int r2 = r + 64;
    gld_lds16(emb + (size_t)(row0 + r2 + l8) * 64 + lx, &EA[r2 * 64]);
    gld_lds16(emb + (size_t)(col0 + r2 + l8) * 64 + lx, &EB[r2 * 64]);
    gld_lds16(scal + (size_t)(row0 + r2 + l8) * 64 + lx, &SA[r2 * 64]);
    gld_lds16(scal + (size_t)(col0 + r2 + l8) * 64 + lx, &SB[r2 * 64]);
  }
  __syncthreads();
  f32x4 accP[4][4], accQ[4][4];
#pragma unroll
  for (int m = 0; m < 4; ++m)
#pragma unroll
    for (int n = 0; n < 4; ++n) {
      accP[m][n] = (f32x4){0.f, 0.f, 0.f, 0.f};
      accQ[m][n] = (f32x4){0.f, 0.f, 0.f, 0.f};
    }
#pragma unroll
  for (int ks = 0; ks < 2; ++ks) {
    f16x8 af[4], bf[4];
#pragma unroll
    for (int m = 0; m < 4; ++m)
      af[m] = *(const f16x8*)&EA[((wm * 64 + m * 16 + (lane & 15)) * 64 +
                                  ks * 32 + (lane >> 4) * 8) ^ sw];
#pragma unroll
    for (int n = 0; n < 4; ++n)
      bf[n] = *(const f16x8*)&EB[((wn * 64 + n * 16 + (lane & 15)) * 64 +
                                  ks * 32 + (lane >> 4) * 8) ^ sw];
#pragma unroll
    for (int m = 0; m < 4; ++m)
#pragma unroll
      for (int n = 0; n < 4; ++n)
        accP[m][n] = __builtin_amdgcn_mfma_f32_16x16x32_f16(af[m], bf[n],
                                                            accP[m][n], 0, 0, 0);
#pragma unroll
    for (int m = 0; m < 4; ++m)
      af[m] = *(const f16x8*)&SA[((wm * 64 + m * 16 + (lane & 15)) * 64 +
                                  ks * 32 + (lane >> 4) * 8) ^ sw];
#pragma unroll
    for (int n = 0; n < 4; ++n)
      bf[n] = *(const f16x8*)&SB[((wn * 64 + n * 16 + (lane & 15)) * 64 +
                                  ks * 32 + (lane >> 4) * 8) ^ sw];
#pragma unroll
    for (int m = 0; m < 4; ++m)
#pragma unroll
      for (int n = 0; n < 4; ++n)
        accQ[m][n] = __builtin_amdgcn_mfma_f32_16x16x32_f16(af[m], bf[n],
                                                            accQ[m][n], 0, 0, 0);
  }
  const int cl = lane & 15, rh4 = (lane >> 4) * 4;
#pragma unroll
  for (int m = 0; m < 4; ++m) {
#pragma unroll
    for (int n = 0; n < 4; ++n) {
      int c = col0 + wn * 64 + n * 16 + cl;
      float sqc = sq[c];
#pragma unroll
      for (int q = 0; q < 4; ++q) {
        size_t r = row0 + wm * 64 + m * 16 + rh4 + q;
        float dist = -(sq[r] + sqc - 2.f * accP[m][n][q]);
        out[r * NN + c] = 1.f + tanhf(dist * accQ[m][n][q]);
      }
    }
  }
}

// --- fused transpose+convert of the weight matrices --------------------------
struct MT {
  const float* src[11];
  f16* dst[11];
  int K[11], N[11], st[11], ts[12];
};
__global__ __launch_bounds__(256) void multi_transp(MT mt) {
  __shared__ float tile[32][33];
  int b = blockIdx.x, w = 0;
  while (b >= mt.ts[w + 1]) ++w;
  int lt = b - mt.ts[w];
  int K = mt.K[w], N = mt.N[w];
  int tk = lt % (K >> 5), tn = lt / (K >> 5);
  int k0 = tk * 32, n0 = tn * 32;
  int tx = threadIdx.x & 31, ty = threadIdx.x >> 5;
  const float* src = mt.src[w];
#pragma unroll
  for (int i = 0; i < 32; i += 8)
    tile[ty + i][tx] = src[(size_t)(k0 + ty + i) * N + n0 + tx];
  __syncthreads();
  f16* dst = mt.dst[w];
  int st = mt.st[w];
#pragma unroll
  for (int i = 0; i < 32; i += 8)
    dst[(size_t)(n0 + ty + i) * st + k0 + tx] = (f16)tile[tx][ty + i];
}

// --- fused edmT builder: transpose fem16 (f16) + noise (f32) -----------------
__global__ __launch_bounds__(256) void edm_t(const f16* __restrict__ fem16,
                                             const float* __restrict__ noise,
                                             f16* __restrict__ edmT) {
  __shared__ float tile[32][33];
  int bx = blockIdx.x, r0 = blockIdx.y * 32, t = blockIdx.z;
  int tx = threadIdx.x & 31, ty = threadIdx.x >> 5;
  f16* dstT = edmT + (size_t)t * G_IN * NN;
  if (bx < 8) {
    int c0 = bx * 32;
    const f16* src = fem16 + (size_t)t * NN * HF;
#pragma unroll
    for (int i = 0; i < 32; i += 8)
      tile[ty + i][tx] = (float)src[(size_t)(r0 + ty + i) * HF + c0 + tx];
    __syncthreads();
#pragma unroll
    for (int i = 0; i < 32; i += 8)
      dstT[(size_t)(c0 + ty + i) * NN + r0 + tx] = (f16)tile[tx][ty + i];
  } else {
    int c0 = (bx - 8) * 32;
    const float* src = noise + (size_t)t * NN * DZ;
#pragma unroll
    for (int i = 0; i < 32; i += 8)
      tile[ty + i][tx] = src[(size_t)(r0 + ty + i) * DZ + c0 + tx];
    __syncthreads();
#pragma unroll
    for (int i = 0; i < 32; i += 8)
      dstT[(size_t)(HF + c0 + ty + i) * NN + r0 + tx] = (f16)tile[tx][ty + i];
  }
}

// --- f32 -> fp16 convert -----------------------------------------------------
__global__ __launch_bounds__(256) void cvt_h(const float* __restrict__ in,
                                             f16* __restrict__ out) {
  long i = ((long)blockIdx.x * 256 + threadIdx.x) * 4;
  float4 v = *(const float4*)(in + i);
  f16x4 o = {(f16)v.x, (f16)v.y, (f16)v.z, (f16)v.w};
  *(f16x4*)(out + i) = o;
}

// --- row softmax + mix with align -> fp16 ------------------------------------
__global__ __launch_bounds__(256) void softmax_mix(
    const float* __restrict__ S, const float* __restrict__ Al,
    const float* __restrict__ lam_ptr, f16* __restrict__ Mh) {
  const int tid = threadIdx.x;
  const float4* s4 = (const float4*)(S + (long)blockIdx.x * 2048);
  float4 a = s4[tid], b = s4[tid + 256];
  float m = fmaxf(fmaxf(fmaxf(a.x, a.y), fmaxf(a.z, a.w)),
                  fmaxf(fmaxf(b.x, b.y), fmaxf(b.z, b.w)));
  __shared__ float red[4];
  float w = wave_max(m);
  if ((tid & 63) == 0) red[tid >> 6] = w;
  __syncthreads();
  m = fmaxf(fmaxf(red[0], red[1]), fmaxf(red[2], red[3]));
  __syncthreads();
  a.x = __expf(a.x - m); a.y = __expf(a.y - m);
  a.z = __expf(a.z - m); a.w = __expf(a.w - m);
  b.x = __expf(b.x - m); b.y = __expf(b.y - m);
  b.z = __expf(b.z - m); b.w = __expf(b.w - m);
  float s = a.x + a.y + a.z + a.w + b.x + b.y + b.z + b.w;
  w = wave_sum(s);
  if ((tid & 63) == 0) red[tid >> 6] = w;
  __syncthreads();
  float inv = 1.f / (red[0] + red[1] + red[2] + red[3]);
  float lam = lam_ptr[0], oml = 1.f - lam;
  const float4* al4 = (const float4*)(Al + (long)blockIdx.x * 2048);
  float4 x = al4[tid], y = al4[tid + 256];
  f16x4 o0 = {(f16)(lam * x.x + oml * a.x * inv),
              (f16)(lam * x.y + oml * a.y * inv),
              (f16)(lam * x.z + oml * a.z * inv),
              (f16)(lam * x.w + oml * a.w * inv)};
  f16x4 o1 = {(f16)(lam * y.x + oml * b.x * inv),
              (f16)(lam * y.y + oml * b.y * inv),
              (f16)(lam * y.z + oml * b.z * inv),
              (f16)(lam * y.w + oml * b.w * inv)};
  f16x4* out4 = (f16x4*)(Mh + (long)blockIdx.x * 2048);
  out4[tid] = o0;
  out4[tid + 256] = o1;
}

// --- column L2 norms of emb0 [N,64] ------------------------------------------
__global__ __launch_bounds__(256) void col_l2norm64(
    const float* __restrict__ x, float* __restrict__ cn) {
  int c = blockIdx.x;
  float ss = 0.f;
  for (int r = threadIdx.x; r < NN; r += 256) {
    float v = x[(long)r * 64 + c];
    ss += v * v;
  }
  __shared__ float red[4];
  float w = wave_sum(ss);
  if ((threadIdx.x & 63) == 0) red[threadIdx.x >> 6] = w;
  __syncthreads();
  if (threadIdx.x == 0)
    cn[c] = fmaxf(sqrtf(red[0] + red[1] + red[2] + red[3]), 1e-12f);
}

// --- emb16 = emb0/cn ; sq[i] = row sumsq -------------------------------------
__global__ void norm_sq64h(const float* __restrict__ x,
                           const float* __restrict__ cn,
                           f16* __restrict__ emb16, float* __restrict__ sq) {
  int i = blockIdx.x, j = threadIdx.x;
  float e = x[(long)i * 64 + j] / cn[j];
  emb16[(long)i * 64 + j] = (f16)e;
  float s = wave_sum(e * e);
  if (j == 0) sq[i] = s;
}

// ---------------------------------------------------------------------------
extern "C" void kernel_launch(void* const* d_in, const int* in_sizes, int n_in,
                              void* d_out, int out_size, void* d_ws,
                              size_t ws_size, hipStream_t stream) {
  (void)in_sizes; (void)n_in; (void)out_size; (void)ws_size;
  const float* sup    = (const float*)d_in[0];
  const float* feat   = (const float*)d_in[1];
  const float* noise  = (const float*)d_in[2];
  const float* align  = (const float*)d_in[3];
  const float* lambd  = (const float*)d_in[4];
  const float* W_fem  = (const float*)d_in[5];
  const float* b_fem  = (const float*)d_in[6];
  const float* W_gnn  = (const float*)d_in[7];
  const float* b_gnn  = (const float*)d_in[8];
  const float* Wg_x   = (const float*)d_in[9];
  const float* Wg_h   = (const float*)d_in[10];
  const float* bg     = (const float*)d_in[11];
  const float* Wc_x   = (const float*)d_in[12];
  const float* Wc_h   = (const float*)d_in[13];
  const float* bc     = (const float*)d_in[14];
  const float* W_att  = (const float*)d_in[15];
  const float* b_att  = (const float*)d_in[16];
  const float* W_emb1 = (const float*)d_in[17];
  const float* b_emb1 = (const float*)d_in[18];
  const float* W_emb2 = (const float*)d_in[19];
  const float* b_emb2 = (const float*)d_in[20];
  const float* W_scal1= (const float*)d_in[21];
  const float* b_scal1= (const float*)d_in[22];
  const float* W_scal2= (const float*)d_in[23];
  const float* b_scal2= (const float*)d_in[24];

  char* wsb = (char*)d_ws;
  size_t po = 0;
  auto P = [&](size_t bytes) {
    size_t r = po;
    po += (bytes + 255) & ~(size_t)255;
    return r;
  };
  f16* fem16  = (f16*)(wsb + P(5L * NN * HF * 2));
  f16* fm16   = (f16*)(wsb + P(5L * NN * HH * 2));
  f16* g16    = (f16*)(wsb + P(4L * NN * HH * 2));
  f16* WT     = (f16*)(wsb + P(884736L * 2));
  f16* Xgc16  = (f16*)(wsb + P(4L * NN * 768 * 2));
  float* hA   = (float*)(wsb + P((long)NN * HH * 4));
  f16* h16A   = (f16*)(wsb + P((long)NN * HH * 2));
  f16* rnnT16 = (f16*)(wsb + P((long)NN * HH * 2));
  float* hP   = (float*)(wsb + P(4L * NN * HH * 4));
  f16* M16_2  = (f16*)(wsb + P(2L * NN * NN * 2));
  f16* e1s1   = (f16*)(wsb + P((long)NN * 512 * 2));
  float* embscF = (float*)(wsb + P(2L * NN * E2D * 4));
  f16* embsc16  = (f16*)(wsb + P(2L * NN * E2D * 2));
  f16* emb16  = (f16*)(wsb + P((long)NN * E2D * 2));
  float* cn   = (float*)(wsb + P(64 * 4));
  float* sq   = (float*)(wsb + P(NN * 4));
  // arena: feat16 | edmT | aggP live early; Sbuf2 aliases after gnn_l2
  size_t arena = P(34078720);
  f16* feat16 = (f16*)(wsb + arena);
  f16* edmT   = (f16*)(wsb + arena + 2621440);
  f16* aggP   = (f16*)(wsb + arena + 8912896);
  float* Sbuf2 = (float*)(wsb + arena);

  // --- weight transpose table -------------------------------------------------
  f16* W_femT  = WT;                       // 256x128
  f16* W_gnnT  = W_femT + 32768;           // 256x384
  f16* WgxcT   = W_gnnT + 98304;           // 768x256 ([Wgx^T; Wcx^T])
  f16* WghT    = WgxcT + 196608;           // 512x256
  f16* WchT    = WghT + 131072;            // 256x256
  f16* W_attT  = WchT + 65536;             // 256x256
  f16* We1s1T  = W_attT + 65536;           // 512x512 ([Wemb1^T; Wscal1^T])
  f16* Wemb2T  = We1s1T + 262144;          // 64x256
  f16* Wscal2T = Wemb2T + 16384;           // 64x256 (adjacent: zB=16384)

  MT mt;
  const float* wsrc[11] = {W_fem, W_gnn, Wg_x, Wc_x, Wg_h, Wc_h,
                           W_att, W_emb1, W_scal1, W_emb2, W_scal2};
  f16* wdst[11] = {W_femT, W_gnnT, WgxcT, WgxcT + 512 * 256, WghT, WchT,
                   W_attT, We1s1T, We1s1T + 256 * 512, Wemb2T, Wscal2T};
  const int wK[11]  = {128, 384, 256, 256, 256, 256, 256, 512, 512, 256, 256};
  const int wNd[11] = {256, 256, 512, 256, 512, 256, 256, 256, 256, 64, 64};
  const int wSt[11] = {128, 384, 256, 256, 256, 256, 256, 512, 512, 256, 256};
  int tcum = 0;
  for (int i = 0; i < 11; ++i) {
    mt.src[i] = wsrc[i];
    mt.dst[i] = wdst[i];
    mt.K[i] = wK[i];
    mt.N[i] = wNd[i];
    mt.st[i] = wSt[i];
    mt.ts[i] = tcum;
    tcum += (wK[i] >> 5) * (wNd[i] >> 5);
  }
  mt.ts[11] = tcum;

  const f16* NH = nullptr;
  float* NF = nullptr;
  f16* NHm = nullptr;

  multi_transp<<<tcum, 256, 0, stream>>>(mt);
  cvt_h<<<(5L * NN * F_IN) / 1024, 256, 0, stream>>>(feat, feat16);

  // FEM: fem16 = relu(feat @ W_fem + b)
  hgemm<1, 64, 1><<<dim3(4, 80, 1), 256, 0, stream>>>(
      feat16, NH, W_femT, b_fem, nullptr, NF, fem16,
      128, 0, 128, 128, 256, 128, 0, 0, 0);

  // edmT
  edm_t<<<dim3(12, 64, 4), 256, 0, stream>>>(fem16, noise, edmT);

  // sup path: 1024-block partial aggregation + fused gnn/l2norm
  sup_agg<<<dim3(32, 2, 16), 256, 0, stream>>>(sup, edmT, aggP);
  gnn_l2<<<256, 256, 0, stream>>>(aggP, W_gnnT, b_gnn, g16);

  // fm16 = fem @ W_att + b
  hgemm<0, 64, 1><<<dim3(4, 80, 1), 256, 0, stream>>>(
      fem16, NH, W_attT, b_att, nullptr, NF, fm16,
      256, 0, 256, 256, 256, 256, 0, 0, 0);

  // Xgc = g16 @ [Wgx | Wcx]  -> [8192 x 768] f16 pre-activations
  hgemm<0, 64, 1><<<dim3(12, 64, 1), 256, 0, stream>>>(
      g16, NH, WgxcT, nullptr, nullptr, NF, Xgc16,
      256, 0, 256, 256, 768, 256, 0, 0, 0);

  for (int p = 0; p < 2; ++p) {
    // S pair: S[z] = fm[2p+z+1] @ fm[2p+z]^T
    hgemm<0, 128, 0><<<dim3(16, 16, 2), 256, 0, stream>>>(
        fm16 + (size_t)(2 * p + 1) * NN * HH, NH,
        fm16 + (size_t)(2 * p) * NN * HH, nullptr, nullptr, Sbuf2, NHm,
        256, 0, 256, 256, 2048, 256, (long)NN * HH, (long)NN * HH,
        (long)NN * NN);
    softmax_mix<<<2 * NN, 256, 0, stream>>>(
        Sbuf2, align + (size_t)(2 * p) * NN * NN, lambd, M16_2);

    for (int tl = 0; tl < 2; ++tl) {
      int t = 2 * p + tl;
      if (t == 0) {
        rnn0_t<<<dim3(64, 8, 1), 256, 0, stream>>>(Xgc16, bg, bc, rnnT16);
      } else {
        gru_step<<<128, 256, 0, stream>>>(
            hP, Xgc16 + (size_t)t * NN * 768, WghT, WchT, bg, bc, rnnT16);
      }
      // h_{t} partials = M16 @ rnn (K-split x4)
      hgemm<0, 64, 0><<<dim3(4, 16, 4), 256, 0, stream>>>(
          M16_2 + (size_t)(t & 1) * NN * NN, NH, rnnT16, nullptr, nullptr,
          hP, NHm, 2048, 0, 2048, 2048, 256, 512, 512, 512, 524288);
    }
  }
  // final h for EAM
  hsum4<<<512, 256, 0, stream>>>(hP, hA, h16A);

  // --- EAM tail ---------------------------------------------------------------
  hgemm<6, 64, 1><<<dim3(8, 16, 1), 256, 0, stream>>>(
      h16A, fem16 + 4L * NN * HF, We1s1T, b_emb1, b_scal1, NF, e1s1,
      256, 256, 256, 512, 512, 512, 0, 0, 0);
  hgemm<5, 64, 2><<<dim3(1, 16, 2), 256, 0, stream>>>(
      e1s1, NH, Wemb2T, b_emb2, b_scal2, embscF, embsc16,
      512, 0, 512, 256, 64, 256, 256, 16384, (long)NN * E2D);
  col_l2norm64<<<64, 256, 0, stream>>>(embscF, cn);
  norm_sq64h<<<NN, 64, 0, stream>>>(embscF, cn, emb16, sq);

  pq_decode<<<dim3(16, 16, 1), 256, 0, stream>>>(
      emb16, embsc16 + (size_t)NN * E2D, sq, (float*)d_out);
}

// Round 11
// 315.478 us; speedup vs baseline: 1.2493x; 1.0049x over previous
//
#include <hip/hip_runtime.h>
#include <math.h>

// ---------------------------------------------------------------------------
// GenNet_tanh forward, round 11: R10 + THE FIX.  Root cause of R8/R9/R10's
// identical absmax 0.09375: the emb2/scal2 GEMM lost zA=256 in the R8
// signature refactor, so the scal head consumed the tanh half (e1) instead
// of the sigmoid half (s1) of e1s1.  One parameter restored.
// ---------------------------------------------------------------------------

#define T_WIN 4
#define NN 2048
#define F_IN 128
#define HF 256
#define HH 256
#define DZ 128
#define G_IN 384
#define EIN 512
#define E1D 256
#define E2D 64

typedef _Float16 f16;
typedef _Float16 f16x8 __attribute__((ext_vector_type(8)));
typedef _Float16 f16x4 __attribute__((ext_vector_type(4)));
typedef float f32x4 __attribute__((ext_vector_type(4)));

__device__ __forceinline__ float wave_sum(float v) {
#pragma unroll
  for (int o = 32; o > 0; o >>= 1) v += __shfl_down(v, o);
  return v;
}
__device__ __forceinline__ float wave_max(float v) {
#pragma unroll
  for (int o = 32; o > 0; o >>= 1) v = fmaxf(v, __shfl_down(v, o));
  return v;
}

__device__ __forceinline__ void gld_lds16(const void* g, void* l) {
  __builtin_amdgcn_global_load_lds(
      (const __attribute__((address_space(1))) unsigned int*)g,
      (__attribute__((address_space(3))) unsigned int*)l, 16, 0, 0);
}

// ---------------------------------------------------------------------------
// fp16 MFMA GEMM, 128 x BN tile, BK=64, 256 threads (4 waves 2x2).
// A: [.,lda] row-major; dual-source: k<kspl from A, else A2 (lda2).
// BT: [N,ldb] row-major.  grid.z advances A by zA, A2 by zA2, BT by zB,
// C by zC.  EPI: 0 none, 1 relu, 5 z-sel tanh/sig, 6 col-sel.
// WOUT: 0 f32, 1 f16, 2 both.
// ---------------------------------------------------------------------------
template <int EPI, int BN, int WOUT>
__global__ __launch_bounds__(256) void hgemm(
    const f16* __restrict__ A, const f16* __restrict__ A2,
    const f16* __restrict__ BT, const float* __restrict__ bias,
    const float* __restrict__ bias2, float* __restrict__ Cf,
    f16* __restrict__ Ch, int lda, int lda2, int kspl, int ldb, int ldc,
    int K, long zA, long zA2, long zB, long zC) {
  constexpr int WN = BN / 2;
  constexpr int FN = WN / 16;
  constexpr int BI = BN / 32;
  __shared__ alignas(16) f16 As[128 * 64];
  __shared__ alignas(16) f16 Bs[BN * 64];
  const int tid = threadIdx.x;
  const int lane = tid & 63, wid = tid >> 6;
  const int wm = wid >> 1, wn = wid & 1;
  const int row0 = blockIdx.y * 128, col0 = blockIdx.x * BN;
  const long zb = blockIdx.z;
  A += zb * zA;
  if (A2) A2 += zb * zA2;
  BT += zb * zB;
  const int l8 = lane >> 3;
  const int lx = ((lane & 7) ^ l8) * 8;  // pre-swizzled source chunk
  const int sw = (lane & 7) * 8;         // frag-read XOR

  f32x4 acc[4][FN];
#pragma unroll
  for (int m = 0; m < 4; ++m)
#pragma unroll
    for (int n = 0; n < FN; ++n) acc[m][n] = (f32x4){0.f, 0.f, 0.f, 0.f};

  for (int k0 = 0; k0 < K; k0 += 64) {
#pragma unroll
    for (int i = 0; i < 4; ++i) {
      int r = wid * 32 + i * 8;
      const f16* src =
          (k0 < kspl) ? A + (size_t)(row0 + r + l8) * lda + k0 + lx
                      : A2 + (size_t)(row0 + r + l8) * lda2 + (k0 - kspl) + lx;
      gld_lds16(src, &As[r * 64]);
    }
#pragma unroll
    for (int i = 0; i < BI; ++i) {
      int r = wid * (BN / 4) + i * 8;
      gld_lds16(BT + (size_t)(col0 + r + l8) * ldb + k0 + lx, &Bs[r * 64]);
    }
    __syncthreads();
#pragma unroll
    for (int ks = 0; ks < 2; ++ks) {
      f16x8 af[4], bf[FN];
#pragma unroll
      for (int m = 0; m < 4; ++m)
        af[m] = *(const f16x8*)&As[((wm * 64 + m * 16 + (lane & 15)) * 64 +
                                    ks * 32 + (lane >> 4) * 8) ^ sw];
#pragma unroll
      for (int n = 0; n < FN; ++n)
        bf[n] = *(const f16x8*)&Bs[((wn * WN + n * 16 + (lane & 15)) * 64 +
                                    ks * 32 + (lane >> 4) * 8) ^ sw];
#pragma unroll
      for (int m = 0; m < 4; ++m)
#pragma unroll
        for (int n = 0; n < FN; ++n)
          acc[m][n] = __builtin_amdgcn_mfma_f32_16x16x32_f16(af[m], bf[n],
                                                             acc[m][n], 0, 0, 0);
    }
    __syncthreads();
  }

  const int cl = lane & 15, rh4 = (lane >> 4) * 4;
  float* Cfb = Cf + zb * zC;
  f16* Chb = Ch + zb * zC;
  const float* bp = (EPI == 5 && zb == 1) ? bias2 : bias;
#pragma unroll
  for (int m = 0; m < 4; ++m) {
#pragma unroll
    for (int n = 0; n < FN; ++n) {
      int cc = col0 + wn * WN + n * 16 + cl;
      float bv = 0.f;
      if (EPI == 6)
        bv = (cc < 256) ? bias[cc] : bias2[cc - 256];
      else if (bp)
        bv = bp[cc];
#pragma unroll
      for (int q = 0; q < 4; ++q) {
        size_t r = row0 + wm * 64 + m * 16 + rh4 + q;
        float v = acc[m][n][q] + bv;
        if (EPI == 1) v = fmaxf(v, 0.f);
        if (EPI == 5) v = (zb == 0) ? tanhf(v) : 1.f / (1.f + __expf(-v));
        if (EPI == 6) v = (cc < 256) ? tanhf(v) : 1.f / (1.f + __expf(-v));
        if (WOUT == 0 || WOUT == 2) Cfb[r * ldc + cc] = v;
        if (WOUT == 1 || WOUT == 2) Chb[r * ldc + cc] = (f16)v;
      }
    }
  }
}

// ---------------------------------------------------------------------------
// sup_gnn2 (R7 sup_agg clone, 128-col B): aggP partials of sup @ edmW.
// Tile 64 rows x 128 cols x K=512.  grid (32, 2, 16): x=m, y=n-half,
// z = t*4 + kh.  LDS 24 KB.
// ---------------------------------------------------------------------------
__global__ __launch_bounds__(256) void sup_gnn2(
    const float* __restrict__ sup, const f16* __restrict__ edmWT,
    f16* __restrict__ aggP) {
  __shared__ alignas(16) f16 As[64 * 64];
  __shared__ alignas(16) f16 Bs[128 * 64];
  const int tid = threadIdx.x;
  const int lane = tid & 63, wid = tid >> 6;
  const int m0 = blockIdx.x * 64, n0 = blockIdx.y * 128;
  const int t = blockIdx.z >> 2, kh = blockIdx.z & 3;
  const int l8 = lane >> 3;
  const int lx = ((lane & 7) ^ l8) * 8;
  const int sw = (lane & 7) * 8;
  const int cl = lane & 15, hi = lane >> 4;
  const int wm = wid >> 1, wn = wid & 1;
  const float* supT = sup + (size_t)t * NN * NN;
  const f16* BTt = edmWT + (size_t)t * 256 * NN;

  f32x4 acc[2][4];
#pragma unroll
  for (int m = 0; m < 2; ++m)
#pragma unroll
    for (int n = 0; n < 4; ++n) acc[m][n] = (f32x4){0.f, 0.f, 0.f, 0.f};

  const int ar = tid >> 2;       // 0..63 rows
  const int g0 = (tid & 3) * 2;  // source granule pair
  const int kbeg = kh * 512;

  for (int k0 = kbeg; k0 < kbeg + 512; k0 += 64) {
    const float* ap = supT + (size_t)(m0 + ar) * NN + k0 + (tid & 3) * 16;
    float4 f0 = *(const float4*)ap;
    float4 f1 = *(const float4*)(ap + 4);
    float4 f2 = *(const float4*)(ap + 8);
    float4 f3 = *(const float4*)(ap + 12);
    f16x8 hv0 = {(f16)f0.x, (f16)f0.y, (f16)f0.z, (f16)f0.w,
                 (f16)f1.x, (f16)f1.y, (f16)f1.z, (f16)f1.w};
    f16x8 hv1 = {(f16)f2.x, (f16)f2.y, (f16)f2.z, (f16)f2.w,
                 (f16)f3.x, (f16)f3.y, (f16)f3.z, (f16)f3.w};
    *(f16x8*)&As[ar * 64 + ((g0 ^ (ar & 7)) * 8)] = hv0;
    *(f16x8*)&As[ar * 64 + (((g0 + 1) ^ (ar & 7)) * 8)] = hv1;
#pragma unroll
    for (int i = 0; i < 4; ++i) {
      int rn = wid * 32 + i * 8;
      gld_lds16(BTt + (size_t)(n0 + rn + l8) * NN + k0 + lx, &Bs[rn * 64]);
    }
    __syncthreads();
#pragma unroll
    for (int ks = 0; ks < 2; ++ks) {
      f16x8 af[2], bf[4];
#pragma unroll
      for (int m = 0; m < 2; ++m)
        af[m] = *(const f16x8*)&As[((wm * 32 + m * 16 + cl) * 64 + ks * 32 +
                                    hi * 8) ^ sw];
#pragma unroll
      for (int n = 0; n < 4; ++n)
        bf[n] = *(const f16x8*)&Bs[((wn * 64 + n * 16 + cl) * 64 + ks * 32 +
                                    hi * 8) ^ sw];
#pragma unroll
      for (int m = 0; m < 2; ++m)
#pragma unroll
        for (int n = 0; n < 4; ++n)
          acc[m][n] = __builtin_amdgcn_mfma_f32_16x16x32_f16(af[m], bf[n],
                                                             acc[m][n], 0, 0, 0);
    }
    __syncthreads();
  }

  f16* dst = aggP + (size_t)kh * (4L * NN * 256) +
             ((size_t)t * NN + m0) * 256 + n0;
#pragma unroll
  for (int m = 0; m < 2; ++m)
#pragma unroll
    for (int n = 0; n < 4; ++n)
#pragma unroll
      for (int q = 0; q < 4; ++q)
        dst[(size_t)(wm * 32 + m * 16 + hi * 4 + q) * 256 + wn * 64 +
            n * 16 + cl] = (f16)acc[m][n][q];
}

// ---------------------------------------------------------------------------
// gnn_fin: g16[r] = l2norm(relu(sum of 4 aggP partials + b)).  1 wave = 1 row.
// ---------------------------------------------------------------------------
__global__ __launch_bounds__(256) void gnn_fin(const f16* __restrict__ aggP,
                                               const float* __restrict__ bgnn,
                                               f16* __restrict__ g16) {
  const int tid = threadIdx.x;
  const int lane = tid & 63, w = tid >> 6;
  const size_t r = (size_t)blockIdx.x * 4 + w;
  const long PS = 4L * NN * 256;
  size_t gi = r * 256 + lane * 4;
  f16x4 a0 = *(const f16x4*)(aggP + gi);
  f16x4 a1 = *(const f16x4*)(aggP + PS + gi);
  f16x4 a2 = *(const f16x4*)(aggP + 2 * PS + gi);
  f16x4 a3 = *(const f16x4*)(aggP + 3 * PS + gi);
  float v[4];
  float ss = 0.f;
#pragma unroll
  for (int j = 0; j < 4; ++j) {
    v[j] = (float)a0[j] + (float)a1[j] + (float)a2[j] + (float)a3[j] +
           bgnn[lane * 4 + j];
    v[j] = fmaxf(v[j], 0.f);
    ss += v[j] * v[j];
  }
  float tot = wave_sum(ss);
  tot = __shfl(tot, 0);
  float inv = 1.f / fmaxf(sqrtf(tot), 1e-12f);
  f16x4 o = {(f16)(v[0] * inv), (f16)(v[1] * inv), (f16)(v[2] * inv),
             (f16)(v[3] * inv)};
  *(f16x4*)(g16 + gi) = o;
}

// --- proven 32x32 f16 transpose: out[c][r] = in[r][c] -------------------------
__global__ __launch_bounds__(256) void transp_h(const f16* __restrict__ in,
                                                f16* __restrict__ out, int R,
                                                int C, long sIn, long sOut) {
  in += blockIdx.z * sIn;
  out += blockIdx.z * sOut;
  __shared__ float tile[32][33];
  int c0 = blockIdx.x * 32, r0 = blockIdx.y * 32;
  int tx = threadIdx.x & 31, ty = threadIdx.x >> 5;
#pragma unroll
  for (int i = 0; i < 32; i += 8)
    tile[ty + i][tx] = (float)in[(size_t)(r0 + ty + i) * C + c0 + tx];
  __syncthreads();
#pragma unroll
  for (int i = 0; i < 32; i += 8)
    out[(size_t)(c0 + ty + i) * R + r0 + tx] = (f16)tile[tx][ty + i];
}

// --- sum 4 K-split partials -> h f32 + f16 -----------------------------------
__global__ __launch_bounds__(256) void hsum4(const float* __restrict__ hP,
                                             float* __restrict__ hf,
                                             f16* __restrict__ h16) {
  long i = ((long)blockIdx.x * 256 + threadIdx.x) * 4;
  float4 a = *(const float4*)(hP + i);
  float4 b = *(const float4*)(hP + 524288 + i);
  float4 c = *(const float4*)(hP + 1048576 + i);
  float4 d = *(const float4*)(hP + 1572864 + i);
  float4 s = {a.x + b.x + c.x + d.x, a.y + b.y + c.y + d.y,
              a.z + b.z + c.z + d.z, a.w + b.w + c.w + d.w};
  *(float4*)(hf + i) = s;
  f16x4 o = {(f16)s.x, (f16)s.y, (f16)s.z, (f16)s.w};
  *(f16x4*)(h16 + i) = o;
}

// --- t=0 shortcut: rnn0 = sigmoid(Xg_u+bg)*tanh(Xc+bc), transposed ----------
__global__ __launch_bounds__(256) void rnn0_t(const f16* __restrict__ Xgc,
                                              const float* __restrict__ bg,
                                              const float* __restrict__ bc,
                                              f16* __restrict__ rnnT) {
  __shared__ float tile[32][33];
  int n0 = blockIdx.x * 32, k0 = blockIdx.y * 32;
  int tx = threadIdx.x & 31, ty = threadIdx.x >> 5;
#pragma unroll
  for (int i = 0; i < 32; i += 8) {
    int n = n0 + ty + i, k = k0 + tx;
    float u = 1.f / (1.f + __expf(-((float)Xgc[(size_t)n * 768 + 256 + k] +
                                    bg[256 + k])));
    float c = tanhf((float)Xgc[(size_t)n * 768 + 512 + k] + bc[k]);
    tile[ty + i][tx] = u * c;
  }
  __syncthreads();
#pragma unroll
  for (int i = 0; i < 32; i += 8)
    rnnT[(size_t)(k0 + ty + i) * NN + n0 + tx] = (f16)tile[tx][ty + i];
}

// ---------------------------------------------------------------------------
// gru_step: one kernel per scan step (t>=1).  16 rows per block, grid 128.
// ---------------------------------------------------------------------------
__global__ __launch_bounds__(256) void gru_step(
    const float* __restrict__ hP, const f16* __restrict__ Xgc,
    const f16* __restrict__ WghT, const f16* __restrict__ WchT,
    const float* __restrict__ bg, const float* __restrict__ bc,
    f16* __restrict__ rnnT) {
  __shared__ alignas(16) f16 A_s[16 * 264];
  __shared__ alignas(16) f16 rh_s[16 * 264];
  __shared__ float u_s[16 * 260];
  __shared__ float hf_s[16 * 260];
  __shared__ alignas(16) f16 tileT[256 * 24];
  const int tid = threadIdx.x;
  const int lane = tid & 63, wid = tid >> 6;
  const int cl = lane & 15, hi = lane >> 4;
  const int r0 = blockIdx.x * 16;

#pragma unroll
  for (int i = 0; i < 4; ++i) {
    int e = i * 256 + tid;
    int row = e >> 6, off = (e & 63) * 4;
    size_t gi = (size_t)(r0 + row) * 256 + off;
    float4 a = *(const float4*)(hP + gi);
    float4 b = *(const float4*)(hP + 524288 + gi);
    float4 c = *(const float4*)(hP + 1048576 + gi);
    float4 d = *(const float4*)(hP + 1572864 + gi);
    float4 s = {a.x + b.x + c.x + d.x, a.y + b.y + c.y + d.y,
                a.z + b.z + c.z + d.z, a.w + b.w + c.w + d.w};
    *(float4*)&hf_s[row * 260 + off] = s;
    f16x4 h4 = {(f16)s.x, (f16)s.y, (f16)s.z, (f16)s.w};
    *(f16x4*)&A_s[row * 264 + off] = h4;
  }
  __syncthreads();

  const int wc0 = wid * 128;
  f32x4 acc[8];
#pragma unroll
  for (int n = 0; n < 8; ++n) acc[n] = (f32x4){0.f, 0.f, 0.f, 0.f};
#pragma unroll
  for (int kk = 0; kk < 256; kk += 32) {
    f16x8 af = *(const f16x8*)&A_s[cl * 264 + kk + hi * 8];
#pragma unroll
    for (int n = 0; n < 8; ++n) {
      f16x8 bf = *(const f16x8*)(WghT + (size_t)(wc0 + n * 16 + cl) * 256 +
                                 kk + hi * 8);
      acc[n] = __builtin_amdgcn_mfma_f32_16x16x32_f16(af, bf, acc[n], 0, 0, 0);
    }
  }
#pragma unroll
  for (int n = 0; n < 8; ++n) {
    int cc = wc0 + n * 16 + cl;
    float bgv = bg[cc];
#pragma unroll
    for (int q = 0; q < 4; ++q) {
      int rl = hi * 4 + q;
      float v = acc[n][q] + bgv + (float)Xgc[(size_t)(r0 + rl) * 768 + cc];
      float sv = 1.f / (1.f + __expf(-v));
      if (cc < 256)
        rh_s[rl * 264 + cc] = (f16)(sv * hf_s[rl * 260 + cc]);
      else
        u_s[rl * 260 + cc - 256] = sv;
    }
  }
  __syncthreads();

  const int wc2 = wid * 64;
  f32x4 acc2[4];
#pragma unroll
  for (int n = 0; n < 4; ++n) acc2[n] = (f32x4){0.f, 0.f, 0.f, 0.f};
#pragma unroll
  for (int kk = 0; kk < 256; kk += 32) {
    f16x8 af = *(const f16x8*)&rh_s[cl * 264 + kk + hi * 8];
#pragma unroll
    for (int n = 0; n < 4; ++n) {
      f16x8 bf = *(const f16x8*)(WchT + (size_t)(wc2 + n * 16 + cl) * 256 +
                                 kk + hi * 8);
      acc2[n] = __builtin_amdgcn_mfma_f32_16x16x32_f16(af, bf, acc2[n], 0, 0, 0);
    }
  }
#pragma unroll
  for (int n = 0; n < 4; ++n) {
    int cc = wc2 + n * 16 + cl;
    float bcv = bc[cc];
#pragma unroll
    for (int q = 0; q < 4; ++q) {
      int rl = hi * 4 + q;
      float cv = tanhf(acc2[n][q] + bcv +
                       (float)Xgc[(size_t)(r0 + rl) * 768 + 512 + cc]);
      float u = u_s[rl * 260 + cc];
      float hv = hf_s[rl * 260 + cc];
      tileT[cc * 24 + rl] = (f16)((1.f - u) * hv + u * cv);
    }
  }
  __syncthreads();
  {
    int cc = tid;
    *(f16x8*)&rnnT[(size_t)cc * NN + r0] = *(const f16x8*)&tileT[cc * 24];
    *(f16x8*)&rnnT[(size_t)cc * NN + r0 + 8] =
        *(const f16x8*)&tileT[cc * 24 + 8];
  }
}

// ---------------------------------------------------------------------------
// Fused P/Q/decode
// ---------------------------------------------------------------------------
__global__ __launch_bounds__(256) void pq_decode(
    const f16* __restrict__ emb, const f16* __restrict__ scal,
    const float* __restrict__ sq, float* __restrict__ out) {
  __shared__ alignas(16) f16 EA[128 * 64], EB[128 * 64], SA[128 * 64],
      SB[128 * 64];
  const int tid = threadIdx.x;
  const int lane = tid & 63, wid = tid >> 6;
  const int wm = wid >> 1, wn = wid & 1;
  const int row0 = blockIdx.y * 128, col0 = blockIdx.x * 128;
  const int l8 = lane >> 3;
  const int lx = ((lane & 7) ^ l8) * 8;
  const int sw = (lane & 7) * 8;
#pragma unroll
  for (int i = 0; i < 2; ++i) {
    int r = wid * 16 + i * 8;
    gld_lds16(emb + (size_t)(row0 + r + l8) * 64 + lx, &EA[r * 64]);
    gld_lds16(emb + (size_t)(col0 + r + l8) * 64 + lx, &EB[r * 64]);
    gld_lds16(scal + (size_t)(row0 + r + l8) * 64 + lx, &SA[r * 64]);
    gld_lds16(scal + (size_t)(col0 + r + l8) * 64 + lx, &SB[r * 64]);
    int r2 = r + 64;
    gld_lds16(emb + (size_t)(row0 + r2 + l8) * 64 + lx, &EA[r2 * 64]);
    gld_lds16(emb + (size_t)(col0 + r2 + l8) * 64 + lx, &EB[r2 * 64]);
    gld_lds16(scal + (size_t)(row0 + r2 + l8) * 64 + lx, &SA[r2 * 64]);
    gld_lds16(scal + (size_t)(col0 + r2 + l8) * 64 + lx, &SB[r2 * 64]);
  }
  __syncthreads();
  f32x4 accP[4][4], accQ[4][4];
#pragma unroll
  for (int m = 0; m < 4; ++m)
#pragma unroll
    for (int n = 0; n < 4; ++n) {
      accP[m][n] = (f32x4){0.f, 0.f, 0.f, 0.f};
      accQ[m][n] = (f32x4){0.f, 0.f, 0.f, 0.f};
    }
#pragma unroll
  for (int ks = 0; ks < 2; ++ks) {
    f16x8 af[4], bf[4];
#pragma unroll
    for (int m = 0; m < 4; ++m)
      af[m] = *(const f16x8*)&EA[((wm * 64 + m * 16 + (lane & 15)) * 64 +
                                  ks * 32 + (lane >> 4) * 8) ^ sw];
#pragma unroll
    for (int n = 0; n < 4; ++n)
      bf[n] = *(const f16x8*)&EB[((wn * 64 + n * 16 + (lane & 15)) * 64 +
                                  ks * 32 + (lane >> 4) * 8) ^ sw];
#pragma unroll
    for (int m = 0; m < 4; ++m)
#pragma unroll
      for (int n = 0; n < 4; ++n)
        accP[m][n] = __builtin_amdgcn_mfma_f32_16x16x32_f16(af[m], bf[n],
                                                            accP[m][n], 0, 0, 0);
#pragma unroll
    for (int m = 0; m < 4; ++m)
      af[m] = *(const f16x8*)&SA[((wm * 64 + m * 16 + (lane & 15)) * 64 +
                                  ks * 32 + (lane >> 4) * 8) ^ sw];
#pragma unroll
    for (int n = 0; n < 4; ++n)
      bf[n] = *(const f16x8*)&SB[((wn * 64 + n * 16 + (lane & 15)) * 64 +
                                  ks * 32 + (lane >> 4) * 8) ^ sw];
#pragma unroll
    for (int m = 0; m < 4; ++m)
#pragma unroll
      for (int n = 0; n < 4; ++n)
        accQ[m][n] = __builtin_amdgcn_mfma_f32_16x16x32_f16(af[m], bf[n],
                                                            accQ[m][n], 0, 0, 0);
  }
  const int cl = lane & 15, rh4 = (lane >> 4) * 4;
#pragma unroll
  for (int m = 0; m < 4; ++m) {
#pragma unroll
    for (int n = 0; n < 4; ++n) {
      int c = col0 + wn * 64 + n * 16 + cl;
      float sqc = sq[c];
#pragma unroll
      for (int q = 0; q < 4; ++q) {
        size_t r = row0 + wm * 64 + m * 16 + rh4 + q;
        float dist = -(sq[r] + sqc - 2.f * accP[m][n][q]);
        out[r * NN + c] = 1.f + tanhf(dist * accQ[m][n][q]);
      }
    }
  }
}

// --- fused transpose+convert of the weight matrices --------------------------
struct MT {
  const float* src[11];
  f16* dst[11];
  int K[11], N[11], st[11], ts[12];
};
__global__ __launch_bounds__(256) void multi_transp(MT mt) {
  __shared__ float tile[32][33];
  int b = blockIdx.x, w = 0;
  while (b >= mt.ts[w + 1]) ++w;
  int lt = b - mt.ts[w];
  int K = mt.K[w], N = mt.N[w];
  int tk = lt % (K >> 5), tn = lt / (K >> 5);
  int k0 = tk * 32, n0 = tn * 32;
  int tx = threadIdx.x & 31, ty = threadIdx.x >> 5;
  const float* src = mt.src[w];
#pragma unroll
  for (int i = 0; i < 32; i += 8)
    tile[ty + i][tx] = src[(size_t)(k0 + ty + i) * N + n0 + tx];
  __syncthreads();
  f16* dst = mt.dst[w];
  int st = mt.st[w];
#pragma unroll
  for (int i = 0; i < 32; i += 8)
    dst[(size_t)(n0 + ty + i) * st + k0 + tx] = (f16)tile[tx][ty + i];
}

// --- f32 -> fp16 convert: feat then noise (one launch) -----------------------
__global__ __launch_bounds__(256) void cvt2(const float* __restrict__ feat,
                                            f16* __restrict__ feat16,
                                            const float* __restrict__ noise,
                                            f16* __restrict__ noise16) {
  const long FN4 = 5L * NN * F_IN;
  long i = ((long)blockIdx.x * 256 + threadIdx.x) * 4;
  const float* src;
  f16* dst;
  long j;
  if (i < FN4) {
    src = feat; dst = feat16; j = i;
  } else {
    src = noise; dst = noise16; j = i - FN4;
  }
  float4 v = *(const float4*)(src + j);
  f16x4 o = {(f16)v.x, (f16)v.y, (f16)v.z, (f16)v.w};
  *(f16x4*)(dst + j) = o;
}

// --- row softmax (f32) + mix with align -> fp16 -------------------------------
__global__ __launch_bounds__(256) void softmax_mix(
    const float* __restrict__ S, const float* __restrict__ Al,
    const float* __restrict__ lam_ptr, f16* __restrict__ Mh) {
  const int tid = threadIdx.x;
  const float4* s4 = (const float4*)(S + (size_t)blockIdx.x * 2048);
  float4 a = s4[tid], b = s4[tid + 256];
  float m = fmaxf(fmaxf(fmaxf(a.x, a.y), fmaxf(a.z, a.w)),
                  fmaxf(fmaxf(b.x, b.y), fmaxf(b.z, b.w)));
  __shared__ float red[4];
  float w = wave_max(m);
  if ((tid & 63) == 0) red[tid >> 6] = w;
  __syncthreads();
  m = fmaxf(fmaxf(red[0], red[1]), fmaxf(red[2], red[3]));
  __syncthreads();
  a.x = __expf(a.x - m); a.y = __expf(a.y - m);
  a.z = __expf(a.z - m); a.w = __expf(a.w - m);
  b.x = __expf(b.x - m); b.y = __expf(b.y - m);
  b.z = __expf(b.z - m); b.w = __expf(b.w - m);
  float s = a.x + a.y + a.z + a.w + b.x + b.y + b.z + b.w;
  w = wave_sum(s);
  if ((tid & 63) == 0) red[tid >> 6] = w;
  __syncthreads();
  float inv = 1.f / (red[0] + red[1] + red[2] + red[3]);
  float lam = lam_ptr[0], oml = 1.f - lam;
  const float4* al4 = (const float4*)(Al + (size_t)blockIdx.x * 2048);
  float4 x = al4[tid], y = al4[tid + 256];
  f16x4 o0 = {(f16)(lam * x.x + oml * a.x * inv),
              (f16)(lam * x.y + oml * a.y * inv),
              (f16)(lam * x.z + oml * a.z * inv),
              (f16)(lam * x.w + oml * a.w * inv)};
  f16x4 o1 = {(f16)(lam * y.x + oml * b.x * inv),
              (f16)(lam * y.y + oml * b.y * inv),
              (f16)(lam * y.z + oml * b.z * inv),
              (f16)(lam * y.w + oml * b.w * inv)};
  f16x4* out4 = (f16x4*)(Mh + (size_t)blockIdx.x * 2048);
  out4[tid] = o0;
  out4[tid + 256] = o1;
}

// --- column L2 norms of emb0 [N,64] ------------------------------------------
__global__ __launch_bounds__(256) void col_l2norm64(
    const float* __restrict__ x, float* __restrict__ cn) {
  int c = blockIdx.x;
  float ss = 0.f;
  for (int r = threadIdx.x; r < NN; r += 256) {
    float v = x[(long)r * 64 + c];
    ss += v * v;
  }
  __shared__ float red[4];
  float w = wave_sum(ss);
  if ((threadIdx.x & 63) == 0) red[threadIdx.x >> 6] = w;
  __syncthreads();
  if (threadIdx.x == 0)
    cn[c] = fmaxf(sqrtf(red[0] + red[1] + red[2] + red[3]), 1e-12f);
}

// --- emb16 = emb0/cn ; sq[i] = row sumsq -------------------------------------
__global__ void norm_sq64h(const float* __restrict__ x,
                           const float* __restrict__ cn,
                           f16* __restrict__ emb16, float* __restrict__ sq) {
  int i = blockIdx.x, j = threadIdx.x;
  float e = x[(long)i * 64 + j] / cn[j];
  emb16[(long)i * 64 + j] = (f16)e;
  float s = wave_sum(e * e);
  if (j == 0) sq[i] = s;
}

// ---------------------------------------------------------------------------
extern "C" void kernel_launch(void* const* d_in, const int* in_sizes, int n_in,
                              void* d_out, int out_size, void* d_ws,
                              size_t ws_size, hipStream_t stream) {
  (void)in_sizes; (void)n_in; (void)out_size; (void)ws_size;
  const float* sup    = (const float*)d_in[0];
  const float* feat   = (const float*)d_in[1];
  const float* noise  = (const float*)d_in[2];
  const float* align  = (const float*)d_in[3];
  const float* lambd  = (const float*)d_in[4];
  const float* W_fem  = (const float*)d_in[5];
  const float* b_fem  = (const float*)d_in[6];
  const float* W_gnn  = (const float*)d_in[7];
  const float* b_gnn  = (const float*)d_in[8];
  const float* Wg_x   = (const float*)d_in[9];
  const float* Wg_h   = (const float*)d_in[10];
  const float* bg     = (const float*)d_in[11];
  const float* Wc_x   = (const float*)d_in[12];
  const float* Wc_h   = (const float*)d_in[13];
  const float* bc     = (const float*)d_in[14];
  const float* W_att  = (const float*)d_in[15];
  const float* b_att  = (const float*)d_in[16];
  const float* W_emb1 = (const float*)d_in[17];
  const float* b_emb1 = (const float*)d_in[18];
  const float* W_emb2 = (const float*)d_in[19];
  const float* b_emb2 = (const float*)d_in[20];
  const float* W_scal1= (const float*)d_in[21];
  const float* b_scal1= (const float*)d_in[22];
  const float* W_scal2= (const float*)d_in[23];
  const float* b_scal2= (const float*)d_in[24];

  char* wsb = (char*)d_ws;
  size_t po = 0;
  auto P = [&](size_t bytes) {
    size_t r = po;
    po += (bytes + 255) & ~(size_t)255;
    return r;
  };
  f16* fem16  = (f16*)(wsb + P(5L * NN * HF * 2));
  f16* fm16   = (f16*)(wsb + P(5L * NN * HH * 2));
  f16* g16    = (f16*)(wsb + P(4L * NN * HH * 2));
  f16* WT     = (f16*)(wsb + P(884736L * 2));
  f16* Xgc16  = (f16*)(wsb + P(4L * NN * 768 * 2));
  float* hA   = (float*)(wsb + P((long)NN * HH * 4));
  f16* h16A   = (f16*)(wsb + P((long)NN * HH * 2));
  f16* rnnT16 = (f16*)(wsb + P((long)NN * HH * 2));
  float* hP   = (float*)(wsb + P(4L * NN * HH * 4));
  f16* M16_2  = (f16*)(wsb + P(2L * NN * NN * 2));
  f16* e1s1   = (f16*)(wsb + P((long)NN * 512 * 2));
  float* embscF = (float*)(wsb + P(2L * NN * E2D * 4));
  f16* embsc16  = (f16*)(wsb + P(2L * NN * E2D * 2));
  f16* emb16  = (f16*)(wsb + P((long)NN * E2D * 2));
  float* cn   = (float*)(wsb + P(64 * 4));
  float* sq   = (float*)(wsb + P(NN * 4));
  // arena: feat16 | noise16 | edmW | edmWT | aggP early; Sbuf2 aliases later
  size_t arena = P(34078720);
  f16* feat16  = (f16*)(wsb + arena);                 //  2,621,440 B
  f16* noise16 = (f16*)(wsb + arena + 2621440);       //  2,097,152 B
  f16* edmW    = (f16*)(wsb + arena + 4718592);       //  4,194,304 B
  f16* edmWT   = (f16*)(wsb + arena + 8912896);       //  4,194,304 B
  f16* aggP    = (f16*)(wsb + arena + 13107200);      // 16,777,216 B
  float* Sbuf2 = (float*)(wsb + arena);               // 33,554,432 B

  // --- weight transpose table -------------------------------------------------
  f16* W_femT  = WT;                       // 256x128
  f16* W_gnnT  = W_femT + 32768;           // 256x384
  f16* WgxcT   = W_gnnT + 98304;           // 768x256 ([Wgx^T; Wcx^T])
  f16* WghT    = WgxcT + 196608;           // 512x256
  f16* WchT    = WghT + 131072;            // 256x256
  f16* W_attT  = WchT + 65536;             // 256x256
  f16* We1s1T  = W_attT + 65536;           // 512x512 ([Wemb1^T; Wscal1^T])
  f16* Wemb2T  = We1s1T + 262144;          // 64x256
  f16* Wscal2T = Wemb2T + 16384;           // 64x256 (adjacent: zB=16384)

  MT mt;
  const float* wsrc[11] = {W_fem, W_gnn, Wg_x, Wc_x, Wg_h, Wc_h,
                           W_att, W_emb1, W_scal1, W_emb2, W_scal2};
  f16* wdst[11] = {W_femT, W_gnnT, WgxcT, WgxcT + 512 * 256, WghT, WchT,
                   W_attT, We1s1T, We1s1T + 256 * 512, Wemb2T, Wscal2T};
  const int wK[11]  = {128, 384, 256, 256, 256, 256, 256, 512, 512, 256, 256};
  const int wNd[11] = {256, 256, 512, 256, 512, 256, 256, 256, 256, 64, 64};
  const int wSt[11] = {128, 384, 256, 256, 256, 256, 256, 512, 512, 256, 256};
  int tcum = 0;
  for (int i = 0; i < 11; ++i) {
    mt.src[i] = wsrc[i];
    mt.dst[i] = wdst[i];
    mt.K[i] = wK[i];
    mt.N[i] = wNd[i];
    mt.st[i] = wSt[i];
    mt.ts[i] = tcum;
    tcum += (wK[i] >> 5) * (wNd[i] >> 5);
  }
  mt.ts[11] = tcum;

  const f16* NH = nullptr;
  float* NF = nullptr;
  f16* NHm = nullptr;

  multi_transp<<<tcum, 256, 0, stream>>>(mt);
  cvt2<<<(5L * NN * F_IN + 4L * NN * DZ) / 1024, 256, 0, stream>>>(
      feat, feat16, noise, noise16);

  // FEM: fem16 = relu(feat @ W_fem + b)
  hgemm<1, 64, 1><<<dim3(4, 80, 1), 256, 0, stream>>>(
      feat16, NH, W_femT, b_fem, nullptr, NF, fem16,
      128, 0, 128, 128, 256, 128, 0, 0, 0, 0);

  // edmW[t][n][c] = edm[t][n] @ Wgnn  (A dual-source: fem16|noise16 at k=256)
  hgemm<0, 64, 1><<<dim3(4, 16, 4), 256, 0, stream>>>(
      fem16, noise16, W_gnnT, nullptr, nullptr, NF, edmW,
      256, 128, 256, 384, 256, 384,
      (long)NN * HF, (long)NN * DZ, 0, (long)NN * 256);

  // edmWT[t][c][n] = edmW[t][n][c]^T  (proven 32x32 transpose)
  transp_h<<<dim3(8, 64, 4), 256, 0, stream>>>(
      edmW, edmWT, NN, 256, (long)NN * 256, 256L * NN);

  // sup @ edmW partials + finalize (bias+relu+l2norm)
  sup_gnn2<<<dim3(32, 2, 16), 256, 0, stream>>>(sup, edmWT, aggP);
  gnn_fin<<<2048, 256, 0, stream>>>(aggP, b_gnn, g16);

  // fm16 = fem @ W_att + b
  hgemm<0, 64, 1><<<dim3(4, 80, 1), 256, 0, stream>>>(
      fem16, NH, W_attT, b_att, nullptr, NF, fm16,
      256, 0, 256, 256, 256, 256, 0, 0, 0, 0);

  // Xgc = g16 @ [Wgx | Wcx]  -> [8192 x 768] f16 pre-activations
  hgemm<0, 64, 1><<<dim3(12, 64, 1), 256, 0, stream>>>(
      g16, NH, WgxcT, nullptr, nullptr, NF, Xgc16,
      256, 0, 256, 256, 768, 256, 0, 0, 0, 0);

  for (int p = 0; p < 2; ++p) {
    // S pair (f32 out): S[z] = fm[2p+z+1] @ fm[2p+z]^T
    hgemm<0, 128, 0><<<dim3(16, 16, 2), 256, 0, stream>>>(
        fm16 + (size_t)(2 * p + 1) * NN * HH, NH,
        fm16 + (size_t)(2 * p) * NN * HH, nullptr, nullptr, Sbuf2, NHm,
        256, 0, 256, 256, 2048, 256,
        (long)NN * HH, 0, (long)NN * HH, (long)NN * NN);
    softmax_mix<<<2 * NN, 256, 0, stream>>>(
        Sbuf2, align + (size_t)(2 * p) * NN * NN, lambd, M16_2);

    for (int tl = 0; tl < 2; ++tl) {
      int t = 2 * p + tl;
      if (t == 0) {
        rnn0_t<<<dim3(64, 8, 1), 256, 0, stream>>>(Xgc16, bg, bc, rnnT16);
      } else {
        gru_step<<<128, 256, 0, stream>>>(
            hP, Xgc16 + (size_t)t * NN * 768, WghT, WchT, bg, bc, rnnT16);
      }
      // h_{t} partials = M16 @ rnn (K-split x4)
      hgemm<0, 64, 0><<<dim3(4, 16, 4), 256, 0, stream>>>(
          M16_2 + (size_t)(t & 1) * NN * NN, NH, rnnT16, nullptr, nullptr,
          hP, NHm, 2048, 0, 2048, 2048, 256, 512,
          512, 0, 512, 524288);
    }
  }
  // final h for EAM
  hsum4<<<512, 256, 0, stream>>>(hP, hA, h16A);

  // --- EAM tail ---------------------------------------------------------------
  hgemm<6, 64, 1><<<dim3(8, 16, 1), 256, 0, stream>>>(
      h16A, fem16 + 4L * NN * HF, We1s1T, b_emb1, b_scal1, NF, e1s1,
      256, 256, 256, 512, 512, 512, 0, 0, 0, 0);
  // FIX: zA=256 — z=1 (scal head) must read the s1 half of e1s1.
  hgemm<5, 64, 2><<<dim3(1, 16, 2), 256, 0, stream>>>(
      e1s1, NH, Wemb2T, b_emb2, b_scal2, embscF, embsc16,
      512, 0, 512, 256, 64, 256, 256, 0, 16384, (long)NN * E2D);
  col_l2norm64<<<64, 256, 0, stream>>>(embscF, cn);
  norm_sq64h<<<NN, 64, 0, stream>>>(embscF, cn, emb16, sq);

  pq_decode<<<dim3(16, 16, 1), 256, 0, stream>>>(
      emb16, embsc16 + (size_t)NN * E2D, sq, (float*)d_out);
}

// Round 12
// 310.343 us; speedup vs baseline: 1.2700x; 1.0165x over previous
//
#include <hip/hip_runtime.h>
#include <math.h>

// ---------------------------------------------------------------------------
// GenNet_tanh forward, round 12: R11 (passing) +
//  - apply GEMM K-split x8 (512 blocks; gru_step sums 8 partials; hsum8)
//  - cvt2 merged into multi_transp (one fewer dispatch)
// ---------------------------------------------------------------------------

#define T_WIN 4
#define NN 2048
#define F_IN 128
#define HF 256
#define HH 256
#define DZ 128
#define G_IN 384
#define EIN 512
#define E1D 256
#define E2D 64

typedef _Float16 f16;
typedef _Float16 f16x8 __attribute__((ext_vector_type(8)));
typedef _Float16 f16x4 __attribute__((ext_vector_type(4)));
typedef float f32x4 __attribute__((ext_vector_type(4)));

__device__ __forceinline__ float wave_sum(float v) {
#pragma unroll
  for (int o = 32; o > 0; o >>= 1) v += __shfl_down(v, o);
  return v;
}
__device__ __forceinline__ float wave_max(float v) {
#pragma unroll
  for (int o = 32; o > 0; o >>= 1) v = fmaxf(v, __shfl_down(v, o));
  return v;
}

__device__ __forceinline__ void gld_lds16(const void* g, void* l) {
  __builtin_amdgcn_global_load_lds(
      (const __attribute__((address_space(1))) unsigned int*)g,
      (__attribute__((address_space(3))) unsigned int*)l, 16, 0, 0);
}

// ---------------------------------------------------------------------------
// fp16 MFMA GEMM, 128 x BN tile, BK=64, 256 threads (4 waves 2x2).
// A: [.,lda] row-major; dual-source: k<kspl from A, else A2 (lda2).
// BT: [N,ldb] row-major.  grid.z advances A by zA, A2 by zA2, BT by zB,
// C by zC.  EPI: 0 none, 1 relu, 5 z-sel tanh/sig, 6 col-sel.
// WOUT: 0 f32, 1 f16, 2 both.
// ---------------------------------------------------------------------------
template <int EPI, int BN, int WOUT>
__global__ __launch_bounds__(256) void hgemm(
    const f16* __restrict__ A, const f16* __restrict__ A2,
    const f16* __restrict__ BT, const float* __restrict__ bias,
    const float* __restrict__ bias2, float* __restrict__ Cf,
    f16* __restrict__ Ch, int lda, int lda2, int kspl, int ldb, int ldc,
    int K, long zA, long zA2, long zB, long zC) {
  constexpr int WN = BN / 2;
  constexpr int FN = WN / 16;
  constexpr int BI = BN / 32;
  __shared__ alignas(16) f16 As[128 * 64];
  __shared__ alignas(16) f16 Bs[BN * 64];
  const int tid = threadIdx.x;
  const int lane = tid & 63, wid = tid >> 6;
  const int wm = wid >> 1, wn = wid & 1;
  const int row0 = blockIdx.y * 128, col0 = blockIdx.x * BN;
  const long zb = blockIdx.z;
  A += zb * zA;
  if (A2) A2 += zb * zA2;
  BT += zb * zB;
  const int l8 = lane >> 3;
  const int lx = ((lane & 7) ^ l8) * 8;  // pre-swizzled source chunk
  const int sw = (lane & 7) * 8;         // frag-read XOR

  f32x4 acc[4][FN];
#pragma unroll
  for (int m = 0; m < 4; ++m)
#pragma unroll
    for (int n = 0; n < FN; ++n) acc[m][n] = (f32x4){0.f, 0.f, 0.f, 0.f};

  for (int k0 = 0; k0 < K; k0 += 64) {
#pragma unroll
    for (int i = 0; i < 4; ++i) {
      int r = wid * 32 + i * 8;
      const f16* src =
          (k0 < kspl) ? A + (size_t)(row0 + r + l8) * lda + k0 + lx
                      : A2 + (size_t)(row0 + r + l8) * lda2 + (k0 - kspl) + lx;
      gld_lds16(src, &As[r * 64]);
    }
#pragma unroll
    for (int i = 0; i < BI; ++i) {
      int r = wid * (BN / 4) + i * 8;
      gld_lds16(BT + (size_t)(col0 + r + l8) * ldb + k0 + lx, &Bs[r * 64]);
    }
    __syncthreads();
#pragma unroll
    for (int ks = 0; ks < 2; ++ks) {
      f16x8 af[4], bf[FN];
#pragma unroll
      for (int m = 0; m < 4; ++m)
        af[m] = *(const f16x8*)&As[((wm * 64 + m * 16 + (lane & 15)) * 64 +
                                    ks * 32 + (lane >> 4) * 8) ^ sw];
#pragma unroll
      for (int n = 0; n < FN; ++n)
        bf[n] = *(const f16x8*)&Bs[((wn * WN + n * 16 + (lane & 15)) * 64 +
                                    ks * 32 + (lane >> 4) * 8) ^ sw];
#pragma unroll
      for (int m = 0; m < 4; ++m)
#pragma unroll
        for (int n = 0; n < FN; ++n)
          acc[m][n] = __builtin_amdgcn_mfma_f32_16x16x32_f16(af[m], bf[n],
                                                             acc[m][n], 0, 0, 0);
    }
    __syncthreads();
  }

  const int cl = lane & 15, rh4 = (lane >> 4) * 4;
  float* Cfb = Cf + zb * zC;
  f16* Chb = Ch + zb * zC;
  const float* bp = (EPI == 5 && zb == 1) ? bias2 : bias;
#pragma unroll
  for (int m = 0; m < 4; ++m) {
#pragma unroll
    for (int n = 0; n < FN; ++n) {
      int cc = col0 + wn * WN + n * 16 + cl;
      float bv = 0.f;
      if (EPI == 6)
        bv = (cc < 256) ? bias[cc] : bias2[cc - 256];
      else if (bp)
        bv = bp[cc];
#pragma unroll
      for (int q = 0; q < 4; ++q) {
        size_t r = row0 + wm * 64 + m * 16 + rh4 + q;
        float v = acc[m][n][q] + bv;
        if (EPI == 1) v = fmaxf(v, 0.f);
        if (EPI == 5) v = (zb == 0) ? tanhf(v) : 1.f / (1.f + __expf(-v));
        if (EPI == 6) v = (cc < 256) ? tanhf(v) : 1.f / (1.f + __expf(-v));
        if (WOUT == 0 || WOUT == 2) Cfb[r * ldc + cc] = v;
        if (WOUT == 1 || WOUT == 2) Chb[r * ldc + cc] = (f16)v;
      }
    }
  }
}

// ---------------------------------------------------------------------------
// sup_gnn2: aggP partials of sup @ edmW.  Tile 64 rows x 128 cols x K=512.
// grid (32, 2, 16): x=m, y=n-half, z = t*4 + kh.  LDS 24 KB.
// ---------------------------------------------------------------------------
__global__ __launch_bounds__(256) void sup_gnn2(
    const float* __restrict__ sup, const f16* __restrict__ edmWT,
    f16* __restrict__ aggP) {
  __shared__ alignas(16) f16 As[64 * 64];
  __shared__ alignas(16) f16 Bs[128 * 64];
  const int tid = threadIdx.x;
  const int lane = tid & 63, wid = tid >> 6;
  const int m0 = blockIdx.x * 64, n0 = blockIdx.y * 128;
  const int t = blockIdx.z >> 2, kh = blockIdx.z & 3;
  const int l8 = lane >> 3;
  const int lx = ((lane & 7) ^ l8) * 8;
  const int sw = (lane & 7) * 8;
  const int cl = lane & 15, hi = lane >> 4;
  const int wm = wid >> 1, wn = wid & 1;
  const float* supT = sup + (size_t)t * NN * NN;
  const f16* BTt = edmWT + (size_t)t * 256 * NN;

  f32x4 acc[2][4];
#pragma unroll
  for (int m = 0; m < 2; ++m)
#pragma unroll
    for (int n = 0; n < 4; ++n) acc[m][n] = (f32x4){0.f, 0.f, 0.f, 0.f};

  const int ar = tid >> 2;       // 0..63 rows
  const int g0 = (tid & 3) * 2;  // source granule pair
  const int kbeg = kh * 512;

  for (int k0 = kbeg; k0 < kbeg + 512; k0 += 64) {
    const float* ap = supT + (size_t)(m0 + ar) * NN + k0 + (tid & 3) * 16;
    float4 f0 = *(const float4*)ap;
    float4 f1 = *(const float4*)(ap + 4);
    float4 f2 = *(const float4*)(ap + 8);
    float4 f3 = *(const float4*)(ap + 12);
    f16x8 hv0 = {(f16)f0.x, (f16)f0.y, (f16)f0.z, (f16)f0.w,
                 (f16)f1.x, (f16)f1.y, (f16)f1.z, (f16)f1.w};
    f16x8 hv1 = {(f16)f2.x, (f16)f2.y, (f16)f2.z, (f16)f2.w,
                 (f16)f3.x, (f16)f3.y, (f16)f3.z, (f16)f3.w};
    *(f16x8*)&As[ar * 64 + ((g0 ^ (ar & 7)) * 8)] = hv0;
    *(f16x8*)&As[ar * 64 + (((g0 + 1) ^ (ar & 7)) * 8)] = hv1;
#pragma unroll
    for (int i = 0; i < 4; ++i) {
      int rn = wid * 32 + i * 8;
      gld_lds16(BTt + (size_t)(n0 + rn + l8) * NN + k0 + lx, &Bs[rn * 64]);
    }
    __syncthreads();
#pragma unroll
    for (int ks = 0; ks < 2; ++ks) {
      f16x8 af[2], bf[4];
#pragma unroll
      for (int m = 0; m < 2; ++m)
        af[m] = *(const f16x8*)&As[((wm * 32 + m * 16 + cl) * 64 + ks * 32 +
                                    hi * 8) ^ sw];
#pragma unroll
      for (int n = 0; n < 4; ++n)
        bf[n] = *(const f16x8*)&Bs[((wn * 64 + n * 16 + cl) * 64 + ks * 32 +
                                    hi * 8) ^ sw];
#pragma unroll
      for (int m = 0; m < 2; ++m)
#pragma unroll
        for (int n = 0; n < 4; ++n)
          acc[m][n] = __builtin_amdgcn_mfma_f32_16x16x32_f16(af[m], bf[n],
                                                             acc[m][n], 0, 0, 0);
    }
    __syncthreads();
  }

  f16* dst = aggP + (size_t)kh * (4L * NN * 256) +
             ((size_t)t * NN + m0) * 256 + n0;
#pragma unroll
  for (int m = 0; m < 2; ++m)
#pragma unroll
    for (int n = 0; n < 4; ++n)
#pragma unroll
      for (int q = 0; q < 4; ++q)
        dst[(size_t)(wm * 32 + m * 16 + hi * 4 + q) * 256 + wn * 64 +
            n * 16 + cl] = (f16)acc[m][n][q];
}

// ---------------------------------------------------------------------------
// gnn_fin: g16[r] = l2norm(relu(sum of 4 aggP partials + b)).  1 wave = 1 row.
// ---------------------------------------------------------------------------
__global__ __launch_bounds__(256) void gnn_fin(const f16* __restrict__ aggP,
                                               const float* __restrict__ bgnn,
                                               f16* __restrict__ g16) {
  const int tid = threadIdx.x;
  const int lane = tid & 63, w = tid >> 6;
  const size_t r = (size_t)blockIdx.x * 4 + w;
  const long PS = 4L * NN * 256;
  size_t gi = r * 256 + lane * 4;
  f16x4 a0 = *(const f16x4*)(aggP + gi);
  f16x4 a1 = *(const f16x4*)(aggP + PS + gi);
  f16x4 a2 = *(const f16x4*)(aggP + 2 * PS + gi);
  f16x4 a3 = *(const f16x4*)(aggP + 3 * PS + gi);
  float v[4];
  float ss = 0.f;
#pragma unroll
  for (int j = 0; j < 4; ++j) {
    v[j] = (float)a0[j] + (float)a1[j] + (float)a2[j] + (float)a3[j] +
           bgnn[lane * 4 + j];
    v[j] = fmaxf(v[j], 0.f);
    ss += v[j] * v[j];
  }
  float tot = wave_sum(ss);
  tot = __shfl(tot, 0);
  float inv = 1.f / fmaxf(sqrtf(tot), 1e-12f);
  f16x4 o = {(f16)(v[0] * inv), (f16)(v[1] * inv), (f16)(v[2] * inv),
             (f16)(v[3] * inv)};
  *(f16x4*)(g16 + gi) = o;
}

// --- proven 32x32 f16 transpose: out[c][r] = in[r][c] -------------------------
__global__ __launch_bounds__(256) void transp_h(const f16* __restrict__ in,
                                                f16* __restrict__ out, int R,
                                                int C, long sIn, long sOut) {
  in += blockIdx.z * sIn;
  out += blockIdx.z * sOut;
  __shared__ float tile[32][33];
  int c0 = blockIdx.x * 32, r0 = blockIdx.y * 32;
  int tx = threadIdx.x & 31, ty = threadIdx.x >> 5;
#pragma unroll
  for (int i = 0; i < 32; i += 8)
    tile[ty + i][tx] = (float)in[(size_t)(r0 + ty + i) * C + c0 + tx];
  __syncthreads();
#pragma unroll
  for (int i = 0; i < 32; i += 8)
    out[(size_t)(c0 + ty + i) * R + r0 + tx] = (f16)tile[tx][ty + i];
}

// --- sum 8 K-split partials -> h f32 + f16 -----------------------------------
__global__ __launch_bounds__(256) void hsum8(const float* __restrict__ hP,
                                             float* __restrict__ hf,
                                             f16* __restrict__ h16) {
  long i = ((long)blockIdx.x * 256 + threadIdx.x) * 4;
  float4 s = *(const float4*)(hP + i);
#pragma unroll
  for (int p = 1; p < 8; ++p) {
    float4 v = *(const float4*)(hP + (long)p * 524288 + i);
    s.x += v.x; s.y += v.y; s.z += v.z; s.w += v.w;
  }
  *(float4*)(hf + i) = s;
  f16x4 o = {(f16)s.x, (f16)s.y, (f16)s.z, (f16)s.w};
  *(f16x4*)(h16 + i) = o;
}

// --- t=0 shortcut: rnn0 = sigmoid(Xg_u+bg)*tanh(Xc+bc), transposed ----------
__global__ __launch_bounds__(256) void rnn0_t(const f16* __restrict__ Xgc,
                                              const float* __restrict__ bg,
                                              const float* __restrict__ bc,
                                              f16* __restrict__ rnnT) {
  __shared__ float tile[32][33];
  int n0 = blockIdx.x * 32, k0 = blockIdx.y * 32;
  int tx = threadIdx.x & 31, ty = threadIdx.x >> 5;
#pragma unroll
  for (int i = 0; i < 32; i += 8) {
    int n = n0 + ty + i, k = k0 + tx;
    float u = 1.f / (1.f + __expf(-((float)Xgc[(size_t)n * 768 + 256 + k] +
                                    bg[256 + k])));
    float c = tanhf((float)Xgc[(size_t)n * 768 + 512 + k] + bc[k]);
    tile[ty + i][tx] = u * c;
  }
  __syncthreads();
#pragma unroll
  for (int i = 0; i < 32; i += 8)
    rnnT[(size_t)(k0 + ty + i) * NN + n0 + tx] = (f16)tile[tx][ty + i];
}

// ---------------------------------------------------------------------------
// gru_step: one kernel per scan step (t>=1).  16 rows per block, grid 128.
// Sums 8 hP partials.
// ---------------------------------------------------------------------------
__global__ __launch_bounds__(256) void gru_step(
    const float* __restrict__ hP, const f16* __restrict__ Xgc,
    const f16* __restrict__ WghT, const f16* __restrict__ WchT,
    const float* __restrict__ bg, const float* __restrict__ bc,
    f16* __restrict__ rnnT) {
  __shared__ alignas(16) f16 A_s[16 * 264];
  __shared__ alignas(16) f16 rh_s[16 * 264];
  __shared__ float u_s[16 * 260];
  __shared__ float hf_s[16 * 260];
  __shared__ alignas(16) f16 tileT[256 * 24];
  const int tid = threadIdx.x;
  const int lane = tid & 63, wid = tid >> 6;
  const int cl = lane & 15, hi = lane >> 4;
  const int r0 = blockIdx.x * 16;

#pragma unroll
  for (int i = 0; i < 4; ++i) {
    int e = i * 256 + tid;
    int row = e >> 6, off = (e & 63) * 4;
    size_t gi = (size_t)(r0 + row) * 256 + off;
    float4 s = *(const float4*)(hP + gi);
#pragma unroll
    for (int p = 1; p < 8; ++p) {
      float4 v = *(const float4*)(hP + (size_t)p * 524288 + gi);
      s.x += v.x; s.y += v.y; s.z += v.z; s.w += v.w;
    }
    *(float4*)&hf_s[row * 260 + off] = s;
    f16x4 h4 = {(f16)s.x, (f16)s.y, (f16)s.z, (f16)s.w};
    *(f16x4*)&A_s[row * 264 + off] = h4;
  }
  __syncthreads();

  const int wc0 = wid * 128;
  f32x4 acc[8];
#pragma unroll
  for (int n = 0; n < 8; ++n) acc[n] = (f32x4){0.f, 0.f, 0.f, 0.f};
#pragma unroll
  for (int kk = 0; kk < 256; kk += 32) {
    f16x8 af = *(const f16x8*)&A_s[cl * 264 + kk + hi * 8];
#pragma unroll
    for (int n = 0; n < 8; ++n) {
      f16x8 bf = *(const f16x8*)(WghT + (size_t)(wc0 + n * 16 + cl) * 256 +
                                 kk + hi * 8);
      acc[n] = __builtin_amdgcn_mfma_f32_16x16x32_f16(af, bf, acc[n], 0, 0, 0);
    }
  }
#pragma unroll
  for (int n = 0; n < 8; ++n) {
    int cc = wc0 + n * 16 + cl;
    float bgv = bg[cc];
#pragma unroll
    for (int q = 0; q < 4; ++q) {
      int rl = hi * 4 + q;
      float v = acc[n][q] + bgv + (float)Xgc[(size_t)(r0 + rl) * 768 + cc];
      float sv = 1.f / (1.f + __expf(-v));
      if (cc < 256)
        rh_s[rl * 264 + cc] = (f16)(sv * hf_s[rl * 260 + cc]);
      else
        u_s[rl * 260 + cc - 256] = sv;
    }
  }
  __syncthreads();

  const int wc2 = wid * 64;
  f32x4 acc2[4];
#pragma unroll
  for (int n = 0; n < 4; ++n) acc2[n] = (f32x4){0.f, 0.f, 0.f, 0.f};
#pragma unroll
  for (int kk = 0; kk < 256; kk += 32) {
    f16x8 af = *(const f16x8*)&rh_s[cl * 264 + kk + hi * 8];
#pragma unroll
    for (int n = 0; n < 4; ++n) {
      f16x8 bf = *(const f16x8*)(WchT + (size_t)(wc2 + n * 16 + cl) * 256 +
                                 kk + hi * 8);
      acc2[n] = __builtin_amdgcn_mfma_f32_16x16x32_f16(af, bf, acc2[n], 0, 0, 0);
    }
  }
#pragma unroll
  for (int n = 0; n < 4; ++n) {
    int cc = wc2 + n * 16 + cl;
    float bcv = bc[cc];
#pragma unroll
    for (int q = 0; q < 4; ++q) {
      int rl = hi * 4 + q;
      float cv = tanhf(acc2[n][q] + bcv +
                       (float)Xgc[(size_t)(r0 + rl) * 768 + 512 + cc]);
      float u = u_s[rl * 260 + cc];
      float hv = hf_s[rl * 260 + cc];
      tileT[cc * 24 + rl] = (f16)((1.f - u) * hv + u * cv);
    }
  }
  __syncthreads();
  {
    int cc = tid;
    *(f16x8*)&rnnT[(size_t)cc * NN + r0] = *(const f16x8*)&tileT[cc * 24];
    *(f16x8*)&rnnT[(size_t)cc * NN + r0 + 8] =
        *(const f16x8*)&tileT[cc * 24 + 8];
  }
}

// ---------------------------------------------------------------------------
// Fused P/Q/decode
// ---------------------------------------------------------------------------
__global__ __launch_bounds__(256) void pq_decode(
    const f16* __restrict__ emb, const f16* __restrict__ scal,
    const float* __restrict__ sq, float* __restrict__ out) {
  __shared__ alignas(16) f16 EA[128 * 64], EB[128 * 64], SA[128 * 64],
      SB[128 * 64];
  const int tid = threadIdx.x;
  const int lane = tid & 63, wid = tid >> 6;
  const int wm = wid >> 1, wn = wid & 1;
  const int row0 = blockIdx.y * 128, col0 = blockIdx.x * 128;
  const int l8 = lane >> 3;
  const int lx = ((lane & 7) ^ l8) * 8;
  const int sw = (lane & 7) * 8;
#pragma unroll
  for (int i = 0; i < 2; ++i) {
    int r = wid * 16 + i * 8;
    gld_lds16(emb + (size_t)(row0 + r + l8) * 64 + lx, &EA[r * 64]);
    gld_lds16(emb + (size_t)(col0 + r + l8) * 64 + lx, &EB[r * 64]);
    gld_lds16(scal + (size_t)(row0 + r + l8) * 64 + lx, &SA[r * 64]);
    gld_lds16(scal + (size_t)(col0 + r + l8) * 64 + lx, &SB[r * 64]);
    int r2 = r + 64;
    gld_lds16(emb + (size_t)(row0 + r2 + l8) * 64 + lx, &EA[r2 * 64]);
    gld_lds16(emb + (size_t)(col0 + r2 + l8) * 64 + lx, &EB[r2 * 64]);
    gld_lds16(scal + (size_t)(row0 + r2 + l8) * 64 + lx, &SA[r2 * 64]);
    gld_lds16(scal + (size_t)(col0 + r2 + l8) * 64 + lx, &SB[r2 * 64]);
  }
  __syncthreads();
  f32x4 accP[4][4], accQ[4][4];
#pragma unroll
  for (int m = 0; m < 4; ++m)
#pragma unroll
    for (int n = 0; n < 4; ++n) {
      accP[m][n] = (f32x4){0.f, 0.f, 0.f, 0.f};
      accQ[m][n] = (f32x4){0.f, 0.f, 0.f, 0.f};
    }
#pragma unroll
  for (int ks = 0; ks < 2; ++ks) {
    f16x8 af[4], bf[4];
#pragma unroll
    for (int m = 0; m < 4; ++m)
      af[m] = *(const f16x8*)&EA[((wm * 64 + m * 16 + (lane & 15)) * 64 +
                                  ks * 32 + (lane >> 4) * 8) ^ sw];
#pragma unroll
    for (int n = 0; n < 4; ++n)
      bf[n] = *(const f16x8*)&EB[((wn * 64 + n * 16 + (lane & 15)) * 64 +
                                  ks * 32 + (lane >> 4) * 8) ^ sw];
#pragma unroll
    for (int m = 0; m < 4; ++m)
#pragma unroll
      for (int n = 0; n < 4; ++n)
        accP[m][n] = __builtin_amdgcn_mfma_f32_16x16x32_f16(af[m], bf[n],
                                                            accP[m][n], 0, 0, 0);
#pragma unroll
    for (int m = 0; m < 4; ++m)
      af[m] = *(const f16x8*)&SA[((wm * 64 + m * 16 + (lane & 15)) * 64 +
                                  ks * 32 + (lane >> 4) * 8) ^ sw];
#pragma unroll
    for (int n = 0; n < 4; ++n)
      bf[n] = *(const f16x8*)&SB[((wn * 64 + n * 16 + (lane & 15)) * 64 +
                                  ks * 32 + (lane >> 4) * 8) ^ sw];
#pragma unroll
    for (int m = 0; m < 4; ++m)
#pragma unroll
      for (int n = 0; n < 4; ++n)
        accQ[m][n] = __builtin_amdgcn_mfma_f32_16x16x32_f16(af[m], bf[n],
                                                            accQ[m][n], 0, 0, 0);
  }
  const int cl = lane & 15, rh4 = (lane >> 4) * 4;
#pragma unroll
  for (int m = 0; m < 4; ++m) {
#pragma unroll
    for (int n = 0; n < 4; ++n) {
      int c = col0 + wn * 64 + n * 16 + cl;
      float sqc = sq[c];
#pragma unroll
      for (int q = 0; q < 4; ++q) {
        size_t r = row0 + wm * 64 + m * 16 + rh4 + q;
        float dist = -(sq[r] + sqc - 2.f * accP[m][n][q]);
        out[r * NN + c] = 1.f + tanhf(dist * accQ[m][n][q]);
      }
    }
  }
}

// --- fused weight transpose + feat/noise f32->f16 convert ---------------------
struct MT {
  const float* src[11];
  f16* dst[11];
  int K[11], N[11], st[11], ts[12];
  const float* feat;
  f16* feat16;
  const float* noise;
  f16* noise16;
};
__global__ __launch_bounds__(256) void multi_transp(MT mt) {
  int b = blockIdx.x;
  if (b >= mt.ts[11]) {
    // convert segment: blocks [ts11, ts11+2304): feat 1280 blocks, noise 1024
    long e = ((long)(b - mt.ts[11]) * 256 + threadIdx.x) * 4;
    const long FN4 = 5L * NN * F_IN;  // 1,310,720
    const float* src;
    f16* dst;
    long j;
    if (e < FN4) {
      src = mt.feat; dst = mt.feat16; j = e;
    } else {
      src = mt.noise; dst = mt.noise16; j = e - FN4;
    }
    float4 v = *(const float4*)(src + j);
    f16x4 o = {(f16)v.x, (f16)v.y, (f16)v.z, (f16)v.w};
    *(f16x4*)(dst + j) = o;
    return;
  }
  __shared__ float tile[32][33];
  int w = 0;
  while (b >= mt.ts[w + 1]) ++w;
  int lt = b - mt.ts[w];
  int K = mt.K[w], N = mt.N[w];
  int tk = lt % (K >> 5), tn = lt / (K >> 5);
  int k0 = tk * 32, n0 = tn * 32;
  int tx = threadIdx.x & 31, ty = threadIdx.x >> 5;
  const float* src = mt.src[w];
#pragma unroll
  for (int i = 0; i < 32; i += 8)
    tile[ty + i][tx] = src[(size_t)(k0 + ty + i) * N + n0 + tx];
  __syncthreads();
  f16* dst = mt.dst[w];
  int st = mt.st[w];
#pragma unroll
  for (int i = 0; i < 32; i += 8)
    dst[(size_t)(n0 + ty + i) * st + k0 + tx] = (f16)tile[tx][ty + i];
}

// --- row softmax (f32) + mix with align -> fp16 -------------------------------
__global__ __launch_bounds__(256) void softmax_mix(
    const float* __restrict__ S, const float* __restrict__ Al,
    const float* __restrict__ lam_ptr, f16* __restrict__ Mh) {
  const int tid = threadIdx.x;
  const float4* s4 = (const float4*)(S + (size_t)blockIdx.x * 2048);
  float4 a = s4[tid], b = s4[tid + 256];
  float m = fmaxf(fmaxf(fmaxf(a.x, a.y), fmaxf(a.z, a.w)),
                  fmaxf(fmaxf(b.x, b.y), fmaxf(b.z, b.w)));
  __shared__ float red[4];
  float w = wave_max(m);
  if ((tid & 63) == 0) red[tid >> 6] = w;
  __syncthreads();
  m = fmaxf(fmaxf(red[0], red[1]), fmaxf(red[2], red[3]));
  __syncthreads();
  a.x = __expf(a.x - m); a.y = __expf(a.y - m);
  a.z = __expf(a.z - m); a.w = __expf(a.w - m);
  b.x = __expf(b.x - m); b.y = __expf(b.y - m);
  b.z = __expf(b.z - m); b.w = __expf(b.w - m);
  float s = a.x + a.y + a.z + a.w + b.x + b.y + b.z + b.w;
  w = wave_sum(s);
  if ((tid & 63) == 0) red[tid >> 6] = w;
  __syncthreads();
  float inv = 1.f / (red[0] + red[1] + red[2] + red[3]);
  float lam = lam_ptr[0], oml = 1.f - lam;
  const float4* al4 = (const float4*)(Al + (size_t)blockIdx.x * 2048);
  float4 x = al4[tid], y = al4[tid + 256];
  f16x4 o0 = {(f16)(lam * x.x + oml * a.x * inv),
              (f16)(lam * x.y + oml * a.y * inv),
              (f16)(lam * x.z + oml * a.z * inv),
              (f16)(lam * x.w + oml * a.w * inv)};
  f16x4 o1 = {(f16)(lam * y.x + oml * b.x * inv),
              (f16)(lam * y.y + oml * b.y * inv),
              (f16)(lam * y.z + oml * b.z * inv),
              (f16)(lam * y.w + oml * b.w * inv)};
  f16x4* out4 = (f16x4*)(Mh + (size_t)blockIdx.x * 2048);
  out4[tid] = o0;
  out4[tid + 256] = o1;
}

// --- column L2 norms of emb0 [N,64] ------------------------------------------
__global__ __launch_bounds__(256) void col_l2norm64(
    const float* __restrict__ x, float* __restrict__ cn) {
  int c = blockIdx.x;
  float ss = 0.f;
  for (int r = threadIdx.x; r < NN; r += 256) {
    float v = x[(long)r * 64 + c];
    ss += v * v;
  }
  __shared__ float red[4];
  float w = wave_sum(ss);
  if ((threadIdx.x & 63) == 0) red[threadIdx.x >> 6] = w;
  __syncthreads();
  if (threadIdx.x == 0)
    cn[c] = fmaxf(sqrtf(red[0] + red[1] + red[2] + red[3]), 1e-12f);
}

// --- emb16 = emb0/cn ; sq[i] = row sumsq -------------------------------------
__global__ void norm_sq64h(const float* __restrict__ x,
                           const float* __restrict__ cn,
                           f16* __restrict__ emb16, float* __restrict__ sq) {
  int i = blockIdx.x, j = threadIdx.x;
  float e = x[(long)i * 64 + j] / cn[j];
  emb16[(long)i * 64 + j] = (f16)e;
  float s = wave_sum(e * e);
  if (j == 0) sq[i] = s;
}

// ---------------------------------------------------------------------------
extern "C" void kernel_launch(void* const* d_in, const int* in_sizes, int n_in,
                              void* d_out, int out_size, void* d_ws,
                              size_t ws_size, hipStream_t stream) {
  (void)in_sizes; (void)n_in; (void)out_size; (void)ws_size;
  const float* sup    = (const float*)d_in[0];
  const float* feat   = (const float*)d_in[1];
  const float* noise  = (const float*)d_in[2];
  const float* align  = (const float*)d_in[3];
  const float* lambd  = (const float*)d_in[4];
  const float* W_fem  = (const float*)d_in[5];
  const float* b_fem  = (const float*)d_in[6];
  const float* W_gnn  = (const float*)d_in[7];
  const float* b_gnn  = (const float*)d_in[8];
  const float* Wg_x   = (const float*)d_in[9];
  const float* Wg_h   = (const float*)d_in[10];
  const float* bg     = (const float*)d_in[11];
  const float* Wc_x   = (const float*)d_in[12];
  const float* Wc_h   = (const float*)d_in[13];
  const float* bc     = (const float*)d_in[14];
  const float* W_att  = (const float*)d_in[15];
  const float* b_att  = (const float*)d_in[16];
  const float* W_emb1 = (const float*)d_in[17];
  const float* b_emb1 = (const float*)d_in[18];
  const float* W_emb2 = (const float*)d_in[19];
  const float* b_emb2 = (const float*)d_in[20];
  const float* W_scal1= (const float*)d_in[21];
  const float* b_scal1= (const float*)d_in[22];
  const float* W_scal2= (const float*)d_in[23];
  const float* b_scal2= (const float*)d_in[24];

  char* wsb = (char*)d_ws;
  size_t po = 0;
  auto P = [&](size_t bytes) {
    size_t r = po;
    po += (bytes + 255) & ~(size_t)255;
    return r;
  };
  f16* fem16  = (f16*)(wsb + P(5L * NN * HF * 2));
  f16* fm16   = (f16*)(wsb + P(5L * NN * HH * 2));
  f16* g16    = (f16*)(wsb + P(4L * NN * HH * 2));
  f16* WT     = (f16*)(wsb + P(884736L * 2));
  f16* Xgc16  = (f16*)(wsb + P(4L * NN * 768 * 2));
  float* hA   = (float*)(wsb + P((long)NN * HH * 4));
  f16* h16A   = (f16*)(wsb + P((long)NN * HH * 2));
  f16* rnnT16 = (f16*)(wsb + P((long)NN * HH * 2));
  float* hP   = (float*)(wsb + P(8L * NN * HH * 4));
  f16* M16_2  = (f16*)(wsb + P(2L * NN * NN * 2));
  f16* e1s1   = (f16*)(wsb + P((long)NN * 512 * 2));
  float* embscF = (float*)(wsb + P(2L * NN * E2D * 4));
  f16* embsc16  = (f16*)(wsb + P(2L * NN * E2D * 2));
  f16* emb16  = (f16*)(wsb + P((long)NN * E2D * 2));
  float* cn   = (float*)(wsb + P(64 * 4));
  float* sq   = (float*)(wsb + P(NN * 4));
  // arena: feat16 | noise16 | edmW | edmWT | aggP early; Sbuf2 aliases later
  size_t arena = P(34078720);
  f16* feat16  = (f16*)(wsb + arena);                 //  2,621,440 B
  f16* noise16 = (f16*)(wsb + arena + 2621440);       //  2,097,152 B
  f16* edmW    = (f16*)(wsb + arena + 4718592);       //  4,194,304 B
  f16* edmWT   = (f16*)(wsb + arena + 8912896);       //  4,194,304 B
  f16* aggP    = (f16*)(wsb + arena + 13107200);      // 16,777,216 B
  float* Sbuf2 = (float*)(wsb + arena);               // 33,554,432 B

  // --- weight transpose table -------------------------------------------------
  f16* W_femT  = WT;                       // 256x128
  f16* W_gnnT  = W_femT + 32768;           // 256x384
  f16* WgxcT   = W_gnnT + 98304;           // 768x256 ([Wgx^T; Wcx^T])
  f16* WghT    = WgxcT + 196608;           // 512x256
  f16* WchT    = WghT + 131072;            // 256x256
  f16* W_attT  = WchT + 65536;             // 256x256
  f16* We1s1T  = W_attT + 65536;           // 512x512 ([Wemb1^T; Wscal1^T])
  f16* Wemb2T  = We1s1T + 262144;          // 64x256
  f16* Wscal2T = Wemb2T + 16384;           // 64x256 (adjacent: zB=16384)

  MT mt;
  const float* wsrc[11] = {W_fem, W_gnn, Wg_x, Wc_x, Wg_h, Wc_h,
                           W_att, W_emb1, W_scal1, W_emb2, W_scal2};
  f16* wdst[11] = {W_femT, W_gnnT, WgxcT, WgxcT + 512 * 256, WghT, WchT,
                   W_attT, We1s1T, We1s1T + 256 * 512, Wemb2T, Wscal2T};
  const int wK[11]  = {128, 384, 256, 256, 256, 256, 256, 512, 512, 256, 256};
  const int wNd[11] = {256, 256, 512, 256, 512, 256, 256, 256, 256, 64, 64};
  const int wSt[11] = {128, 384, 256, 256, 256, 256, 256, 512, 512, 256, 256};
  int tcum = 0;
  for (int i = 0; i < 11; ++i) {
    mt.src[i] = wsrc[i];
    mt.dst[i] = wdst[i];
    mt.K[i] = wK[i];
    mt.N[i] = wNd[i];
    mt.st[i] = wSt[i];
    mt.ts[i] = tcum;
    tcum += (wK[i] >> 5) * (wNd[i] >> 5);
  }
  mt.ts[11] = tcum;
  mt.feat = feat;
  mt.feat16 = feat16;
  mt.noise = noise;
  mt.noise16 = noise16;
  const int cvt_blocks = (5 * NN * F_IN + 4 * NN * DZ) / 1024;  // 2304

  const f16* NH = nullptr;
  float* NF = nullptr;
  f16* NHm = nullptr;

  multi_transp<<<tcum + cvt_blocks, 256, 0, stream>>>(mt);

  // FEM: fem16 = relu(feat @ W_fem + b)
  hgemm<1, 64, 1><<<dim3(4, 80, 1), 256, 0, stream>>>(
      feat16, NH, W_femT, b_fem, nullptr, NF, fem16,
      128, 0, 128, 128, 256, 128, 0, 0, 0, 0);

  // edmW[t][n][c] = edm[t][n] @ Wgnn  (A dual-source: fem16|noise16 at k=256)
  hgemm<0, 64, 1><<<dim3(4, 16, 4), 256, 0, stream>>>(
      fem16, noise16, W_gnnT, nullptr, nullptr, NF, edmW,
      256, 128, 256, 384, 256, 384,
      (long)NN * HF, (long)NN * DZ, 0, (long)NN * 256);

  // edmWT[t][c][n] = edmW[t][n][c]^T
  transp_h<<<dim3(8, 64, 4), 256, 0, stream>>>(
      edmW, edmWT, NN, 256, (long)NN * 256, 256L * NN);

  // sup @ edmW partials + finalize (bias+relu+l2norm)
  sup_gnn2<<<dim3(32, 2, 16), 256, 0, stream>>>(sup, edmWT, aggP);
  gnn_fin<<<2048, 256, 0, stream>>>(aggP, b_gnn, g16);

  // fm16 = fem @ W_att + b
  hgemm<0, 64, 1><<<dim3(4, 80, 1), 256, 0, stream>>>(
      fem16, NH, W_attT, b_att, nullptr, NF, fm16,
      256, 0, 256, 256, 256, 256, 0, 0, 0, 0);

  // Xgc = g16 @ [Wgx | Wcx]  -> [8192 x 768] f16 pre-activations
  hgemm<0, 64, 1><<<dim3(12, 64, 1), 256, 0, stream>>>(
      g16, NH, WgxcT, nullptr, nullptr, NF, Xgc16,
      256, 0, 256, 256, 768, 256, 0, 0, 0, 0);

  for (int p = 0; p < 2; ++p) {
    // S pair (f32 out): S[z] = fm[2p+z+1] @ fm[2p+z]^T
    hgemm<0, 128, 0><<<dim3(16, 16, 2), 256, 0, stream>>>(
        fm16 + (size_t)(2 * p + 1) * NN * HH, NH,
        fm16 + (size_t)(2 * p) * NN * HH, nullptr, nullptr, Sbuf2, NHm,
        256, 0, 256, 256, 2048, 256,
        (long)NN * HH, 0, (long)NN * HH, (long)NN * NN);
    softmax_mix<<<2 * NN, 256, 0, stream>>>(
        Sbuf2, align + (size_t)(2 * p) * NN * NN, lambd, M16_2);

    for (int tl = 0; tl < 2; ++tl) {
      int t = 2 * p + tl;
      if (t == 0) {
        rnn0_t<<<dim3(64, 8, 1), 256, 0, stream>>>(Xgc16, bg, bc, rnnT16);
      } else {
        gru_step<<<128, 256, 0, stream>>>(
            hP, Xgc16 + (size_t)t * NN * 768, WghT, WchT, bg, bc, rnnT16);
      }
      // h_{t} partials = M16 @ rnn (K-split x8: each z does K=256)
      hgemm<0, 64, 0><<<dim3(4, 16, 8), 256, 0, stream>>>(
          M16_2 + (size_t)(t & 1) * NN * NN, NH, rnnT16, nullptr, nullptr,
          hP, NHm, 2048, 0, 2048, 2048, 256, 256,
          256, 0, 256, 524288);
    }
  }
  // final h for EAM
  hsum8<<<512, 256, 0, stream>>>(hP, hA, h16A);

  // --- EAM tail ---------------------------------------------------------------
  hgemm<6, 64, 1><<<dim3(8, 16, 1), 256, 0, stream>>>(
      h16A, fem16 + 4L * NN * HF, We1s1T, b_emb1, b_scal1, NF, e1s1,
      256, 256, 256, 512, 512, 512, 0, 0, 0, 0);
  // zA=256: z=1 (scal head) reads the s1 half of e1s1.
  hgemm<5, 64, 2><<<dim3(1, 16, 2), 256, 0, stream>>>(
      e1s1, NH, Wemb2T, b_emb2, b_scal2, embscF, embsc16,
      512, 0, 512, 256, 64, 256, 256, 0, 16384, (long)NN * E2D);
  col_l2norm64<<<64, 256, 0, stream>>>(embscF, cn);
  norm_sq64h<<<NN, 64, 0, stream>>>(embscF, cn, emb16, sq);

  pq_decode<<<dim3(16, 16, 1), 256, 0, stream>>>(
      emb16, embsc16 + (size_t)NN * E2D, sq, (float*)d_out);
}

// Round 13
// 307.593 us; speedup vs baseline: 1.2813x; 1.0089x over previous
//
#include <hip/hip_runtime.h>
#include <math.h>

// ---------------------------------------------------------------------------
// GenNet_tanh forward, round 13: R12 + sup_gnn3 (64x256 tile, grid (32,4,4)):
// sup is read ONCE (67 MB) instead of twice; 16 MFMA/wave/k-step.
// ---------------------------------------------------------------------------

#define T_WIN 4
#define NN 2048
#define F_IN 128
#define HF 256
#define HH 256
#define DZ 128
#define G_IN 384
#define EIN 512
#define E1D 256
#define E2D 64

typedef _Float16 f16;
typedef _Float16 f16x8 __attribute__((ext_vector_type(8)));
typedef _Float16 f16x4 __attribute__((ext_vector_type(4)));
typedef float f32x4 __attribute__((ext_vector_type(4)));

__device__ __forceinline__ float wave_sum(float v) {
#pragma unroll
  for (int o = 32; o > 0; o >>= 1) v += __shfl_down(v, o);
  return v;
}
__device__ __forceinline__ float wave_max(float v) {
#pragma unroll
  for (int o = 32; o > 0; o >>= 1) v = fmaxf(v, __shfl_down(v, o));
  return v;
}

__device__ __forceinline__ void gld_lds16(const void* g, void* l) {
  __builtin_amdgcn_global_load_lds(
      (const __attribute__((address_space(1))) unsigned int*)g,
      (__attribute__((address_space(3))) unsigned int*)l, 16, 0, 0);
}

// ---------------------------------------------------------------------------
// fp16 MFMA GEMM, 128 x BN tile, BK=64, 256 threads (4 waves 2x2).
// A: [.,lda] row-major; dual-source: k<kspl from A, else A2 (lda2).
// BT: [N,ldb] row-major.  grid.z advances A by zA, A2 by zA2, BT by zB,
// C by zC.  EPI: 0 none, 1 relu, 5 z-sel tanh/sig, 6 col-sel.
// WOUT: 0 f32, 1 f16, 2 both.
// ---------------------------------------------------------------------------
template <int EPI, int BN, int WOUT>
__global__ __launch_bounds__(256) void hgemm(
    const f16* __restrict__ A, const f16* __restrict__ A2,
    const f16* __restrict__ BT, const float* __restrict__ bias,
    const float* __restrict__ bias2, float* __restrict__ Cf,
    f16* __restrict__ Ch, int lda, int lda2, int kspl, int ldb, int ldc,
    int K, long zA, long zA2, long zB, long zC) {
  constexpr int WN = BN / 2;
  constexpr int FN = WN / 16;
  constexpr int BI = BN / 32;
  __shared__ alignas(16) f16 As[128 * 64];
  __shared__ alignas(16) f16 Bs[BN * 64];
  const int tid = threadIdx.x;
  const int lane = tid & 63, wid = tid >> 6;
  const int wm = wid >> 1, wn = wid & 1;
  const int row0 = blockIdx.y * 128, col0 = blockIdx.x * BN;
  const long zb = blockIdx.z;
  A += zb * zA;
  if (A2) A2 += zb * zA2;
  BT += zb * zB;
  const int l8 = lane >> 3;
  const int lx = ((lane & 7) ^ l8) * 8;  // pre-swizzled source chunk
  const int sw = (lane & 7) * 8;         // frag-read XOR

  f32x4 acc[4][FN];
#pragma unroll
  for (int m = 0; m < 4; ++m)
#pragma unroll
    for (int n = 0; n < FN; ++n) acc[m][n] = (f32x4){0.f, 0.f, 0.f, 0.f};

  for (int k0 = 0; k0 < K; k0 += 64) {
#pragma unroll
    for (int i = 0; i < 4; ++i) {
      int r = wid * 32 + i * 8;
      const f16* src =
          (k0 < kspl) ? A + (size_t)(row0 + r + l8) * lda + k0 + lx
                      : A2 + (size_t)(row0 + r + l8) * lda2 + (k0 - kspl) + lx;
      gld_lds16(src, &As[r * 64]);
    }
#pragma unroll
    for (int i = 0; i < BI; ++i) {
      int r = wid * (BN / 4) + i * 8;
      gld_lds16(BT + (size_t)(col0 + r + l8) * ldb + k0 + lx, &Bs[r * 64]);
    }
    __syncthreads();
#pragma unroll
    for (int ks = 0; ks < 2; ++ks) {
      f16x8 af[4], bf[FN];
#pragma unroll
      for (int m = 0; m < 4; ++m)
        af[m] = *(const f16x8*)&As[((wm * 64 + m * 16 + (lane & 15)) * 64 +
                                    ks * 32 + (lane >> 4) * 8) ^ sw];
#pragma unroll
      for (int n = 0; n < FN; ++n)
        bf[n] = *(const f16x8*)&Bs[((wn * WN + n * 16 + (lane & 15)) * 64 +
                                    ks * 32 + (lane >> 4) * 8) ^ sw];
#pragma unroll
      for (int m = 0; m < 4; ++m)
#pragma unroll
        for (int n = 0; n < FN; ++n)
          acc[m][n] = __builtin_amdgcn_mfma_f32_16x16x32_f16(af[m], bf[n],
                                                             acc[m][n], 0, 0, 0);
    }
    __syncthreads();
  }

  const int cl = lane & 15, rh4 = (lane >> 4) * 4;
  float* Cfb = Cf + zb * zC;
  f16* Chb = Ch + zb * zC;
  const float* bp = (EPI == 5 && zb == 1) ? bias2 : bias;
#pragma unroll
  for (int m = 0; m < 4; ++m) {
#pragma unroll
    for (int n = 0; n < FN; ++n) {
      int cc = col0 + wn * WN + n * 16 + cl;
      float bv = 0.f;
      if (EPI == 6)
        bv = (cc < 256) ? bias[cc] : bias2[cc - 256];
      else if (bp)
        bv = bp[cc];
#pragma unroll
      for (int q = 0; q < 4; ++q) {
        size_t r = row0 + wm * 64 + m * 16 + rh4 + q;
        float v = acc[m][n][q] + bv;
        if (EPI == 1) v = fmaxf(v, 0.f);
        if (EPI == 5) v = (zb == 0) ? tanhf(v) : 1.f / (1.f + __expf(-v));
        if (EPI == 6) v = (cc < 256) ? tanhf(v) : 1.f / (1.f + __expf(-v));
        if (WOUT == 0 || WOUT == 2) Cfb[r * ldc + cc] = v;
        if (WOUT == 1 || WOUT == 2) Chb[r * ldc + cc] = (f16)v;
      }
    }
  }
}

// ---------------------------------------------------------------------------
// sup_gnn3: aggP[kh][t][m][c] partials of sup @ edmW.
// Tile 64 rows x 256 cols x K=512.  grid (32, 4, 4): x=m, y=kh, z=t.
// LDS 40 KB.  sup is read exactly once.
// ---------------------------------------------------------------------------
__global__ __launch_bounds__(256) void sup_gnn3(
    const float* __restrict__ sup, const f16* __restrict__ edmWT,
    f16* __restrict__ aggP) {
  __shared__ alignas(16) f16 As[64 * 64];
  __shared__ alignas(16) f16 Bs[256 * 64];
  const int tid = threadIdx.x;
  const int lane = tid & 63, wid = tid >> 6;
  const int m0 = blockIdx.x * 64, kh = blockIdx.y, t = blockIdx.z;
  const int l8 = lane >> 3;
  const int lx = ((lane & 7) ^ l8) * 8;
  const int sw = (lane & 7) * 8;
  const int cl = lane & 15, hi = lane >> 4;
  const int wm = wid >> 1, wn = wid & 1;
  const float* supT = sup + (size_t)t * NN * NN;
  const f16* BTt = edmWT + (size_t)t * 256 * NN;

  f32x4 acc[2][8];
#pragma unroll
  for (int m = 0; m < 2; ++m)
#pragma unroll
    for (int n = 0; n < 8; ++n) acc[m][n] = (f32x4){0.f, 0.f, 0.f, 0.f};

  const int ar = tid >> 2;       // 0..63 rows
  const int g0 = (tid & 3) * 2;  // source granule pair
  const int kbeg = kh * 512;

  for (int k0 = kbeg; k0 < kbeg + 512; k0 += 64) {
    const float* ap = supT + (size_t)(m0 + ar) * NN + k0 + (tid & 3) * 16;
    float4 f0 = *(const float4*)ap;
    float4 f1 = *(const float4*)(ap + 4);
    float4 f2 = *(const float4*)(ap + 8);
    float4 f3 = *(const float4*)(ap + 12);
    f16x8 hv0 = {(f16)f0.x, (f16)f0.y, (f16)f0.z, (f16)f0.w,
                 (f16)f1.x, (f16)f1.y, (f16)f1.z, (f16)f1.w};
    f16x8 hv1 = {(f16)f2.x, (f16)f2.y, (f16)f2.z, (f16)f2.w,
                 (f16)f3.x, (f16)f3.y, (f16)f3.z, (f16)f3.w};
    *(f16x8*)&As[ar * 64 + ((g0 ^ (ar & 7)) * 8)] = hv0;
    *(f16x8*)&As[ar * 64 + (((g0 + 1) ^ (ar & 7)) * 8)] = hv1;
#pragma unroll
    for (int i = 0; i < 8; ++i) {
      int rn = wid * 64 + i * 8;
      gld_lds16(BTt + (size_t)(rn + l8) * NN + k0 + lx, &Bs[rn * 64]);
    }
    __syncthreads();
#pragma unroll
    for (int ks = 0; ks < 2; ++ks) {
      f16x8 af[2], bf[8];
#pragma unroll
      for (int m = 0; m < 2; ++m)
        af[m] = *(const f16x8*)&As[((wm * 32 + m * 16 + cl) * 64 + ks * 32 +
                                    hi * 8) ^ sw];
#pragma unroll
      for (int n = 0; n < 8; ++n)
        bf[n] = *(const f16x8*)&Bs[((wn * 128 + n * 16 + cl) * 64 + ks * 32 +
                                    hi * 8) ^ sw];
#pragma unroll
      for (int m = 0; m < 2; ++m)
#pragma unroll
        for (int n = 0; n < 8; ++n)
          acc[m][n] = __builtin_amdgcn_mfma_f32_16x16x32_f16(af[m], bf[n],
                                                             acc[m][n], 0, 0, 0);
    }
    __syncthreads();
  }

  f16* dst = aggP + (size_t)kh * (4L * NN * 256) + ((size_t)t * NN + m0) * 256;
#pragma unroll
  for (int m = 0; m < 2; ++m)
#pragma unroll
    for (int n = 0; n < 8; ++n)
#pragma unroll
      for (int q = 0; q < 4; ++q)
        dst[(size_t)(wm * 32 + m * 16 + hi * 4 + q) * 256 + wn * 128 +
            n * 16 + cl] = (f16)acc[m][n][q];
}

// ---------------------------------------------------------------------------
// gnn_fin: g16[r] = l2norm(relu(sum of 4 aggP partials + b)).  1 wave = 1 row.
// ---------------------------------------------------------------------------
__global__ __launch_bounds__(256) void gnn_fin(const f16* __restrict__ aggP,
                                               const float* __restrict__ bgnn,
                                               f16* __restrict__ g16) {
  const int tid = threadIdx.x;
  const int lane = tid & 63, w = tid >> 6;
  const size_t r = (size_t)blockIdx.x * 4 + w;
  const long PS = 4L * NN * 256;
  size_t gi = r * 256 + lane * 4;
  f16x4 a0 = *(const f16x4*)(aggP + gi);
  f16x4 a1 = *(const f16x4*)(aggP + PS + gi);
  f16x4 a2 = *(const f16x4*)(aggP + 2 * PS + gi);
  f16x4 a3 = *(const f16x4*)(aggP + 3 * PS + gi);
  float v[4];
  float ss = 0.f;
#pragma unroll
  for (int j = 0; j < 4; ++j) {
    v[j] = (float)a0[j] + (float)a1[j] + (float)a2[j] + (float)a3[j] +
           bgnn[lane * 4 + j];
    v[j] = fmaxf(v[j], 0.f);
    ss += v[j] * v[j];
  }
  float tot = wave_sum(ss);
  tot = __shfl(tot, 0);
  float inv = 1.f / fmaxf(sqrtf(tot), 1e-12f);
  f16x4 o = {(f16)(v[0] * inv), (f16)(v[1] * inv), (f16)(v[2] * inv),
             (f16)(v[3] * inv)};
  *(f16x4*)(g16 + gi) = o;
}

// --- proven 32x32 f16 transpose: out[c][r] = in[r][c] -------------------------
__global__ __launch_bounds__(256) void transp_h(const f16* __restrict__ in,
                                                f16* __restrict__ out, int R,
                                                int C, long sIn, long sOut) {
  in += blockIdx.z * sIn;
  out += blockIdx.z * sOut;
  __shared__ float tile[32][33];
  int c0 = blockIdx.x * 32, r0 = blockIdx.y * 32;
  int tx = threadIdx.x & 31, ty = threadIdx.x >> 5;
#pragma unroll
  for (int i = 0; i < 32; i += 8)
    tile[ty + i][tx] = (float)in[(size_t)(r0 + ty + i) * C + c0 + tx];
  __syncthreads();
#pragma unroll
  for (int i = 0; i < 32; i += 8)
    out[(size_t)(c0 + ty + i) * R + r0 + tx] = (f16)tile[tx][ty + i];
}

// --- sum 8 K-split partials -> h f32 + f16 -----------------------------------
__global__ __launch_bounds__(256) void hsum8(const float* __restrict__ hP,
                                             float* __restrict__ hf,
                                             f16* __restrict__ h16) {
  long i = ((long)blockIdx.x * 256 + threadIdx.x) * 4;
  float4 s = *(const float4*)(hP + i);
#pragma unroll
  for (int p = 1; p < 8; ++p) {
    float4 v = *(const float4*)(hP + (long)p * 524288 + i);
    s.x += v.x; s.y += v.y; s.z += v.z; s.w += v.w;
  }
  *(float4*)(hf + i) = s;
  f16x4 o = {(f16)s.x, (f16)s.y, (f16)s.z, (f16)s.w};
  *(f16x4*)(h16 + i) = o;
}

// --- t=0 shortcut: rnn0 = sigmoid(Xg_u+bg)*tanh(Xc+bc), transposed ----------
__global__ __launch_bounds__(256) void rnn0_t(const f16* __restrict__ Xgc,
                                              const float* __restrict__ bg,
                                              const float* __restrict__ bc,
                                              f16* __restrict__ rnnT) {
  __shared__ float tile[32][33];
  int n0 = blockIdx.x * 32, k0 = blockIdx.y * 32;
  int tx = threadIdx.x & 31, ty = threadIdx.x >> 5;
#pragma unroll
  for (int i = 0; i < 32; i += 8) {
    int n = n0 + ty + i, k = k0 + tx;
    float u = 1.f / (1.f + __expf(-((float)Xgc[(size_t)n * 768 + 256 + k] +
                                    bg[256 + k])));
    float c = tanhf((float)Xgc[(size_t)n * 768 + 512 + k] + bc[k]);
    tile[ty + i][tx] = u * c;
  }
  __syncthreads();
#pragma unroll
  for (int i = 0; i < 32; i += 8)
    rnnT[(size_t)(k0 + ty + i) * NN + n0 + tx] = (f16)tile[tx][ty + i];
}

// ---------------------------------------------------------------------------
// gru_step: one kernel per scan step (t>=1).  16 rows per block, grid 128.
// Sums 8 hP partials.
// ---------------------------------------------------------------------------
__global__ __launch_bounds__(256) void gru_step(
    const float* __restrict__ hP, const f16* __restrict__ Xgc,
    const f16* __restrict__ WghT, const f16* __restrict__ WchT,
    const float* __restrict__ bg, const float* __restrict__ bc,
    f16* __restrict__ rnnT) {
  __shared__ alignas(16) f16 A_s[16 * 264];
  __shared__ alignas(16) f16 rh_s[16 * 264];
  __shared__ float u_s[16 * 260];
  __shared__ float hf_s[16 * 260];
  __shared__ alignas(16) f16 tileT[256 * 24];
  const int tid = threadIdx.x;
  const int lane = tid & 63, wid = tid >> 6;
  const int cl = lane & 15, hi = lane >> 4;
  const int r0 = blockIdx.x * 16;

#pragma unroll
  for (int i = 0; i < 4; ++i) {
    int e = i * 256 + tid;
    int row = e >> 6, off = (e & 63) * 4;
    size_t gi = (size_t)(r0 + row) * 256 + off;
    float4 s = *(const float4*)(hP + gi);
#pragma unroll
    for (int p = 1; p < 8; ++p) {
      float4 v = *(const float4*)(hP + (size_t)p * 524288 + gi);
      s.x += v.x; s.y += v.y; s.z += v.z; s.w += v.w;
    }
    *(float4*)&hf_s[row * 260 + off] = s;
    f16x4 h4 = {(f16)s.x, (f16)s.y, (f16)s.z, (f16)s.w};
    *(f16x4*)&A_s[row * 264 + off] = h4;
  }
  __syncthreads();

  const int wc0 = wid * 128;
  f32x4 acc[8];
#pragma unroll
  for (int n = 0; n < 8; ++n) acc[n] = (f32x4){0.f, 0.f, 0.f, 0.f};
#pragma unroll
  for (int kk = 0; kk < 256; kk += 32) {
    f16x8 af = *(const f16x8*)&A_s[cl * 264 + kk + hi * 8];
#pragma unroll
    for (int n = 0; n < 8; ++n) {
      f16x8 bf = *(const f16x8*)(WghT + (size_t)(wc0 + n * 16 + cl) * 256 +
                                 kk + hi * 8);
      acc[n] = __builtin_amdgcn_mfma_f32_16x16x32_f16(af, bf, acc[n], 0, 0, 0);
    }
  }
#pragma unroll
  for (int n = 0; n < 8; ++n) {
    int cc = wc0 + n * 16 + cl;
    float bgv = bg[cc];
#pragma unroll
    for (int q = 0; q < 4; ++q) {
      int rl = hi * 4 + q;
      float v = acc[n][q] + bgv + (float)Xgc[(size_t)(r0 + rl) * 768 + cc];
      float sv = 1.f / (1.f + __expf(-v));
      if (cc < 256)
        rh_s[rl * 264 + cc] = (f16)(sv * hf_s[rl * 260 + cc]);
      else
        u_s[rl * 260 + cc - 256] = sv;
    }
  }
  __syncthreads();

  const int wc2 = wid * 64;
  f32x4 acc2[4];
#pragma unroll
  for (int n = 0; n < 4; ++n) acc2[n] = (f32x4){0.f, 0.f, 0.f, 0.f};
#pragma unroll
  for (int kk = 0; kk < 256; kk += 32) {
    f16x8 af = *(const f16x8*)&rh_s[cl * 264 + kk + hi * 8];
#pragma unroll
    for (int n = 0; n < 4; ++n) {
      f16x8 bf = *(const f16x8*)(WchT + (size_t)(wc2 + n * 16 + cl) * 256 +
                                 kk + hi * 8);
      acc2[n] = __builtin_amdgcn_mfma_f32_16x16x32_f16(af, bf, acc2[n], 0, 0, 0);
    }
  }
#pragma unroll
  for (int n = 0; n < 4; ++n) {
    int cc = wc2 + n * 16 + cl;
    float bcv = bc[cc];
#pragma unroll
    for (int q = 0; q < 4; ++q) {
      int rl = hi * 4 + q;
      float cv = tanhf(acc2[n][q] + bcv +
                       (float)Xgc[(size_t)(r0 + rl) * 768 + 512 + cc]);
      float u = u_s[rl * 260 + cc];
      float hv = hf_s[rl * 260 + cc];
      tileT[cc * 24 + rl] = (f16)((1.f - u) * hv + u * cv);
    }
  }
  __syncthreads();
  {
    int cc = tid;
    *(f16x8*)&rnnT[(size_t)cc * NN + r0] = *(const f16x8*)&tileT[cc * 24];
    *(f16x8*)&rnnT[(size_t)cc * NN + r0 + 8] =
        *(const f16x8*)&tileT[cc * 24 + 8];
  }
}

// ---------------------------------------------------------------------------
// Fused P/Q/decode
// ---------------------------------------------------------------------------
__global__ __launch_bounds__(256) void pq_decode(
    const f16* __restrict__ emb, const f16* __restrict__ scal,
    const float* __restrict__ sq, float* __restrict__ out) {
  __shared__ alignas(16) f16 EA[128 * 64], EB[128 * 64], SA[128 * 64],
      SB[128 * 64];
  const int tid = threadIdx.x;
  const int lane = tid & 63, wid = tid >> 6;
  const int wm = wid >> 1, wn = wid & 1;
  const int row0 = blockIdx.y * 128, col0 = blockIdx.x * 128;
  const int l8 = lane >> 3;
  const int lx = ((lane & 7) ^ l8) * 8;
  const int sw = (lane & 7) * 8;
#pragma unroll
  for (int i = 0; i < 2; ++i) {
    int r = wid * 16 + i * 8;
    gld_lds16(emb + (size_t)(row0 + r + l8) * 64 + lx, &EA[r * 64]);
    gld_lds16(emb + (size_t)(col0 + r + l8) * 64 + lx, &EB[r * 64]);
    gld_lds16(scal + (size_t)(row0 + r + l8) * 64 + lx, &SA[r * 64]);
    gld_lds16(scal + (size_t)(col0 + r + l8) * 64 + lx, &SB[r * 64]);
    int r2 = r + 64;
    gld_lds16(emb + (size_t)(row0 + r2 + l8) * 64 + lx, &EA[r2 * 64]);
    gld_lds16(emb + (size_t)(col0 + r2 + l8) * 64 + lx, &EB[r2 * 64]);
    gld_lds16(scal + (size_t)(row0 + r2 + l8) * 64 + lx, &SA[r2 * 64]);
    gld_lds16(scal + (size_t)(col0 + r2 + l8) * 64 + lx, &SB[r2 * 64]);
  }
  __syncthreads();
  f32x4 accP[4][4], accQ[4][4];
#pragma unroll
  for (int m = 0; m < 4; ++m)
#pragma unroll
    for (int n = 0; n < 4; ++n) {
      accP[m][n] = (f32x4){0.f, 0.f, 0.f, 0.f};
      accQ[m][n] = (f32x4){0.f, 0.f, 0.f, 0.f};
    }
#pragma unroll
  for (int ks = 0; ks < 2; ++ks) {
    f16x8 af[4], bf[4];
#pragma unroll
    for (int m = 0; m < 4; ++m)
      af[m] = *(const f16x8*)&EA[((wm * 64 + m * 16 + (lane & 15)) * 64 +
                                  ks * 32 + (lane >> 4) * 8) ^ sw];
#pragma unroll
    for (int n = 0; n < 4; ++n)
      bf[n] = *(const f16x8*)&EB[((wn * 64 + n * 16 + (lane & 15)) * 64 +
                                  ks * 32 + (lane >> 4) * 8) ^ sw];
#pragma unroll
    for (int m = 0; m < 4; ++m)
#pragma unroll
      for (int n = 0; n < 4; ++n)
        accP[m][n] = __builtin_amdgcn_mfma_f32_16x16x32_f16(af[m], bf[n],
                                                            accP[m][n], 0, 0, 0);
#pragma unroll
    for (int m = 0; m < 4; ++m)
      af[m] = *(const f16x8*)&SA[((wm * 64 + m * 16 + (lane & 15)) * 64 +
                                  ks * 32 + (lane >> 4) * 8) ^ sw];
#pragma unroll
    for (int n = 0; n < 4; ++n)
      bf[n] = *(const f16x8*)&SB[((wn * 64 + n * 16 + (lane & 15)) * 64 +
                                  ks * 32 + (lane >> 4) * 8) ^ sw];
#pragma unroll
    for (int m = 0; m < 4; ++m)
#pragma unroll
      for (int n = 0; n < 4; ++n)
        accQ[m][n] = __builtin_amdgcn_mfma_f32_16x16x32_f16(af[m], bf[n],
                                                            accQ[m][n], 0, 0, 0);
  }
  const int cl = lane & 15, rh4 = (lane >> 4) * 4;
#pragma unroll
  for (int m = 0; m < 4; ++m) {
#pragma unroll
    for (int n = 0; n < 4; ++n) {
      int c = col0 + wn * 64 + n * 16 + cl;
      float sqc = sq[c];
#pragma unroll
      for (int q = 0; q < 4; ++q) {
        size_t r = row0 + wm * 64 + m * 16 + rh4 + q;
        float dist = -(sq[r] + sqc - 2.f * accP[m][n][q]);
        out[r * NN + c] = 1.f + tanhf(dist * accQ[m][n][q]);
      }
    }
  }
}

// --- fused weight transpose + feat/noise f32->f16 convert ---------------------
struct MT {
  const float* src[11];
  f16* dst[11];
  int K[11], N[11], st[11], ts[12];
  const float* feat;
  f16* feat16;
  const float* noise;
  f16* noise16;
};
__global__ __launch_bounds__(256) void multi_transp(MT mt) {
  int b = blockIdx.x;
  if (b >= mt.ts[11]) {
    long e = ((long)(b - mt.ts[11]) * 256 + threadIdx.x) * 4;
    const long FN4 = 5L * NN * F_IN;
    const float* src;
    f16* dst;
    long j;
    if (e < FN4) {
      src = mt.feat; dst = mt.feat16; j = e;
    } else {
      src = mt.noise; dst = mt.noise16; j = e - FN4;
    }
    float4 v = *(const float4*)(src + j);
    f16x4 o = {(f16)v.x, (f16)v.y, (f16)v.z, (f16)v.w};
    *(f16x4*)(dst + j) = o;
    return;
  }
  __shared__ float tile[32][33];
  int w = 0;
  while (b >= mt.ts[w + 1]) ++w;
  int lt = b - mt.ts[w];
  int K = mt.K[w], N = mt.N[w];
  int tk = lt % (K >> 5), tn = lt / (K >> 5);
  int k0 = tk * 32, n0 = tn * 32;
  int tx = threadIdx.x & 31, ty = threadIdx.x >> 5;
  const float* src = mt.src[w];
#pragma unroll
  for (int i = 0; i < 32; i += 8)
    tile[ty + i][tx] = src[(size_t)(k0 + ty + i) * N + n0 + tx];
  __syncthreads();
  f16* dst = mt.dst[w];
  int st = mt.st[w];
#pragma unroll
  for (int i = 0; i < 32; i += 8)
    dst[(size_t)(n0 + ty + i) * st + k0 + tx] = (f16)tile[tx][ty + i];
}

// --- row softmax (f32) + mix with align -> fp16 -------------------------------
__global__ __launch_bounds__(256) void softmax_mix(
    const float* __restrict__ S, const float* __restrict__ Al,
    const float* __restrict__ lam_ptr, f16* __restrict__ Mh) {
  const int tid = threadIdx.x;
  const float4* s4 = (const float4*)(S + (size_t)blockIdx.x * 2048);
  float4 a = s4[tid], b = s4[tid + 256];
  float m = fmaxf(fmaxf(fmaxf(a.x, a.y), fmaxf(a.z, a.w)),
                  fmaxf(fmaxf(b.x, b.y), fmaxf(b.z, b.w)));
  __shared__ float red[4];
  float w = wave_max(m);
  if ((tid & 63) == 0) red[tid >> 6] = w;
  __syncthreads();
  m = fmaxf(fmaxf(red[0], red[1]), fmaxf(red[2], red[3]));
  __syncthreads();
  a.x = __expf(a.x - m); a.y = __expf(a.y - m);
  a.z = __expf(a.z - m); a.w = __expf(a.w - m);
  b.x = __expf(b.x - m); b.y = __expf(b.y - m);
  b.z = __expf(b.z - m); b.w = __expf(b.w - m);
  float s = a.x + a.y + a.z + a.w + b.x + b.y + b.z + b.w;
  w = wave_sum(s);
  if ((tid & 63) == 0) red[tid >> 6] = w;
  __syncthreads();
  float inv = 1.f / (red[0] + red[1] + red[2] + red[3]);
  float lam = lam_ptr[0], oml = 1.f - lam;
  const float4* al4 = (const float4*)(Al + (size_t)blockIdx.x * 2048);
  float4 x = al4[tid], y = al4[tid + 256];
  f16x4 o0 = {(f16)(lam * x.x + oml * a.x * inv),
              (f16)(lam * x.y + oml * a.y * inv),
              (f16)(lam * x.z + oml * a.z * inv),
              (f16)(lam * x.w + oml * a.w * inv)};
  f16x4 o1 = {(f16)(lam * y.x + oml * b.x * inv),
              (f16)(lam * y.y + oml * b.y * inv),
              (f16)(lam * y.z + oml * b.z * inv),
              (f16)(lam * y.w + oml * b.w * inv)};
  f16x4* out4 = (f16x4*)(Mh + (size_t)blockIdx.x * 2048);
  out4[tid] = o0;
  out4[tid + 256] = o1;
}

// --- column L2 norms of emb0 [N,64] ------------------------------------------
__global__ __launch_bounds__(256) void col_l2norm64(
    const float* __restrict__ x, float* __restrict__ cn) {
  int c = blockIdx.x;
  float ss = 0.f;
  for (int r = threadIdx.x; r < NN; r += 256) {
    float v = x[(long)r * 64 + c];
    ss += v * v;
  }
  __shared__ float red[4];
  float w = wave_sum(ss);
  if ((threadIdx.x & 63) == 0) red[threadIdx.x >> 6] = w;
  __syncthreads();
  if (threadIdx.x == 0)
    cn[c] = fmaxf(sqrtf(red[0] + red[1] + red[2] + red[3]), 1e-12f);
}

// --- emb16 = emb0/cn ; sq[i] = row sumsq -------------------------------------
__global__ void norm_sq64h(const float* __restrict__ x,
                           const float* __restrict__ cn,
                           f16* __restrict__ emb16, float* __restrict__ sq) {
  int i = blockIdx.x, j = threadIdx.x;
  float e = x[(long)i * 64 + j] / cn[j];
  emb16[(long)i * 64 + j] = (f16)e;
  float s = wave_sum(e * e);
  if (j == 0) sq[i] = s;
}

// ---------------------------------------------------------------------------
extern "C" void kernel_launch(void* const* d_in, const int* in_sizes, int n_in,
                              void* d_out, int out_size, void* d_ws,
                              size_t ws_size, hipStream_t stream) {
  (void)in_sizes; (void)n_in; (void)out_size; (void)ws_size;
  const float* sup    = (const float*)d_in[0];
  const float* feat   = (const float*)d_in[1];
  const float* noise  = (const float*)d_in[2];
  const float* align  = (const float*)d_in[3];
  const float* lambd  = (const float*)d_in[4];
  const float* W_fem  = (const float*)d_in[5];
  const float* b_fem  = (const float*)d_in[6];
  const float* W_gnn  = (const float*)d_in[7];
  const float* b_gnn  = (const float*)d_in[8];
  const float* Wg_x   = (const float*)d_in[9];
  const float* Wg_h   = (const float*)d_in[10];
  const float* bg     = (const float*)d_in[11];
  const float* Wc_x   = (const float*)d_in[12];
  const float* Wc_h   = (const float*)d_in[13];
  const float* bc     = (const float*)d_in[14];
  const float* W_att  = (const float*)d_in[15];
  const float* b_att  = (const float*)d_in[16];
  const float* W_emb1 = (const float*)d_in[17];
  const float* b_emb1 = (const float*)d_in[18];
  const float* W_emb2 = (const float*)d_in[19];
  const float* b_emb2 = (const float*)d_in[20];
  const float* W_scal1= (const float*)d_in[21];
  const float* b_scal1= (const float*)d_in[22];
  const float* W_scal2= (const float*)d_in[23];
  const float* b_scal2= (const float*)d_in[24];

  char* wsb = (char*)d_ws;
  size_t po = 0;
  auto P = [&](size_t bytes) {
    size_t r = po;
    po += (bytes + 255) & ~(size_t)255;
    return r;
  };
  f16* fem16  = (f16*)(wsb + P(5L * NN * HF * 2));
  f16* fm16   = (f16*)(wsb + P(5L * NN * HH * 2));
  f16* g16    = (f16*)(wsb + P(4L * NN * HH * 2));
  f16* WT     = (f16*)(wsb + P(884736L * 2));
  f16* Xgc16  = (f16*)(wsb + P(4L * NN * 768 * 2));
  float* hA   = (float*)(wsb + P((long)NN * HH * 4));
  f16* h16A   = (f16*)(wsb + P((long)NN * HH * 2));
  f16* rnnT16 = (f16*)(wsb + P((long)NN * HH * 2));
  float* hP   = (float*)(wsb + P(8L * NN * HH * 4));
  f16* M16_2  = (f16*)(wsb + P(2L * NN * NN * 2));
  f16* e1s1   = (f16*)(wsb + P((long)NN * 512 * 2));
  float* embscF = (float*)(wsb + P(2L * NN * E2D * 4));
  f16* embsc16  = (f16*)(wsb + P(2L * NN * E2D * 2));
  f16* emb16  = (f16*)(wsb + P((long)NN * E2D * 2));
  float* cn   = (float*)(wsb + P(64 * 4));
  float* sq   = (float*)(wsb + P(NN * 4));
  // arena: feat16 | noise16 | edmW | edmWT | aggP early; Sbuf2 aliases later
  size_t arena = P(34078720);
  f16* feat16  = (f16*)(wsb + arena);                 //  2,621,440 B
  f16* noise16 = (f16*)(wsb + arena + 2621440);       //  2,097,152 B
  f16* edmW    = (f16*)(wsb + arena + 4718592);       //  4,194,304 B
  f16* edmWT   = (f16*)(wsb + arena + 8912896);       //  4,194,304 B
  f16* aggP    = (f16*)(wsb + arena + 13107200);      // 16,777,216 B
  float* Sbuf2 = (float*)(wsb + arena);               // 33,554,432 B

  // --- weight transpose table -------------------------------------------------
  f16* W_femT  = WT;                       // 256x128
  f16* W_gnnT  = W_femT + 32768;           // 256x384
  f16* WgxcT   = W_gnnT + 98304;           // 768x256 ([Wgx^T; Wcx^T])
  f16* WghT    = WgxcT + 196608;           // 512x256
  f16* WchT    = WghT + 131072;            // 256x256
  f16* W_attT  = WchT + 65536;             // 256x256
  f16* We1s1T  = W_attT + 65536;           // 512x512 ([Wemb1^T; Wscal1^T])
  f16* Wemb2T  = We1s1T + 262144;          // 64x256
  f16* Wscal2T = Wemb2T + 16384;           // 64x256 (adjacent: zB=16384)

  MT mt;
  const float* wsrc[11] = {W_fem, W_gnn, Wg_x, Wc_x, Wg_h, Wc_h,
                           W_att, W_emb1, W_scal1, W_emb2, W_scal2};
  f16* wdst[11] = {W_femT, W_gnnT, WgxcT, WgxcT + 512 * 256, WghT, WchT,
                   W_attT, We1s1T, We1s1T + 256 * 512, Wemb2T, Wscal2T};
  const int wK[11]  = {128, 384, 256, 256, 256, 256, 256, 512, 512, 256, 256};
  const int wNd[11] = {256, 256, 512, 256, 512, 256, 256, 256, 256, 64, 64};
  const int wSt[11] = {128, 384, 256, 256, 256, 256, 256, 512, 512, 256, 256};
  int tcum = 0;
  for (int i = 0; i < 11; ++i) {
    mt.src[i] = wsrc[i];
    mt.dst[i] = wdst[i];
    mt.K[i] = wK[i];
    mt.N[i] = wNd[i];
    mt.st[i] = wSt[i];
    mt.ts[i] = tcum;
    tcum += (wK[i] >> 5) * (wNd[i] >> 5);
  }
  mt.ts[11] = tcum;
  mt.feat = feat;
  mt.feat16 = feat16;
  mt.noise = noise;
  mt.noise16 = noise16;
  const int cvt_blocks = (5 * NN * F_IN + 4 * NN * DZ) / 1024;  // 2304

  const f16* NH = nullptr;
  float* NF = nullptr;
  f16* NHm = nullptr;

  multi_transp<<<tcum + cvt_blocks, 256, 0, stream>>>(mt);

  // FEM: fem16 = relu(feat @ W_fem + b)
  hgemm<1, 64, 1><<<dim3(4, 80, 1), 256, 0, stream>>>(
      feat16, NH, W_femT, b_fem, nullptr, NF, fem16,
      128, 0, 128, 128, 256, 128, 0, 0, 0, 0);

  // edmW[t][n][c] = edm[t][n] @ Wgnn  (A dual-source: fem16|noise16 at k=256)
  hgemm<0, 64, 1><<<dim3(4, 16, 4), 256, 0, stream>>>(
      fem16, noise16, W_gnnT, nullptr, nullptr, NF, edmW,
      256, 128, 256, 384, 256, 384,
      (long)NN * HF, (long)NN * DZ, 0, (long)NN * 256);

  // edmWT[t][c][n] = edmW[t][n][c]^T
  transp_h<<<dim3(8, 64, 4), 256, 0, stream>>>(
      edmW, edmWT, NN, 256, (long)NN * 256, 256L * NN);

  // sup @ edmW partials (sup read once) + finalize (bias+relu+l2norm)
  sup_gnn3<<<dim3(32, 4, 4), 256, 0, stream>>>(sup, edmWT, aggP);
  gnn_fin<<<2048, 256, 0, stream>>>(aggP, b_gnn, g16);

  // fm16 = fem @ W_att + b
  hgemm<0, 64, 1><<<dim3(4, 80, 1), 256, 0, stream>>>(
      fem16, NH, W_attT, b_att, nullptr, NF, fm16,
      256, 0, 256, 256, 256, 256, 0, 0, 0, 0);

  // Xgc = g16 @ [Wgx | Wcx]  -> [8192 x 768] f16 pre-activations
  hgemm<0, 64, 1><<<dim3(12, 64, 1), 256, 0, stream>>>(
      g16, NH, WgxcT, nullptr, nullptr, NF, Xgc16,
      256, 0, 256, 256, 768, 256, 0, 0, 0, 0);

  for (int p = 0; p < 2; ++p) {
    // S pair (f32 out): S[z] = fm[2p+z+1] @ fm[2p+z]^T
    hgemm<0, 128, 0><<<dim3(16, 16, 2), 256, 0, stream>>>(
        fm16 + (size_t)(2 * p + 1) * NN * HH, NH,
        fm16 + (size_t)(2 * p) * NN * HH, nullptr, nullptr, Sbuf2, NHm,
        256, 0, 256, 256, 2048, 256,
        (long)NN * HH, 0, (long)NN * HH, (long)NN * NN);
    softmax_mix<<<2 * NN, 256, 0, stream>>>(
        Sbuf2, align + (size_t)(2 * p) * NN * NN, lambd, M16_2);

    for (int tl = 0; tl < 2; ++tl) {
      int t = 2 * p + tl;
      if (t == 0) {
        rnn0_t<<<dim3(64, 8, 1), 256, 0, stream>>>(Xgc16, bg, bc, rnnT16);
      } else {
        gru_step<<<128, 256, 0, stream>>>(
            hP, Xgc16 + (size_t)t * NN * 768, WghT, WchT, bg, bc, rnnT16);
      }
      // h_{t} partials = M16 @ rnn (K-split x8: each z does K=256)
      hgemm<0, 64, 0><<<dim3(4, 16, 8), 256, 0, stream>>>(
          M16_2 + (size_t)(t & 1) * NN * NN, NH, rnnT16, nullptr, nullptr,
          hP, NHm, 2048, 0, 2048, 2048, 256, 256,
          256, 0, 256, 524288);
    }
  }
  // final h for EAM
  hsum8<<<512, 256, 0, stream>>>(hP, hA, h16A);

  // --- EAM tail ---------------------------------------------------------------
  hgemm<6, 64, 1><<<dim3(8, 16, 1), 256, 0, stream>>>(
      h16A, fem16 + 4L * NN * HF, We1s1T, b_emb1, b_scal1, NF, e1s1,
      256, 256, 256, 512, 512, 512, 0, 0, 0, 0);
  // zA=256: z=1 (scal head) reads the s1 half of e1s1.
  hgemm<5, 64, 2><<<dim3(1, 16, 2), 256, 0, stream>>>(
      e1s1, NH, Wemb2T, b_emb2, b_scal2, embscF, embsc16,
      512, 0, 512, 256, 64, 256, 256, 0, 16384, (long)NN * E2D);
  col_l2norm64<<<64, 256, 0, stream>>>(embscF, cn);
  norm_sq64h<<<NN, 64, 0, stream>>>(embscF, cn, emb16, sq);

  pq_decode<<<dim3(16, 16, 1), 256, 0, stream>>>(
      emb16, embsc16 + (size_t)NN * E2D, sq, (float*)d_out);
}

// Round 14
// 305.897 us; speedup vs baseline: 1.2884x; 1.0055x over previous
//
#include <hip/hip_runtime.h>
#include <math.h>

// ---------------------------------------------------------------------------
// GenNet_tanh forward, round 14: R13 + WOUT=3 (transposed f16 out via proven
// LDS tileT pattern) on the edmW GEMM -> writes edmWT directly, deleting the
// transp_h dispatch and 16.8 MB of intermediate traffic.
// ---------------------------------------------------------------------------

#define T_WIN 4
#define NN 2048
#define F_IN 128
#define HF 256
#define HH 256
#define DZ 128
#define G_IN 384
#define EIN 512
#define E1D 256
#define E2D 64

typedef _Float16 f16;
typedef _Float16 f16x8 __attribute__((ext_vector_type(8)));
typedef _Float16 f16x4 __attribute__((ext_vector_type(4)));
typedef float f32x4 __attribute__((ext_vector_type(4)));

__device__ __forceinline__ float wave_sum(float v) {
#pragma unroll
  for (int o = 32; o > 0; o >>= 1) v += __shfl_down(v, o);
  return v;
}
__device__ __forceinline__ float wave_max(float v) {
#pragma unroll
  for (int o = 32; o > 0; o >>= 1) v = fmaxf(v, __shfl_down(v, o));
  return v;
}

__device__ __forceinline__ void gld_lds16(const void* g, void* l) {
  __builtin_amdgcn_global_load_lds(
      (const __attribute__((address_space(1))) unsigned int*)g,
      (__attribute__((address_space(3))) unsigned int*)l, 16, 0, 0);
}

// ---------------------------------------------------------------------------
// fp16 MFMA GEMM, 128 x BN tile, BK=64, 256 threads (4 waves 2x2).
// A: [.,lda] row-major; dual-source: k<kspl from A, else A2 (lda2).
// BT: [N,ldb] row-major.  grid.z advances A by zA, A2 by zA2, BT by zB,
// C by zC.  EPI: 0 none, 1 relu, 5 z-sel tanh/sig, 6 col-sel.
// WOUT: 0 f32, 1 f16, 2 both, 3 f16 TRANSPOSED (BN==64 only; ldc = out ld).
// ---------------------------------------------------------------------------
template <int EPI, int BN, int WOUT>
__global__ __launch_bounds__(256) void hgemm(
    const f16* __restrict__ A, const f16* __restrict__ A2,
    const f16* __restrict__ BT, const float* __restrict__ bias,
    const float* __restrict__ bias2, float* __restrict__ Cf,
    f16* __restrict__ Ch, int lda, int lda2, int kspl, int ldb, int ldc,
    int K, long zA, long zA2, long zB, long zC) {
  constexpr int WN = BN / 2;
  constexpr int FN = WN / 16;
  constexpr int BI = BN / 32;
  __shared__ alignas(16) f16 As[128 * 64];
  __shared__ alignas(16) f16 Bs[BN * 64];
  __shared__ alignas(16) f16 tileT[(WOUT == 3) ? 64 * 136 : 1];
  const int tid = threadIdx.x;
  const int lane = tid & 63, wid = tid >> 6;
  const int wm = wid >> 1, wn = wid & 1;
  const int row0 = blockIdx.y * 128, col0 = blockIdx.x * BN;
  const long zb = blockIdx.z;
  A += zb * zA;
  if (A2) A2 += zb * zA2;
  BT += zb * zB;
  const int l8 = lane >> 3;
  const int lx = ((lane & 7) ^ l8) * 8;  // pre-swizzled source chunk
  const int sw = (lane & 7) * 8;         // frag-read XOR

  f32x4 acc[4][FN];
#pragma unroll
  for (int m = 0; m < 4; ++m)
#pragma unroll
    for (int n = 0; n < FN; ++n) acc[m][n] = (f32x4){0.f, 0.f, 0.f, 0.f};

  for (int k0 = 0; k0 < K; k0 += 64) {
#pragma unroll
    for (int i = 0; i < 4; ++i) {
      int r = wid * 32 + i * 8;
      const f16* src =
          (k0 < kspl) ? A + (size_t)(row0 + r + l8) * lda + k0 + lx
                      : A2 + (size_t)(row0 + r + l8) * lda2 + (k0 - kspl) + lx;
      gld_lds16(src, &As[r * 64]);
    }
#pragma unroll
    for (int i = 0; i < BI; ++i) {
      int r = wid * (BN / 4) + i * 8;
      gld_lds16(BT + (size_t)(col0 + r + l8) * ldb + k0 + lx, &Bs[r * 64]);
    }
    __syncthreads();
#pragma unroll
    for (int ks = 0; ks < 2; ++ks) {
      f16x8 af[4], bf[FN];
#pragma unroll
      for (int m = 0; m < 4; ++m)
        af[m] = *(const f16x8*)&As[((wm * 64 + m * 16 + (lane & 15)) * 64 +
                                    ks * 32 + (lane >> 4) * 8) ^ sw];
#pragma unroll
      for (int n = 0; n < FN; ++n)
        bf[n] = *(const f16x8*)&Bs[((wn * WN + n * 16 + (lane & 15)) * 64 +
                                    ks * 32 + (lane >> 4) * 8) ^ sw];
#pragma unroll
      for (int m = 0; m < 4; ++m)
#pragma unroll
        for (int n = 0; n < FN; ++n)
          acc[m][n] = __builtin_amdgcn_mfma_f32_16x16x32_f16(af[m], bf[n],
                                                             acc[m][n], 0, 0, 0);
    }
    __syncthreads();
  }

  const int cl = lane & 15, rh4 = (lane >> 4) * 4;
  float* Cfb = Cf + zb * zC;
  f16* Chb = Ch + zb * zC;
  const float* bp = (EPI == 5 && zb == 1) ? bias2 : bias;
#pragma unroll
  for (int m = 0; m < 4; ++m) {
#pragma unroll
    for (int n = 0; n < FN; ++n) {
      int cc = col0 + wn * WN + n * 16 + cl;
      float bv = 0.f;
      if (EPI == 6)
        bv = (cc < 256) ? bias[cc] : bias2[cc - 256];
      else if (bp)
        bv = bp[cc];
#pragma unroll
      for (int q = 0; q < 4; ++q) {
        size_t r = row0 + wm * 64 + m * 16 + rh4 + q;
        float v = acc[m][n][q] + bv;
        if (EPI == 1) v = fmaxf(v, 0.f);
        if (EPI == 5) v = (zb == 0) ? tanhf(v) : 1.f / (1.f + __expf(-v));
        if (EPI == 6) v = (cc < 256) ? tanhf(v) : 1.f / (1.f + __expf(-v));
        if (WOUT == 3) {
          int ccl = wn * WN + n * 16 + cl;
          int rl = wm * 64 + m * 16 + rh4 + q;
          tileT[ccl * 136 + rl] = (f16)v;
        } else {
          if (WOUT == 0 || WOUT == 2) Cfb[r * ldc + cc] = v;
          if (WOUT == 1 || WOUT == 2) Chb[r * ldc + cc] = (f16)v;
        }
      }
    }
  }
  if (WOUT == 3) {
    __syncthreads();
#pragma unroll
    for (int i = 0; i < 4; ++i) {
      int chunk = i * 256 + tid;
      int rr = chunk >> 4, seg = (chunk & 15) * 8;
      *(f16x8*)&Chb[(size_t)(col0 + rr) * ldc + row0 + seg] =
          *(const f16x8*)&tileT[rr * 136 + seg];
    }
  }
}

// ---------------------------------------------------------------------------
// sup_gnn3: aggP[kh][t][m][c] partials of sup @ edmW.
// Tile 64 rows x 256 cols x K=512.  grid (32, 4, 4): x=m, y=kh, z=t.
// ---------------------------------------------------------------------------
__global__ __launch_bounds__(256) void sup_gnn3(
    const float* __restrict__ sup, const f16* __restrict__ edmWT,
    f16* __restrict__ aggP) {
  __shared__ alignas(16) f16 As[64 * 64];
  __shared__ alignas(16) f16 Bs[256 * 64];
  const int tid = threadIdx.x;
  const int lane = tid & 63, wid = tid >> 6;
  const int m0 = blockIdx.x * 64, kh = blockIdx.y, t = blockIdx.z;
  const int l8 = lane >> 3;
  const int lx = ((lane & 7) ^ l8) * 8;
  const int sw = (lane & 7) * 8;
  const int cl = lane & 15, hi = lane >> 4;
  const int wm = wid >> 1, wn = wid & 1;
  const float* supT = sup + (size_t)t * NN * NN;
  const f16* BTt = edmWT + (size_t)t * 256 * NN;

  f32x4 acc[2][8];
#pragma unroll
  for (int m = 0; m < 2; ++m)
#pragma unroll
    for (int n = 0; n < 8; ++n) acc[m][n] = (f32x4){0.f, 0.f, 0.f, 0.f};

  const int ar = tid >> 2;
  const int g0 = (tid & 3) * 2;
  const int kbeg = kh * 512;

  for (int k0 = kbeg; k0 < kbeg + 512; k0 += 64) {
    const float* ap = supT + (size_t)(m0 + ar) * NN + k0 + (tid & 3) * 16;
    float4 f0 = *(const float4*)ap;
    float4 f1 = *(const float4*)(ap + 4);
    float4 f2 = *(const float4*)(ap + 8);
    float4 f3 = *(const float4*)(ap + 12);
    f16x8 hv0 = {(f16)f0.x, (f16)f0.y, (f16)f0.z, (f16)f0.w,
                 (f16)f1.x, (f16)f1.y, (f16)f1.z, (f16)f1.w};
    f16x8 hv1 = {(f16)f2.x, (f16)f2.y, (f16)f2.z, (f16)f2.w,
                 (f16)f3.x, (f16)f3.y, (f16)f3.z, (f16)f3.w};
    *(f16x8*)&As[ar * 64 + ((g0 ^ (ar & 7)) * 8)] = hv0;
    *(f16x8*)&As[ar * 64 + (((g0 + 1) ^ (ar & 7)) * 8)] = hv1;
#pragma unroll
    for (int i = 0; i < 8; ++i) {
      int rn = wid * 64 + i * 8;
      gld_lds16(BTt + (size_t)(rn + l8) * NN + k0 + lx, &Bs[rn * 64]);
    }
    __syncthreads();
#pragma unroll
    for (int ks = 0; ks < 2; ++ks) {
      f16x8 af[2], bf[8];
#pragma unroll
      for (int m = 0; m < 2; ++m)
        af[m] = *(const f16x8*)&As[((wm * 32 + m * 16 + cl) * 64 + ks * 32 +
                                    hi * 8) ^ sw];
#pragma unroll
      for (int n = 0; n < 8; ++n)
        bf[n] = *(const f16x8*)&Bs[((wn * 128 + n * 16 + cl) * 64 + ks * 32 +
                                    hi * 8) ^ sw];
#pragma unroll
      for (int m = 0; m < 2; ++m)
#pragma unroll
        for (int n = 0; n < 8; ++n)
          acc[m][n] = __builtin_amdgcn_mfma_f32_16x16x32_f16(af[m], bf[n],
                                                             acc[m][n], 0, 0, 0);
    }
    __syncthreads();
  }

  f16* dst = aggP + (size_t)kh * (4L * NN * 256) + ((size_t)t * NN + m0) * 256;
#pragma unroll
  for (int m = 0; m < 2; ++m)
#pragma unroll
    for (int n = 0; n < 8; ++n)
#pragma unroll
      for (int q = 0; q < 4; ++q)
        dst[(size_t)(wm * 32 + m * 16 + hi * 4 + q) * 256 + wn * 128 +
            n * 16 + cl] = (f16)acc[m][n][q];
}

// ---------------------------------------------------------------------------
// gnn_fin: g16[r] = l2norm(relu(sum of 4 aggP partials + b)).  1 wave = 1 row.
// ---------------------------------------------------------------------------
__global__ __launch_bounds__(256) void gnn_fin(const f16* __restrict__ aggP,
                                               const float* __restrict__ bgnn,
                                               f16* __restrict__ g16) {
  const int tid = threadIdx.x;
  const int lane = tid & 63, w = tid >> 6;
  const size_t r = (size_t)blockIdx.x * 4 + w;
  const long PS = 4L * NN * 256;
  size_t gi = r * 256 + lane * 4;
  f16x4 a0 = *(const f16x4*)(aggP + gi);
  f16x4 a1 = *(const f16x4*)(aggP + PS + gi);
  f16x4 a2 = *(const f16x4*)(aggP + 2 * PS + gi);
  f16x4 a3 = *(const f16x4*)(aggP + 3 * PS + gi);
  float v[4];
  float ss = 0.f;
#pragma unroll
  for (int j = 0; j < 4; ++j) {
    v[j] = (float)a0[j] + (float)a1[j] + (float)a2[j] + (float)a3[j] +
           bgnn[lane * 4 + j];
    v[j] = fmaxf(v[j], 0.f);
    ss += v[j] * v[j];
  }
  float tot = wave_sum(ss);
  tot = __shfl(tot, 0);
  float inv = 1.f / fmaxf(sqrtf(tot), 1e-12f);
  f16x4 o = {(f16)(v[0] * inv), (f16)(v[1] * inv), (f16)(v[2] * inv),
             (f16)(v[3] * inv)};
  *(f16x4*)(g16 + gi) = o;
}

// --- sum 8 K-split partials -> h f32 + f16 -----------------------------------
__global__ __launch_bounds__(256) void hsum8(const float* __restrict__ hP,
                                             float* __restrict__ hf,
                                             f16* __restrict__ h16) {
  long i = ((long)blockIdx.x * 256 + threadIdx.x) * 4;
  float4 s = *(const float4*)(hP + i);
#pragma unroll
  for (int p = 1; p < 8; ++p) {
    float4 v = *(const float4*)(hP + (long)p * 524288 + i);
    s.x += v.x; s.y += v.y; s.z += v.z; s.w += v.w;
  }
  *(float4*)(hf + i) = s;
  f16x4 o = {(f16)s.x, (f16)s.y, (f16)s.z, (f16)s.w};
  *(f16x4*)(h16 + i) = o;
}

// --- t=0 shortcut: rnn0 = sigmoid(Xg_u+bg)*tanh(Xc+bc), transposed ----------
__global__ __launch_bounds__(256) void rnn0_t(const f16* __restrict__ Xgc,
                                              const float* __restrict__ bg,
                                              const float* __restrict__ bc,
                                              f16* __restrict__ rnnT) {
  __shared__ float tile[32][33];
  int n0 = blockIdx.x * 32, k0 = blockIdx.y * 32;
  int tx = threadIdx.x & 31, ty = threadIdx.x >> 5;
#pragma unroll
  for (int i = 0; i < 32; i += 8) {
    int n = n0 + ty + i, k = k0 + tx;
    float u = 1.f / (1.f + __expf(-((float)Xgc[(size_t)n * 768 + 256 + k] +
                                    bg[256 + k])));
    float c = tanhf((float)Xgc[(size_t)n * 768 + 512 + k] + bc[k]);
    tile[ty + i][tx] = u * c;
  }
  __syncthreads();
#pragma unroll
  for (int i = 0; i < 32; i += 8)
    rnnT[(size_t)(k0 + ty + i) * NN + n0 + tx] = (f16)tile[tx][ty + i];
}

// ---------------------------------------------------------------------------
// gru_step: one kernel per scan step (t>=1).  16 rows per block, grid 128.
// ---------------------------------------------------------------------------
__global__ __launch_bounds__(256) void gru_step(
    const float* __restrict__ hP, const f16* __restrict__ Xgc,
    const f16* __restrict__ WghT, const f16* __restrict__ WchT,
    const float* __restrict__ bg, const float* __restrict__ bc,
    f16* __restrict__ rnnT) {
  __shared__ alignas(16) f16 A_s[16 * 264];
  __shared__ alignas(16) f16 rh_s[16 * 264];
  __shared__ float u_s[16 * 260];
  __shared__ float hf_s[16 * 260];
  __shared__ alignas(16) f16 tileT[256 * 24];
  const int tid = threadIdx.x;
  const int lane = tid & 63, wid = tid >> 6;
  const int cl = lane & 15, hi = lane >> 4;
  const int r0 = blockIdx.x * 16;

#pragma unroll
  for (int i = 0; i < 4; ++i) {
    int e = i * 256 + tid;
    int row = e >> 6, off = (e & 63) * 4;
    size_t gi = (size_t)(r0 + row) * 256 + off;
    float4 s = *(const float4*)(hP + gi);
#pragma unroll
    for (int p = 1; p < 8; ++p) {
      float4 v = *(const float4*)(hP + (size_t)p * 524288 + gi);
      s.x += v.x; s.y += v.y; s.z += v.z; s.w += v.w;
    }
    *(float4*)&hf_s[row * 260 + off] = s;
    f16x4 h4 = {(f16)s.x, (f16)s.y, (f16)s.z, (f16)s.w};
    *(f16x4*)&A_s[row * 264 + off] = h4;
  }
  __syncthreads();

  const int wc0 = wid * 128;
  f32x4 acc[8];
#pragma unroll
  for (int n = 0; n < 8; ++n) acc[n] = (f32x4){0.f, 0.f, 0.f, 0.f};
#pragma unroll
  for (int kk = 0; kk < 256; kk += 32) {
    f16x8 af = *(const f16x8*)&A_s[cl * 264 + kk + hi * 8];
#pragma unroll
    for (int n = 0; n < 8; ++n) {
      f16x8 bf = *(const f16x8*)(WghT + (size_t)(wc0 + n * 16 + cl) * 256 +
                                 kk + hi * 8);
      acc[n] = __builtin_amdgcn_mfma_f32_16x16x32_f16(af, bf, acc[n], 0, 0, 0);
    }
  }
#pragma unroll
  for (int n = 0; n < 8; ++n) {
    int cc = wc0 + n * 16 + cl;
    float bgv = bg[cc];
#pragma unroll
    for (int q = 0; q < 4; ++q) {
      int rl = hi * 4 + q;
      float v = acc[n][q] + bgv + (float)Xgc[(size_t)(r0 + rl) * 768 + cc];
      float sv = 1.f / (1.f + __expf(-v));
      if (cc < 256)
        rh_s[rl * 264 + cc] = (f16)(sv * hf_s[rl * 260 + cc]);
      else
        u_s[rl * 260 + cc - 256] = sv;
    }
  }
  __syncthreads();

  const int wc2 = wid * 64;
  f32x4 acc2[4];
#pragma unroll
  for (int n = 0; n < 4; ++n) acc2[n] = (f32x4){0.f, 0.f, 0.f, 0.f};
#pragma unroll
  for (int kk = 0; kk < 256; kk += 32) {
    f16x8 af = *(const f16x8*)&rh_s[cl * 264 + kk + hi * 8];
#pragma unroll
    for (int n = 0; n < 4; ++n) {
      f16x8 bf = *(const f16x8*)(WchT + (size_t)(wc2 + n * 16 + cl) * 256 +
                                 kk + hi * 8);
      acc2[n] = __builtin_amdgcn_mfma_f32_16x16x32_f16(af, bf, acc2[n], 0, 0, 0);
    }
  }
#pragma unroll
  for (int n = 0; n < 4; ++n) {
    int cc = wc2 + n * 16 + cl;
    float bcv = bc[cc];
#pragma unroll
    for (int q = 0; q < 4; ++q) {
      int rl = hi * 4 + q;
      float cv = tanhf(acc2[n][q] + bcv +
                       (float)Xgc[(size_t)(r0 + rl) * 768 + 512 + cc]);
      float u = u_s[rl * 260 + cc];
      float hv = hf_s[rl * 260 + cc];
      tileT[cc * 24 + rl] = (f16)((1.f - u) * hv + u * cv);
    }
  }
  __syncthreads();
  {
    int cc = tid;
    *(f16x8*)&rnnT[(size_t)cc * NN + r0] = *(const f16x8*)&tileT[cc * 24];
    *(f16x8*)&rnnT[(size_t)cc * NN + r0 + 8] =
        *(const f16x8*)&tileT[cc * 24 + 8];
  }
}

// ---------------------------------------------------------------------------
// Fused P/Q/decode
// ---------------------------------------------------------------------------
__global__ __launch_bounds__(256) void pq_decode(
    const f16* __restrict__ emb, const f16* __restrict__ scal,
    const float* __restrict__ sq, float* __restrict__ out) {
  __shared__ alignas(16) f16 EA[128 * 64], EB[128 * 64], SA[128 * 64],
      SB[128 * 64];
  const int tid = threadIdx.x;
  const int lane = tid & 63, wid = tid >> 6;
  const int wm = wid >> 1, wn = wid & 1;
  const int row0 = blockIdx.y * 128, col0 = blockIdx.x * 128;
  const int l8 = lane >> 3;
  const int lx = ((lane & 7) ^ l8) * 8;
  const int sw = (lane & 7) * 8;
#pragma unroll
  for (int i = 0; i < 2; ++i) {
    int r = wid * 16 + i * 8;
    gld_lds16(emb + (size_t)(row0 + r + l8) * 64 + lx, &EA[r * 64]);
    gld_lds16(emb + (size_t)(col0 + r + l8) * 64 + lx, &EB[r * 64]);
    gld_lds16(scal + (size_t)(row0 + r + l8) * 64 + lx, &SA[r * 64]);
    gld_lds16(scal + (size_t)(col0 + r + l8) * 64 + lx, &SB[r * 64]);
    int r2 = r + 64;
    gld_lds16(emb + (size_t)(row0 + r2 + l8) * 64 + lx, &EA[r2 * 64]);
    gld_lds16(emb + (size_t)(col0 + r2 + l8) * 64 + lx, &EB[r2 * 64]);
    gld_lds16(scal + (size_t)(row0 + r2 + l8) * 64 + lx, &SA[r2 * 64]);
    gld_lds16(scal + (size_t)(col0 + r2 + l8) * 64 + lx, &SB[r2 * 64]);
  }
  __syncthreads();
  f32x4 accP[4][4], accQ[4][4];
#pragma unroll
  for (int m = 0; m < 4; ++m)
#pragma unroll
    for (int n = 0; n < 4; ++n) {
      accP[m][n] = (f32x4){0.f, 0.f, 0.f, 0.f};
      accQ[m][n] = (f32x4){0.f, 0.f, 0.f, 0.f};
    }
#pragma unroll
  for (int ks = 0; ks < 2; ++ks) {
    f16x8 af[4], bf[4];
#pragma unroll
    for (int m = 0; m < 4; ++m)
      af[m] = *(const f16x8*)&EA[((wm * 64 + m * 16 + (lane & 15)) * 64 +
                                  ks * 32 + (lane >> 4) * 8) ^ sw];
#pragma unroll
    for (int n = 0; n < 4; ++n)
      bf[n] = *(const f16x8*)&EB[((wn * 64 + n * 16 + (lane & 15)) * 64 +
                                  ks * 32 + (lane >> 4) * 8) ^ sw];
#pragma unroll
    for (int m = 0; m < 4; ++m)
#pragma unroll
      for (int n = 0; n < 4; ++n)
        accP[m][n] = __builtin_amdgcn_mfma_f32_16x16x32_f16(af[m], bf[n],
                                                            accP[m][n], 0, 0, 0);
#pragma unroll
    for (int m = 0; m < 4; ++m)
      af[m] = *(const f16x8*)&SA[((wm * 64 + m * 16 + (lane & 15)) * 64 +
                                  ks * 32 + (lane >> 4) * 8) ^ sw];
#pragma unroll
    for (int n = 0; n < 4; ++n)
      bf[n] = *(const f16x8*)&SB[((wn * 64 + n * 16 + (lane & 15)) * 64 +
                                  ks * 32 + (lane >> 4) * 8) ^ sw];
#pragma unroll
    for (int m = 0; m < 4; ++m)
#pragma unroll
      for (int n = 0; n < 4; ++n)
        accQ[m][n] = __builtin_amdgcn_mfma_f32_16x16x32_f16(af[m], bf[n],
                                                            accQ[m][n], 0, 0, 0);
  }
  const int cl = lane & 15, rh4 = (lane >> 4) * 4;
#pragma unroll
  for (int m = 0; m < 4; ++m) {
#pragma unroll
    for (int n = 0; n < 4; ++n) {
      int c = col0 + wn * 64 + n * 16 + cl;
      float sqc = sq[c];
#pragma unroll
      for (int q = 0; q < 4; ++q) {
        size_t r = row0 + wm * 64 + m * 16 + rh4 + q;
        float dist = -(sq[r] + sqc - 2.f * accP[m][n][q]);
        out[r * NN + c] = 1.f + tanhf(dist * accQ[m][n][q]);
      }
    }
  }
}

// --- fused weight transpose + feat/noise f32->f16 convert ---------------------
struct MT {
  const float* src[11];
  f16* dst[11];
  int K[11], N[11], st[11], ts[12];
  const float* feat;
  f16* feat16;
  const float* noise;
  f16* noise16;
};
__global__ __launch_bounds__(256) void multi_transp(MT mt) {
  int b = blockIdx.x;
  if (b >= mt.ts[11]) {
    long e = ((long)(b - mt.ts[11]) * 256 + threadIdx.x) * 4;
    const long FN4 = 5L * NN * F_IN;
    const float* src;
    f16* dst;
    long j;
    if (e < FN4) {
      src = mt.feat; dst = mt.feat16; j = e;
    } else {
      src = mt.noise; dst = mt.noise16; j = e - FN4;
    }
    float4 v = *(const float4*)(src + j);
    f16x4 o = {(f16)v.x, (f16)v.y, (f16)v.z, (f16)v.w};
    *(f16x4*)(dst + j) = o;
    return;
  }
  __shared__ float tile[32][33];
  int w = 0;
  while (b >= mt.ts[w + 1]) ++w;
  int lt = b - mt.ts[w];
  int K = mt.K[w], N = mt.N[w];
  int tk = lt % (K >> 5), tn = lt / (K >> 5);
  int k0 = tk * 32, n0 = tn * 32;
  int tx = threadIdx.x & 31, ty = threadIdx.x >> 5;
  const float* src = mt.src[w];
#pragma unroll
  for (int i = 0; i < 32; i += 8)
    tile[ty + i][tx] = src[(size_t)(k0 + ty + i) * N + n0 + tx];
  __syncthreads();
  f16* dst = mt.dst[w];
  int st = mt.st[w];
#pragma unroll
  for (int i = 0; i < 32; i += 8)
    dst[(size_t)(n0 + ty + i) * st + k0 + tx] = (f16)tile[tx][ty + i];
}

// --- row softmax (f32) + mix with align -> fp16 -------------------------------
__global__ __launch_bounds__(256) void softmax_mix(
    const float* __restrict__ S, const float* __restrict__ Al,
    const float* __restrict__ lam_ptr, f16* __restrict__ Mh) {
  const int tid = threadIdx.x;
  const float4* s4 = (const float4*)(S + (size_t)blockIdx.x * 2048);
  float4 a = s4[tid], b = s4[tid + 256];
  float m = fmaxf(fmaxf(fmaxf(a.x, a.y), fmaxf(a.z, a.w)),
                  fmaxf(fmaxf(b.x, b.y), fmaxf(b.z, b.w)));
  __shared__ float red[4];
  float w = wave_max(m);
  if ((tid & 63) == 0) red[tid >> 6] = w;
  __syncthreads();
  m = fmaxf(fmaxf(red[0], red[1]), fmaxf(red[2], red[3]));
  __syncthreads();
  a.x = __expf(a.x - m); a.y = __expf(a.y - m);
  a.z = __expf(a.z - m); a.w = __expf(a.w - m);
  b.x = __expf(b.x - m); b.y = __expf(b.y - m);
  b.z = __expf(b.z - m); b.w = __expf(b.w - m);
  float s = a.x + a.y + a.z + a.w + b.x + b.y + b.z + b.w;
  w = wave_sum(s);
  if ((tid & 63) == 0) red[tid >> 6] = w;
  __syncthreads();
  float inv = 1.f / (red[0] + red[1] + red[2] + red[3]);
  float lam = lam_ptr[0], oml = 1.f - lam;
  const float4* al4 = (const float4*)(Al + (size_t)blockIdx.x * 2048);
  float4 x = al4[tid], y = al4[tid + 256];
  f16x4 o0 = {(f16)(lam * x.x + oml * a.x * inv),
              (f16)(lam * x.y + oml * a.y * inv),
              (f16)(lam * x.z + oml * a.z * inv),
              (f16)(lam * x.w + oml * a.w * inv)};
  f16x4 o1 = {(f16)(lam * y.x + oml * b.x * inv),
              (f16)(lam * y.y + oml * b.y * inv),
              (f16)(lam * y.z + oml * b.z * inv),
              (f16)(lam * y.w + oml * b.w * inv)};
  f16x4* out4 = (f16x4*)(Mh + (size_t)blockIdx.x * 2048);
  out4[tid] = o0;
  out4[tid + 256] = o1;
}

// --- column L2 norms of emb0 [N,64] ------------------------------------------
__global__ __launch_bounds__(256) void col_l2norm64(
    const float* __restrict__ x, float* __restrict__ cn) {
  int c = blockIdx.x;
  float ss = 0.f;
  for (int r = threadIdx.x; r < NN; r += 256) {
    float v = x[(long)r * 64 + c];
    ss += v * v;
  }
  __shared__ float red[4];
  float w = wave_sum(ss);
  if ((threadIdx.x & 63) == 0) red[threadIdx.x >> 6] = w;
  __syncthreads();
  if (threadIdx.x == 0)
    cn[c] = fmaxf(sqrtf(red[0] + red[1] + red[2] + red[3]), 1e-12f);
}

// --- emb16 = emb0/cn ; sq[i] = row sumsq -------------------------------------
__global__ void norm_sq64h(const float* __restrict__ x,
                           const float* __restrict__ cn,
                           f16* __restrict__ emb16, float* __restrict__ sq) {
  int i = blockIdx.x, j = threadIdx.x;
  float e = x[(long)i * 64 + j] / cn[j];
  emb16[(long)i * 64 + j] = (f16)e;
  float s = wave_sum(e * e);
  if (j == 0) sq[i] = s;
}

// ---------------------------------------------------------------------------
extern "C" void kernel_launch(void* const* d_in, const int* in_sizes, int n_in,
                              void* d_out, int out_size, void* d_ws,
                              size_t ws_size, hipStream_t stream) {
  (void)in_sizes; (void)n_in; (void)out_size; (void)ws_size;
  const float* sup    = (const float*)d_in[0];
  const float* feat   = (const float*)d_in[1];
  const float* noise  = (const float*)d_in[2];
  const float* align  = (const float*)d_in[3];
  const float* lambd  = (const float*)d_in[4];
  const float* W_fem  = (const float*)d_in[5];
  const float* b_fem  = (const float*)d_in[6];
  const float* W_gnn  = (const float*)d_in[7];
  const float* b_gnn  = (const float*)d_in[8];
  const float* Wg_x   = (const float*)d_in[9];
  const float* Wg_h   = (const float*)d_in[10];
  const float* bg     = (const float*)d_in[11];
  const float* Wc_x   = (const float*)d_in[12];
  const float* Wc_h   = (const float*)d_in[13];
  const float* bc     = (const float*)d_in[14];
  const float* W_att  = (const float*)d_in[15];
  const float* b_att  = (const float*)d_in[16];
  const float* W_emb1 = (const float*)d_in[17];
  const float* b_emb1 = (const float*)d_in[18];
  const float* W_emb2 = (const float*)d_in[19];
  const float* b_emb2 = (const float*)d_in[20];
  const float* W_scal1= (const float*)d_in[21];
  const float* b_scal1= (const float*)d_in[22];
  const float* W_scal2= (const float*)d_in[23];
  const float* b_scal2= (const float*)d_in[24];

  char* wsb = (char*)d_ws;
  size_t po = 0;
  auto P = [&](size_t bytes) {
    size_t r = po;
    po += (bytes + 255) & ~(size_t)255;
    return r;
  };
  f16* fem16  = (f16*)(wsb + P(5L * NN * HF * 2));
  f16* fm16   = (f16*)(wsb + P(5L * NN * HH * 2));
  f16* g16    = (f16*)(wsb + P(4L * NN * HH * 2));
  f16* WT     = (f16*)(wsb + P(884736L * 2));
  f16* Xgc16  = (f16*)(wsb + P(4L * NN * 768 * 2));
  float* hA   = (float*)(wsb + P((long)NN * HH * 4));
  f16* h16A   = (f16*)(wsb + P((long)NN * HH * 2));
  f16* rnnT16 = (f16*)(wsb + P((long)NN * HH * 2));
  float* hP   = (float*)(wsb + P(8L * NN * HH * 4));
  f16* M16_2  = (f16*)(wsb + P(2L * NN * NN * 2));
  f16* e1s1   = (f16*)(wsb + P((long)NN * 512 * 2));
  float* embscF = (float*)(wsb + P(2L * NN * E2D * 4));
  f16* embsc16  = (f16*)(wsb + P(2L * NN * E2D * 2));
  f16* emb16  = (f16*)(wsb + P((long)NN * E2D * 2));
  float* cn   = (float*)(wsb + P(64 * 4));
  float* sq   = (float*)(wsb + P(NN * 4));
  // arena: feat16 | noise16 | edmWT | aggP early; Sbuf2 aliases later
  size_t arena = P(34078720);
  f16* feat16  = (f16*)(wsb + arena);                 //  2,621,440 B
  f16* noise16 = (f16*)(wsb + arena + 2621440);       //  2,097,152 B
  f16* edmWT   = (f16*)(wsb + arena + 8912896);       //  4,194,304 B
  f16* aggP    = (f16*)(wsb + arena + 13107200);      // 16,777,216 B
  float* Sbuf2 = (float*)(wsb + arena);               // 33,554,432 B

  // --- weight transpose table -------------------------------------------------
  f16* W_femT  = WT;                       // 256x128
  f16* W_gnnT  = W_femT + 32768;           // 256x384
  f16* WgxcT   = W_gnnT + 98304;           // 768x256 ([Wgx^T; Wcx^T])
  f16* WghT    = WgxcT + 196608;           // 512x256
  f16* WchT    = WghT + 131072;            // 256x256
  f16* W_attT  = WchT + 65536;             // 256x256
  f16* We1s1T  = W_attT + 65536;           // 512x512 ([Wemb1^T; Wscal1^T])
  f16* Wemb2T  = We1s1T + 262144;          // 64x256
  f16* Wscal2T = Wemb2T + 16384;           // 64x256 (adjacent: zB=16384)

  MT mt;
  const float* wsrc[11] = {W_fem, W_gnn, Wg_x, Wc_x, Wg_h, Wc_h,
                           W_att, W_emb1, W_scal1, W_emb2, W_scal2};
  f16* wdst[11] = {W_femT, W_gnnT, WgxcT, WgxcT + 512 * 256, WghT, WchT,
                   W_attT, We1s1T, We1s1T + 256 * 512, Wemb2T, Wscal2T};
  const int wK[11]  = {128, 384, 256, 256, 256, 256, 256, 512, 512, 256, 256};
  const int wNd[11] = {256, 256, 512, 256, 512, 256, 256, 256, 256, 64, 64};
  const int wSt[11] = {128, 384, 256, 256, 256, 256, 256, 512, 512, 256, 256};
  int tcum = 0;
  for (int i = 0; i < 11; ++i) {
    mt.src[i] = wsrc[i];
    mt.dst[i] = wdst[i];
    mt.K[i] = wK[i];
    mt.N[i] = wNd[i];
    mt.st[i] = wSt[i];
    mt.ts[i] = tcum;
    tcum += (wK[i] >> 5) * (wNd[i] >> 5);
  }
  mt.ts[11] = tcum;
  mt.feat = feat;
  mt.feat16 = feat16;
  mt.noise = noise;
  mt.noise16 = noise16;
  const int cvt_blocks = (5 * NN * F_IN + 4 * NN * DZ) / 1024;  // 2304

  const f16* NH = nullptr;
  float* NF = nullptr;
  f16* NHm = nullptr;

  multi_transp<<<tcum + cvt_blocks, 256, 0, stream>>>(mt);

  // FEM: fem16 = relu(feat @ W_fem + b)
  hgemm<1, 64, 1><<<dim3(4, 80, 1), 256, 0, stream>>>(
      feat16, NH, W_femT, b_fem, nullptr, NF, fem16,
      128, 0, 128, 128, 256, 128, 0, 0, 0, 0);

  // edmWT[t][c][n] = (edm[t] @ Wgnn)^T, written transposed directly (WOUT=3)
  hgemm<0, 64, 3><<<dim3(4, 16, 4), 256, 0, stream>>>(
      fem16, noise16, W_gnnT, nullptr, nullptr, NF, edmWT,
      256, 128, 256, 384, 2048, 384,
      (long)NN * HF, (long)NN * DZ, 0, 256L * NN);

  // sup @ edmW partials (sup read once) + finalize (bias+relu+l2norm)
  sup_gnn3<<<dim3(32, 4, 4), 256, 0, stream>>>(sup, edmWT, aggP);
  gnn_fin<<<2048, 256, 0, stream>>>(aggP, b_gnn, g16);

  // fm16 = fem @ W_att + b
  hgemm<0, 64, 1><<<dim3(4, 80, 1), 256, 0, stream>>>(
      fem16, NH, W_attT, b_att, nullptr, NF, fm16,
      256, 0, 256, 256, 256, 256, 0, 0, 0, 0);

  // Xgc = g16 @ [Wgx | Wcx]  -> [8192 x 768] f16 pre-activations
  hgemm<0, 64, 1><<<dim3(12, 64, 1), 256, 0, stream>>>(
      g16, NH, WgxcT, nullptr, nullptr, NF, Xgc16,
      256, 0, 256, 256, 768, 256, 0, 0, 0, 0);

  for (int p = 0; p < 2; ++p) {
    // S pair (f32 out): S[z] = fm[2p+z+1] @ fm[2p+z]^T
    hgemm<0, 128, 0><<<dim3(16, 16, 2), 256, 0, stream>>>(
        fm16 + (size_t)(2 * p + 1) * NN * HH, NH,
        fm16 + (size_t)(2 * p) * NN * HH, nullptr, nullptr, Sbuf2, NHm,
        256, 0, 256, 256, 2048, 256,
        (long)NN * HH, 0, (long)NN * HH, (long)NN * NN);
    softmax_mix<<<2 * NN, 256, 0, stream>>>(
        Sbuf2, align + (size_t)(2 * p) * NN * NN, lambd, M16_2);

    for (int tl = 0; tl < 2; ++tl) {
      int t = 2 * p + tl;
      if (t == 0) {
        rnn0_t<<<dim3(64, 8, 1), 256, 0, stream>>>(Xgc16, bg, bc, rnnT16);
      } else {
        gru_step<<<128, 256, 0, stream>>>(
            hP, Xgc16 + (size_t)t * NN * 768, WghT, WchT, bg, bc, rnnT16);
      }
      // h_{t} partials = M16 @ rnn (K-split x8: each z does K=256)
      hgemm<0, 64, 0><<<dim3(4, 16, 8), 256, 0, stream>>>(
          M16_2 + (size_t)(t & 1) * NN * NN, NH, rnnT16, nullptr, nullptr,
          hP, NHm, 2048, 0, 2048, 2048, 256, 256,
          256, 0, 256, 524288);
    }
  }
  // final h for EAM
  hsum8<<<512, 256, 0, stream>>>(hP, hA, h16A);

  // --- EAM tail ---------------------------------------------------------------
  hgemm<6, 64, 1><<<dim3(8, 16, 1), 256, 0, stream>>>(
      h16A, fem16 + 4L * NN * HF, We1s1T, b_emb1, b_scal1, NF, e1s1,
      256, 256, 256, 512, 512, 512, 0, 0, 0, 0);
  // zA=256: z=1 (scal head) reads the s1 half of e1s1.
  hgemm<5, 64, 2><<<dim3(1, 16, 2), 256, 0, stream>>>(
      e1s1, NH, Wemb2T, b_emb2, b_scal2, embscF, embsc16,
      512, 0, 512, 256, 64, 256, 256, 0, 16384, (long)NN * E2D);
  col_l2norm64<<<64, 256, 0, stream>>>(embscF, cn);
  norm_sq64h<<<NN, 64, 0, stream>>>(embscF, cn, emb16, sq);

  pq_decode<<<dim3(16, 16, 1), 256, 0, stream>>>(
      emb16, embsc16 + (size_t)NN * E2D, sq, (float*)d_out);
}